// Round 8
// baseline (107.746 us; speedup 1.0000x reference)
//
#include <hip/hip_runtime.h>
#include <hip/hip_fp16.h>
#include <math.h>

#define TT 16
#define HH 64
#define WW 64
#define CC 128

__device__ __forceinline__ float2 cadd(float2 a, float2 b){ return make_float2(a.x+b.x, a.y+b.y); }
__device__ __forceinline__ float2 csub(float2 a, float2 b){ return make_float2(a.x-b.x, a.y-b.y); }
__device__ __forceinline__ float2 cmul(float2 a, float2 b) {
    return make_float2(a.x*b.x - a.y*b.y, a.x*b.y + a.y*b.x);
}
__device__ __forceinline__ float2 cmac(float2 acc, float2 a, float2 b) {
    acc.x = fmaf(a.x, b.x, fmaf(-a.y, b.y, acc.x));
    acc.y = fmaf(a.x, b.y, fmaf(a.y, b.x, acc.y));
    return acc;
}
__device__ __forceinline__ float2 csq(float2 a) {
    return make_float2(a.x*a.x - a.y*a.y, 2.f*a.x*a.y);
}

// ---------------- radix butterflies ----------------
template<int SGN>
__device__ __forceinline__ void dft4(float2 b0, float2 b1, float2 b2, float2 b3,
                                     float2& y0, float2& y1, float2& y2, float2& y3) {
    float2 e0 = cadd(b0, b2), e1 = csub(b0, b2);
    float2 o0 = cadd(b1, b3), o1 = csub(b1, b3);
    y0 = cadd(e0, o0); y2 = csub(e0, o0);
    float2 r = make_float2((float)(-SGN) * o1.y, (float)SGN * o1.x);
    y1 = cadd(e1, r); y3 = csub(e1, r);
}

template<int SGN>
__device__ __forceinline__ void dft8(const float2* a, float2* X) {
    const float C = 0.70710678118654752f;
    float2 E0,E1,E2,E3,O0,O1,O2,O3;
    dft4<SGN>(a[0],a[2],a[4],a[6], E0,E1,E2,E3);
    dft4<SGN>(a[1],a[3],a[5],a[7], O0,O1,O2,O3);
    float2 T1 = make_float2(C*(O1.x - (float)SGN*O1.y), C*((float)SGN*O1.x + O1.y));
    float2 T2 = make_float2((float)(-SGN)*O2.y, (float)SGN*O2.x);
    float2 T3 = make_float2(-C*(O3.x + (float)SGN*O3.y), C*((float)SGN*O3.x - O3.y));
    X[0]=cadd(E0,O0); X[4]=csub(E0,O0);
    X[1]=cadd(E1,T1); X[5]=csub(E1,T1);
    X[2]=cadd(E2,T2); X[6]=csub(E2,T2);
    X[3]=cadd(E3,T3); X[7]=csub(E3,T3);
}

template<int SGN>
__device__ __forceinline__ void dft16(const float2* v, float2* X) {
    const float ct[10] = {1.f, 0.92387953251f, 0.70710678119f, 0.38268343236f, 0.f,
                          0.f, -0.70710678119f, 0.f, 0.f, -0.92387953251f};
    const float st[10] = {0.f, 0.38268343236f, 0.70710678119f, 0.92387953251f, 1.f,
                          0.f, 0.70710678119f, 0.f, 0.f, -0.38268343236f};
    float2 Z[16];
    #pragma unroll
    for (int h0 = 0; h0 < 4; ++h0) {
        float2 y0,y1,y2,y3;
        dft4<SGN>(v[h0], v[4+h0], v[8+h0], v[12+h0], y0,y1,y2,y3);
        float2 ys[4] = {y0,y1,y2,y3};
        #pragma unroll
        for (int k0 = 0; k0 < 4; ++k0) {
            int m = h0 * k0;
            float cc = ct[m], ss = (float)SGN * st[m];
            Z[k0*4 + h0] = make_float2(ys[k0].x*cc - ys[k0].y*ss,
                                       ys[k0].x*ss + ys[k0].y*cc);
        }
    }
    #pragma unroll
    for (int k0 = 0; k0 < 4; ++k0) {
        float2 y0,y1,y2,y3;
        dft4<SGN>(Z[k0*4+0], Z[k0*4+1], Z[k0*4+2], Z[k0*4+3], y0,y1,y2,y3);
        X[k0] = y0; X[k0+4] = y1; X[k0+8] = y2; X[k0+12] = y3;
    }
}

// ---------------- fused kernel prep: tanh + kw-DFT + kh-DFT, half2 out ----------------
__global__ __launch_bounds__(256) void k_prep(const float* __restrict__ Ak,
                                              const float* __restrict__ Bk,
                                              __half2* __restrict__ Ahw,
                                              __half2* __restrict__ Bhw) {
    __shared__ float Asl[7][7][64];
    __shared__ float Bsl[7][7][64];
    __shared__ float2 Awl[7][64];
    __shared__ float2 Bwl[7][64];
    __shared__ float2 tw64[64];
    int bid = blockIdx.x;
    int kt = bid / 66;
    int rem = bid % 66;
    int om = rem >> 1, chalf = rem & 1;
    int c0 = chalf * 64;
    int tid = threadIdx.x;
    for (int i = tid; i < 64; i += 256) {
        float s, cq; sincosf(-6.283185307179586f * i / 64.0f, &s, &cq);
        tw64[i] = make_float2(cq, s);
    }
    for (int i = tid; i < 49 * 64; i += 256) {
        int p = i >> 6, cl = i & 63;
        int kh = p / 7, kw = p % 7;
        int idx = (((c0 + cl) * 3 + kt) * 7 + kh) * 7 + kw;
        Asl[kh][kw][cl] = 0.9f * tanhf(Ak[idx]);
        Bsl[kh][kw][cl] = Bk[idx];
    }
    __syncthreads();
    for (int i = tid; i < 7 * 64; i += 256) {
        int kh = i >> 6, cl = i & 63;
        float2 aA = make_float2(0.f,0.f), aB = make_float2(0.f,0.f);
        #pragma unroll
        for (int kw = 0; kw < 7; ++kw) {
            float2 t = tw64[(om * (kw - 3)) & 63];
            float va = Asl[kh][kw][cl], vb = Bsl[kh][kw][cl];
            aA.x = fmaf(va, t.x, aA.x); aA.y = fmaf(va, t.y, aA.y);
            aB.x = fmaf(vb, t.x, aB.x); aB.y = fmaf(vb, t.y, aB.y);
        }
        Awl[kh][cl] = aA; Bwl[kh][cl] = aB;
    }
    __syncthreads();
    for (int i = tid; i < 64 * 64; i += 256) {
        int eta = i >> 6, cl = i & 63;
        float2 aA = make_float2(0.f,0.f), aB = make_float2(0.f,0.f);
        #pragma unroll
        for (int kh = 0; kh < 7; ++kh) {
            float2 t = tw64[(eta * (kh - 3)) & 63];
            aA = cmac(aA, Awl[kh][cl], t);
            aB = cmac(aB, Bwl[kh][cl], t);
        }
        int ep = ((eta & 7) << 3) | (eta >> 3);      // digit-swapped eta position
        int o = ((kt * 33 + om) * 64 + ep) * 128 + c0 + cl;
        Ahw[o] = __float22half2_rn(aA);
        Bhw[o] = __float22half2_rn(aB);
    }
}

// Z layout (half2): Z[om33][cc16][t16][h64][c8]  -> uint4 index:
//   (((om*16+cc)*16 + t)*64 + h)*2 + p   (p = c-half of 8 channels)
// Each pmid block owns one contiguous 32 KB chunk (om,cc).

// ------- pass 1: forward radix-8 FFT along W (real input) -> dense Z -------
// grid: t(16) x hq(16) x chalf(2) = 512 blocks, 512 threads.
__global__ __launch_bounds__(512) void p1(const float* __restrict__ x,
                                          uint4* __restrict__ Z) {
    __shared__ float rf[64][64];           // 16 KB plane (fp32), aliased half2 after stage 1
    __shared__ __half2 sp[4][33][64];      // 33.8 KB spectra staging
    __shared__ float2 tw64[64];
    __half2* zal = (__half2*)&rf[0][0];
    int bid = blockIdx.x;
    int t = bid >> 5, hq = (bid >> 1) & 15, chalf = bid & 1;
    int tid = threadIdx.x;
    if (tid < 64) {
        float s, cq; sincosf(-6.283185307179586f * tid / 64.0f, &s, &cq);
        tw64[tid] = make_float2(cq, s);
    }
    int c = tid & 63, s4 = tid >> 6;       // s4 in [0,8)
    for (int hh = 0; hh < 4; ++hh) {
        const float4* src4 = (const float4*)(x + (size_t)(t*64 + hq*4 + hh) * 64 * 128
                                               + chalf * 64);
        for (int i = tid; i < 1024; i += 512) {
            int w = i >> 4, c4 = (i & 15) * 4;
            float4 v = src4[w * 32 + (i & 15)];
            rf[w][c4] = v.x; rf[w][c4+1] = v.y; rf[w][c4+2] = v.z; rf[w][c4+3] = v.w;
        }
        __syncthreads();
        // stage 1 phase A: all fp32 reads to registers
        float ar[8];
        #pragma unroll
        for (int h1 = 0; h1 < 8; ++h1) ar[h1] = rf[h1*8 + s4][c];
        __syncthreads();
        // stage 1 phase B: dft8 + twiddle -> half2 alias in place
        {
            float2 a[8], Y[8];
            #pragma unroll
            for (int h1 = 0; h1 < 8; ++h1) a[h1] = make_float2(ar[h1], 0.f);
            dft8<-1>(a, Y);
            #pragma unroll
            for (int k0 = 0; k0 < 8; ++k0) {
                float2 z = cmul(Y[k0], tw64[(s4 * k0) & 63]);
                zal[(k0*8 + s4) * 64 + c] = __float22half2_rn(z);
            }
        }
        __syncthreads();
        // stage 2: k0 = s4, emit om<=32 into staging
        {
            float2 b[8], X[8];
            #pragma unroll
            for (int h0 = 0; h0 < 8; ++h0)
                b[h0] = __half22float2(zal[(s4*8 + h0) * 64 + c]);
            dft8<-1>(b, X);
            #pragma unroll
            for (int k1 = 0; k1 < 8; ++k1) {
                int om = s4 + 8 * k1;
                if (om <= 32) sp[hh][om][c] = __float22half2_rn(X[k1]);
            }
        }
        __syncthreads();
    }
    // dense write: 8 consecutive lanes emit one full 128B line (4h x 8c)
    for (int i = tid; i < 2112; i += 512) {
        int p = i & 1, hh = (i >> 1) & 3, jj = i >> 3;   // jj < 264
        int om = jj >> 3, ccl = jj & 7;
        int cb = ccl * 8 + p * 4;
        uint4 u;
        __half2 v0 = sp[hh][om][cb+0], v1 = sp[hh][om][cb+1];
        __half2 v2 = sp[hh][om][cb+2], v3 = sp[hh][om][cb+3];
        u.x = *(unsigned int*)&v0; u.y = *(unsigned int*)&v1;
        u.z = *(unsigned int*)&v2; u.w = *(unsigned int*)&v3;
        Z[(((size_t)(om*16 + chalf*8 + ccl)*16 + t)*64 + hq*4 + hh)*2 + p] = u;
    }
}

// ------- fused middle pass: H-FFT + T-FFT + G multiply + inv-T + inv-H, in place -------
// One block per (om,cc8): tile = contiguous 32 KB of Z. Logic identical to r7 (verified).
__global__ __launch_bounds__(512, 4) void pmid(uint4* __restrict__ Z,
                                               const __half2* __restrict__ Ahw,
                                               const __half2* __restrict__ Bhw) {
    __shared__ __half2 tl[16][64][9];     // 36.9 KB, pad column -> <=2-way banks
    // XCD-chunked swizzle: 528 = 8*66 (bijective)
    int l = (blockIdx.x & 7) * 66 + (blockIdx.x >> 3);
    int om = l >> 4, cc = l & 15;
    int c0 = cc * 8;
    int tid = threadIdx.x;
    uint4* g = Z + (size_t)l * 2048;

    // prefetch half2 G tables into registers (hidden under H stages)
    int cg = tid & 7, rT = tid >> 3;                 // rT in [0,64)
    const int PKT = 33 * 64 * 128;
    int kb = (om * 64 + rT) * 128 + c0 + cg;
    __half2 a0h = Ahw[kb], a1h = Ahw[kb + PKT], a2h = Ahw[kb + 2*PKT];
    __half2 b0h = Bhw[kb], b1h = Bhw[kb + PKT], b2h = Bhw[kb + 2*PKT];

    int d = tid & 7;
    float twc[8], tws[8];
    {
        float s1, c1; sincosf(-6.283185307179586f * d / 64.0f, &s1, &c1);
        twc[0] = 1.f; tws[0] = 0.f;
        #pragma unroll
        for (int k = 1; k < 8; ++k) {
            twc[k] = twc[k-1]*c1 - tws[k-1]*s1;
            tws[k] = twc[k-1]*s1 + tws[k-1]*c1;
        }
    }
    // load tile: fully contiguous 32 KB
    for (int i = tid; i < 2048; i += 512) {
        uint4 u = g[i];
        int t = i >> 7, h = (i >> 1) & 63, p = i & 1;
        tl[t][h][p*4+0] = *(__half2*)&u.x;
        tl[t][h][p*4+1] = *(__half2*)&u.y;
        tl[t][h][p*4+2] = *(__half2*)&u.z;
        tl[t][h][p*4+3] = *(__half2*)&u.w;
    }
    __syncthreads();
    int cl = (tid >> 3) & 7, ts = tid >> 6;          // ts in [0,8)
    // H forward stage 1: DFT8 over h1 at fixed h0=d, twiddle w^{-d*k0}
    #pragma unroll
    for (int q = 0; q < 2; ++q) {
        int t = ts*2 + q;
        float2 a[8], Y[8];
        #pragma unroll
        for (int h1 = 0; h1 < 8; ++h1)
            a[h1] = __half22float2(tl[t][h1*8 + d][cl]);
        dft8<-1>(a, Y);
        #pragma unroll
        for (int k0 = 0; k0 < 8; ++k0) {
            float2 z = make_float2(Y[k0].x*twc[k0] - Y[k0].y*tws[k0],
                                   Y[k0].x*tws[k0] + Y[k0].y*twc[k0]);
            tl[t][k0*8 + d][cl] = __float22half2_rn(z);
        }
    }
    __syncthreads();
    // H forward stage 2: DFT8 over h0 at fixed k0=d; row k0*8+k1 := bin k0+8*k1
    #pragma unroll
    for (int q = 0; q < 2; ++q) {
        int t = ts*2 + q;
        float2 a[8], Y[8];
        #pragma unroll
        for (int h0 = 0; h0 < 8; ++h0)
            a[h0] = __half22float2(tl[t][d*8 + h0][cl]);
        dft8<-1>(a, Y);
        #pragma unroll
        for (int k1 = 0; k1 < 8; ++k1)
            tl[t][d*8 + k1][cl] = __float22half2_rn(Y[k1]);
    }
    __syncthreads();
    // T phase: fwd dft16, G = S(A_f)*B_f multiply, inv dft16 (tables pre-permuted).
    {
        const float CT16[16] = {1.f, 0.9238795325f, 0.7071067812f, 0.3826834324f, 0.f,
                                -0.3826834324f, -0.7071067812f, -0.9238795325f, -1.f,
                                -0.9238795325f, -0.7071067812f, -0.3826834324f, 0.f,
                                0.3826834324f, 0.7071067812f, 0.9238795325f};
        const float ST16[16] = {0.f, 0.3826834324f, 0.7071067812f, 0.9238795325f, 1.f,
                                0.9238795325f, 0.7071067812f, 0.3826834324f, 0.f,
                                -0.3826834324f, -0.7071067812f, -0.9238795325f, -1.f,
                                -0.9238795325f, -0.7071067812f, -0.3826834324f};
        float2 v[16], X[16];
        #pragma unroll
        for (int t = 0; t < 16; ++t) v[t] = __half22float2(tl[t][rT][cg]);
        dft16<-1>(v, X);
        float2 A0 = __half22float2(a0h), A1 = __half22float2(a1h), A2 = __half22float2(a2h);
        float2 B0 = __half22float2(b0h), B1 = __half22float2(b1h), B2 = __half22float2(b2h);
        #pragma unroll
        for (int ta = 0; ta < 16; ++ta) {
            float2 wv = make_float2(CT16[ta], -ST16[ta]);
            float2 wc = make_float2(CT16[ta],  ST16[ta]);
            float2 Af = A1; Af = cmac(Af, A0, wc); Af = cmac(Af, A2, wv);
            float2 Bf = B1; Bf = cmac(Bf, B0, wc); Bf = cmac(Bf, B2, wv);
            // S = sum_{k=0}^{7} Af^k = (1+Af)(1+Af^2)(1+Af^4)
            float2 A2q = csq(Af), A4q = csq(A2q);
            float2 S = cmul(make_float2(1.f+Af.x, Af.y), make_float2(1.f+A2q.x, A2q.y));
            S = cmul(S, make_float2(1.f+A4q.x, A4q.y));
            float2 G = cmul(S, Bf);
            X[ta] = cmul(X[ta], G);
        }
        dft16<1>(X, v);
        const float sc = 0.015625f;                  // 1/64 fold
        #pragma unroll
        for (int t = 0; t < 16; ++t)
            tl[t][rT][cg] = __float22half2_rn(make_float2(v[t].x*sc, v[t].y*sc));
    }
    __syncthreads();
    // inverse H stage 1: DFT8<+1> over eta1 at fixed eta0=d, twiddle w^{+d*h0}
    #pragma unroll
    for (int q = 0; q < 2; ++q) {
        int t = ts*2 + q;
        float2 a[8], Y[8];
        #pragma unroll
        for (int e1 = 0; e1 < 8; ++e1)
            a[e1] = __half22float2(tl[t][d*8 + e1][cl]);
        dft8<1>(a, Y);
        #pragma unroll
        for (int h0 = 0; h0 < 8; ++h0) {
            float2 z = make_float2( Y[h0].x*twc[h0] + Y[h0].y*tws[h0],
                                   -Y[h0].x*tws[h0] + Y[h0].y*twc[h0]);
            tl[t][d*8 + h0][cl] = __float22half2_rn(z);
        }
    }
    __syncthreads();
    // inverse H stage 2: DFT8<+1> over eta0 at fixed h0=d; out row d+8*h1 (natural h)
    #pragma unroll
    for (int q = 0; q < 2; ++q) {
        int t = ts*2 + q;
        float2 a[8], Y[8];
        #pragma unroll
        for (int e0 = 0; e0 < 8; ++e0)
            a[e0] = __half22float2(tl[t][e0*8 + d][cl]);
        dft8<1>(a, Y);
        #pragma unroll
        for (int h1 = 0; h1 < 8; ++h1)
            tl[t][d + 8*h1][cl] = __float22half2_rn(Y[h1]);
    }
    __syncthreads();
    // write back: full-line overwrite of the block-private chunk
    for (int i = tid; i < 2048; i += 512) {
        int t = i >> 7, h = (i >> 1) & 63, p = i & 1;
        uint4 u;
        __half2 v0 = tl[t][h][p*4+0], v1 = tl[t][h][p*4+1];
        __half2 v2 = tl[t][h][p*4+2], v3 = tl[t][h][p*4+3];
        u.x = *(unsigned int*)&v0; u.y = *(unsigned int*)&v1;
        u.z = *(unsigned int*)&v2; u.w = *(unsigned int*)&v3;
        g[i] = u;
    }
}

// ------- pass 5: dense Z read + Hermitian-expand + inverse W-FFT, real out -------
// grid: t(16) x hq(16) x chalf(2) = 512 blocks, 512 threads.
__global__ __launch_bounds__(512) void p5(const uint4* __restrict__ Z,
                                          float* __restrict__ out) {
    __shared__ __half2 sp[4][33][64];      // 33.8 KB
    __shared__ __half2 plane[64][64];      // 16 KB
    __shared__ float2 tw64[64];
    int bid = blockIdx.x;
    int t = bid >> 5, hq = (bid >> 1) & 15, chalf = bid & 1;
    int tid = threadIdx.x;
    if (tid < 64) {
        float s, cq; sincosf(6.283185307179586f * tid / 64.0f, &s, &cq);
        tw64[tid] = make_float2(cq, s);
    }
    // dense staging read (full 128B lines)
    for (int i = tid; i < 2112; i += 512) {
        int p = i & 1, hh = (i >> 1) & 3, jj = i >> 3;
        int om = jj >> 3, ccl = jj & 7;
        uint4 u = Z[(((size_t)(om*16 + chalf*8 + ccl)*16 + t)*64 + hq*4 + hh)*2 + p];
        int cb = ccl * 8 + p * 4;
        sp[hh][om][cb+0] = *(__half2*)&u.x;
        sp[hh][om][cb+1] = *(__half2*)&u.y;
        sp[hh][om][cb+2] = *(__half2*)&u.z;
        sp[hh][om][cb+3] = *(__half2*)&u.w;
    }
    __syncthreads();
    int c = tid & 63, s4 = tid >> 6;
    for (int hh = 0; hh < 4; ++hh) {
        // Hermitian expand into the 64-om plane
        for (int i = tid; i < 33 * 64; i += 512) {
            int om = i >> 6, cl = i & 63;
            __half2 v = sp[hh][om][cl];
            plane[om][cl] = v;
            if (om >= 1 && om <= 31) {
                __half2 m = v; m.y = __hneg(m.y);
                plane[64 - om][cl] = m;
            }
        }
        __syncthreads();
        // stage 1 phase A: reads to registers
        float2 ar[8];
        #pragma unroll
        for (int h1 = 0; h1 < 8; ++h1)
            ar[h1] = __half22float2(plane[h1*8 + s4][c]);
        __syncthreads();
        // stage 1 phase B: dft8 + twiddle, in place
        {
            float2 Y[8];
            dft8<1>(ar, Y);
            #pragma unroll
            for (int k0 = 0; k0 < 8; ++k0) {
                float2 z = cmul(Y[k0], tw64[(s4 * k0) & 63]);
                plane[k0*8 + s4][c] = __float22half2_rn(z);
            }
        }
        __syncthreads();
        // stage 2 + dense fp32 output
        {
            float2 b[8], X[8];
            #pragma unroll
            for (int h0 = 0; h0 < 8; ++h0)
                b[h0] = __half22float2(plane[s4*8 + h0][c]);
            dft8<1>(b, X);
            float* dst = out + (size_t)(t*64 + hq*4 + hh) * 64 * 128 + chalf * 64 + c;
            #pragma unroll
            for (int k1 = 0; k1 < 8; ++k1)
                dst[(size_t)(s4 + 8*k1) * 128] = X[k1].x * (1.0f / 1024.0f);
        }
        __syncthreads();
    }
}

extern "C" void kernel_launch(void* const* d_in, const int* in_sizes, int n_in,
                              void* d_out, int out_size, void* d_ws, size_t ws_size,
                              hipStream_t stream) {
    const float* x  = (const float*)d_in[0];
    const float* Ak = (const float*)d_in[1];
    const float* Bk = (const float*)d_in[2];
    float* out = (float*)d_out;

    // Z: 33*16*16*64*8 half2 = 17.3 MB (uint4-addressed); G tables after.
    uint4* Z = (uint4*)d_ws;
    __half2* Ahw = (__half2*)((char*)d_ws + (size_t)33*16*16*64*8*4);
    __half2* Bhw = Ahw + 3 * 33 * 64 * 128;

    hipLaunchKernelGGL(k_prep, dim3(198), dim3(256), 0, stream, Ak, Bk, Ahw, Bhw);
    hipLaunchKernelGGL(p1,     dim3(512), dim3(512), 0, stream, x, Z);
    hipLaunchKernelGGL(pmid,   dim3(528), dim3(512), 0, stream, Z, Ahw, Bhw);
    hipLaunchKernelGGL(p5,     dim3(512), dim3(512), 0, stream, Z, out);
}

// Round 9
// 83.338 us; speedup vs baseline: 1.2929x; 1.2929x over previous
//
#include <hip/hip_runtime.h>
#include <hip/hip_fp16.h>
#include <math.h>

#define TT 16
#define HH 64
#define WW 64
#define CC 128

__device__ __forceinline__ float2 cadd(float2 a, float2 b){ return make_float2(a.x+b.x, a.y+b.y); }
__device__ __forceinline__ float2 csub(float2 a, float2 b){ return make_float2(a.x-b.x, a.y-b.y); }
__device__ __forceinline__ float2 cmul(float2 a, float2 b) {
    return make_float2(a.x*b.x - a.y*b.y, a.x*b.y + a.y*b.x);
}
__device__ __forceinline__ float2 cmac(float2 acc, float2 a, float2 b) {
    acc.x = fmaf(a.x, b.x, fmaf(-a.y, b.y, acc.x));
    acc.y = fmaf(a.x, b.y, fmaf(a.y, b.x, acc.y));
    return acc;
}
__device__ __forceinline__ float2 csq(float2 a) {
    return make_float2(a.x*a.x - a.y*a.y, 2.f*a.x*a.y);
}

// ---------------- radix butterflies ----------------
template<int SGN>
__device__ __forceinline__ void dft4(float2 b0, float2 b1, float2 b2, float2 b3,
                                     float2& y0, float2& y1, float2& y2, float2& y3) {
    float2 e0 = cadd(b0, b2), e1 = csub(b0, b2);
    float2 o0 = cadd(b1, b3), o1 = csub(b1, b3);
    y0 = cadd(e0, o0); y2 = csub(e0, o0);
    float2 r = make_float2((float)(-SGN) * o1.y, (float)SGN * o1.x);
    y1 = cadd(e1, r); y3 = csub(e1, r);
}

template<int SGN>
__device__ __forceinline__ void dft8(const float2* a, float2* X) {
    const float C = 0.70710678118654752f;
    float2 E0,E1,E2,E3,O0,O1,O2,O3;
    dft4<SGN>(a[0],a[2],a[4],a[6], E0,E1,E2,E3);
    dft4<SGN>(a[1],a[3],a[5],a[7], O0,O1,O2,O3);
    float2 T1 = make_float2(C*(O1.x - (float)SGN*O1.y), C*((float)SGN*O1.x + O1.y));
    float2 T2 = make_float2((float)(-SGN)*O2.y, (float)SGN*O2.x);
    float2 T3 = make_float2(-C*(O3.x + (float)SGN*O3.y), C*((float)SGN*O3.x - O3.y));
    X[0]=cadd(E0,O0); X[4]=csub(E0,O0);
    X[1]=cadd(E1,T1); X[5]=csub(E1,T1);
    X[2]=cadd(E2,T2); X[6]=csub(E2,T2);
    X[3]=cadd(E3,T3); X[7]=csub(E3,T3);
}

template<int SGN>
__device__ __forceinline__ void dft16(const float2* v, float2* X) {
    const float ct[10] = {1.f, 0.92387953251f, 0.70710678119f, 0.38268343236f, 0.f,
                          0.f, -0.70710678119f, 0.f, 0.f, -0.92387953251f};
    const float st[10] = {0.f, 0.38268343236f, 0.70710678119f, 0.92387953251f, 1.f,
                          0.f, 0.70710678119f, 0.f, 0.f, -0.38268343236f};
    float2 Z[16];
    #pragma unroll
    for (int h0 = 0; h0 < 4; ++h0) {
        float2 y0,y1,y2,y3;
        dft4<SGN>(v[h0], v[4+h0], v[8+h0], v[12+h0], y0,y1,y2,y3);
        float2 ys[4] = {y0,y1,y2,y3};
        #pragma unroll
        for (int k0 = 0; k0 < 4; ++k0) {
            int m = h0 * k0;
            float cc = ct[m], ss = (float)SGN * st[m];
            Z[k0*4 + h0] = make_float2(ys[k0].x*cc - ys[k0].y*ss,
                                       ys[k0].x*ss + ys[k0].y*cc);
        }
    }
    #pragma unroll
    for (int k0 = 0; k0 < 4; ++k0) {
        float2 y0,y1,y2,y3;
        dft4<SGN>(Z[k0*4+0], Z[k0*4+1], Z[k0*4+2], Z[k0*4+3], y0,y1,y2,y3);
        X[k0] = y0; X[k0+4] = y1; X[k0+8] = y2; X[k0+12] = y3;
    }
}

// ---------------- fused kernel prep: tanh + kw-DFT + kh-DFT, half2 out ----------------
__global__ __launch_bounds__(256) void k_prep(const float* __restrict__ Ak,
                                              const float* __restrict__ Bk,
                                              __half2* __restrict__ Ahw,
                                              __half2* __restrict__ Bhw) {
    __shared__ float Asl[7][7][64];
    __shared__ float Bsl[7][7][64];
    __shared__ float2 Awl[7][64];
    __shared__ float2 Bwl[7][64];
    __shared__ float2 tw64[64];
    int bid = blockIdx.x;
    int kt = bid / 66;
    int rem = bid % 66;
    int om = rem >> 1, chalf = rem & 1;
    int c0 = chalf * 64;
    int tid = threadIdx.x;
    for (int i = tid; i < 64; i += 256) {
        float s, cq; sincosf(-6.283185307179586f * i / 64.0f, &s, &cq);
        tw64[i] = make_float2(cq, s);
    }
    for (int i = tid; i < 49 * 64; i += 256) {
        int p = i >> 6, cl = i & 63;
        int kh = p / 7, kw = p % 7;
        int idx = (((c0 + cl) * 3 + kt) * 7 + kh) * 7 + kw;
        Asl[kh][kw][cl] = 0.9f * tanhf(Ak[idx]);
        Bsl[kh][kw][cl] = Bk[idx];
    }
    __syncthreads();
    for (int i = tid; i < 7 * 64; i += 256) {
        int kh = i >> 6, cl = i & 63;
        float2 aA = make_float2(0.f,0.f), aB = make_float2(0.f,0.f);
        #pragma unroll
        for (int kw = 0; kw < 7; ++kw) {
            float2 t = tw64[(om * (kw - 3)) & 63];
            float va = Asl[kh][kw][cl], vb = Bsl[kh][kw][cl];
            aA.x = fmaf(va, t.x, aA.x); aA.y = fmaf(va, t.y, aA.y);
            aB.x = fmaf(vb, t.x, aB.x); aB.y = fmaf(vb, t.y, aB.y);
        }
        Awl[kh][cl] = aA; Bwl[kh][cl] = aB;
    }
    __syncthreads();
    for (int i = tid; i < 64 * 64; i += 256) {
        int eta = i >> 6, cl = i & 63;
        float2 aA = make_float2(0.f,0.f), aB = make_float2(0.f,0.f);
        #pragma unroll
        for (int kh = 0; kh < 7; ++kh) {
            float2 t = tw64[(eta * (kh - 3)) & 63];
            aA = cmac(aA, Awl[kh][cl], t);
            aB = cmac(aB, Bwl[kh][cl], t);
        }
        int ep = ((eta & 7) << 3) | (eta >> 3);      // digit-swapped eta position
        int o = ((kt * 33 + om) * 64 + ep) * 128 + c0 + cl;
        Ahw[o] = __float22half2_rn(aA);
        Bhw[o] = __float22half2_rn(aB);
    }
}

// Z layout (half2): Z[om33][cc16][t16][h64][c8]  -> uint4 index:
//   (((om*16+cc)*16 + t)*64 + h)*2 + p   (p = c-half of 8 channels)
// Each pmid block owns one contiguous 32 KB chunk (om,cc).

// ------- pass 1: forward radix-8 FFT along W (real input) -> dense Z -------
// grid: t(16) x hq(16) x chalf(2) = 512 blocks, 512 threads.
__global__ __launch_bounds__(512) void p1(const float* __restrict__ x,
                                          uint4* __restrict__ Z) {
    __shared__ float rf[64][64];           // 16 KB plane (fp32), aliased half2 after stage 1
    __shared__ __half2 sp[4][33][64];      // 33.8 KB spectra staging
    __shared__ float2 tw64[64];
    __half2* zal = (__half2*)&rf[0][0];
    int bid = blockIdx.x;
    int t = bid >> 5, hq = (bid >> 1) & 15, chalf = bid & 1;
    int tid = threadIdx.x;
    if (tid < 64) {
        float s, cq; sincosf(-6.283185307179586f * tid / 64.0f, &s, &cq);
        tw64[tid] = make_float2(cq, s);
    }
    int c = tid & 63, s4 = tid >> 6;       // s4 in [0,8)
    for (int hh = 0; hh < 4; ++hh) {
        const float4* src4 = (const float4*)(x + (size_t)(t*64 + hq*4 + hh) * 64 * 128
                                               + chalf * 64);
        for (int i = tid; i < 1024; i += 512) {
            int w = i >> 4, c4 = (i & 15) * 4;
            float4 v = src4[w * 32 + (i & 15)];
            rf[w][c4] = v.x; rf[w][c4+1] = v.y; rf[w][c4+2] = v.z; rf[w][c4+3] = v.w;
        }
        __syncthreads();
        // stage 1 phase A: all fp32 reads to registers
        float ar[8];
        #pragma unroll
        for (int h1 = 0; h1 < 8; ++h1) ar[h1] = rf[h1*8 + s4][c];
        __syncthreads();
        // stage 1 phase B: dft8 + twiddle -> half2 alias in place
        {
            float2 a[8], Y[8];
            #pragma unroll
            for (int h1 = 0; h1 < 8; ++h1) a[h1] = make_float2(ar[h1], 0.f);
            dft8<-1>(a, Y);
            #pragma unroll
            for (int k0 = 0; k0 < 8; ++k0) {
                float2 z = cmul(Y[k0], tw64[(s4 * k0) & 63]);
                zal[(k0*8 + s4) * 64 + c] = __float22half2_rn(z);
            }
        }
        __syncthreads();
        // stage 2: k0 = s4, emit om<=32 into staging
        {
            float2 b[8], X[8];
            #pragma unroll
            for (int h0 = 0; h0 < 8; ++h0)
                b[h0] = __half22float2(zal[(s4*8 + h0) * 64 + c]);
            dft8<-1>(b, X);
            #pragma unroll
            for (int k1 = 0; k1 < 8; ++k1) {
                int om = s4 + 8 * k1;
                if (om <= 32) sp[hh][om][c] = __float22half2_rn(X[k1]);
            }
        }
        __syncthreads();
    }
    // dense write: 8 consecutive lanes emit one full 128B line (4h x 8c)
    for (int i = tid; i < 2112; i += 512) {
        int p = i & 1, hh = (i >> 1) & 3, jj = i >> 3;   // jj < 264
        int om = jj >> 3, ccl = jj & 7;
        int cb = ccl * 8 + p * 4;
        uint4 u;
        __half2 v0 = sp[hh][om][cb+0], v1 = sp[hh][om][cb+1];
        __half2 v2 = sp[hh][om][cb+2], v3 = sp[hh][om][cb+3];
        u.x = *(unsigned int*)&v0; u.y = *(unsigned int*)&v1;
        u.z = *(unsigned int*)&v2; u.w = *(unsigned int*)&v3;
        Z[(((size_t)(om*16 + chalf*8 + ccl)*16 + t)*64 + hq*4 + hh)*2 + p] = u;
    }
}

// ------- fused middle pass: H-FFT + T-FFT + G multiply + inv-T + inv-H, in place -------
// 256 threads (VGPR cap 128 -> no scratch spill), one block per (om,cc8):
// tile = contiguous 32 KB of Z.
__global__ __launch_bounds__(256, 4) void pmid(uint4* __restrict__ Z,
                                               const __half2* __restrict__ Ahw,
                                               const __half2* __restrict__ Bhw) {
    __shared__ __half2 tl[16][64][9];     // 36.9 KB, pad column -> <=2-way banks
    // XCD-chunked swizzle: 528 = 8*66 (bijective)
    int l = (blockIdx.x & 7) * 66 + (blockIdx.x >> 3);
    int om = l >> 4, cc = l & 15;
    int c0 = cc * 8;
    int tid = threadIdx.x;
    uint4* g = Z + (size_t)l * 2048;

    int d = tid & 7;
    float twc[8], tws[8];
    {
        float s1, c1; sincosf(-6.283185307179586f * d / 64.0f, &s1, &c1);
        twc[0] = 1.f; tws[0] = 0.f;
        #pragma unroll
        for (int k = 1; k < 8; ++k) {
            twc[k] = twc[k-1]*c1 - tws[k-1]*s1;
            tws[k] = twc[k-1]*s1 + tws[k-1]*c1;
        }
    }
    // load tile: fully contiguous 32 KB
    for (int i = tid; i < 2048; i += 256) {
        uint4 u = g[i];
        int t = i >> 7, h = (i >> 1) & 63, p = i & 1;
        tl[t][h][p*4+0] = *(__half2*)&u.x;
        tl[t][h][p*4+1] = *(__half2*)&u.y;
        tl[t][h][p*4+2] = *(__half2*)&u.z;
        tl[t][h][p*4+3] = *(__half2*)&u.w;
    }
    __syncthreads();
    int cl = (tid >> 3) & 7, ts = tid >> 6;          // ts in [0,4)
    // H forward stage 1: DFT8 over h1 at fixed h0=d, twiddle w^{-d*k0}
    #pragma unroll
    for (int q = 0; q < 4; ++q) {
        int t = ts*4 + q;
        float2 a[8], Y[8];
        #pragma unroll
        for (int h1 = 0; h1 < 8; ++h1)
            a[h1] = __half22float2(tl[t][h1*8 + d][cl]);
        dft8<-1>(a, Y);
        #pragma unroll
        for (int k0 = 0; k0 < 8; ++k0) {
            float2 z = make_float2(Y[k0].x*twc[k0] - Y[k0].y*tws[k0],
                                   Y[k0].x*tws[k0] + Y[k0].y*twc[k0]);
            tl[t][k0*8 + d][cl] = __float22half2_rn(z);
        }
    }
    __syncthreads();
    // H forward stage 2: DFT8 over h0 at fixed k0=d; row k0*8+k1 := bin k0+8*k1
    #pragma unroll
    for (int q = 0; q < 4; ++q) {
        int t = ts*4 + q;
        float2 a[8], Y[8];
        #pragma unroll
        for (int h0 = 0; h0 < 8; ++h0)
            a[h0] = __half22float2(tl[t][d*8 + h0][cl]);
        dft8<-1>(a, Y);
        #pragma unroll
        for (int k1 = 0; k1 < 8; ++k1)
            tl[t][d*8 + k1][cl] = __float22half2_rn(Y[k1]);
    }
    __syncthreads();
    // T phase: fwd dft16, G = S(A_f)*B_f multiply, inv dft16 (tables pre-permuted).
    // Two 32-row halves per thread; G loaded per half (L2-resident, coalesced).
    {
        const float CT16[16] = {1.f, 0.9238795325f, 0.7071067812f, 0.3826834324f, 0.f,
                                -0.3826834324f, -0.7071067812f, -0.9238795325f, -1.f,
                                -0.9238795325f, -0.7071067812f, -0.3826834324f, 0.f,
                                0.3826834324f, 0.7071067812f, 0.9238795325f};
        const float ST16[16] = {0.f, 0.3826834324f, 0.7071067812f, 0.9238795325f, 1.f,
                                0.9238795325f, 0.7071067812f, 0.3826834324f, 0.f,
                                -0.3826834324f, -0.7071067812f, -0.9238795325f, -1.f,
                                -0.9238795325f, -0.7071067812f, -0.3826834324f};
        int cg = tid & 7, rT0 = tid >> 3;            // rT0 in [0,32)
        const int PKT = 33 * 64 * 128;
        #pragma unroll
        for (int j = 0; j < 2; ++j) {
            int rT = rT0 + 32*j;
            int kb = (om * 64 + rT) * 128 + c0 + cg;
            float2 A0 = __half22float2(Ahw[kb]);
            float2 A1 = __half22float2(Ahw[kb + PKT]);
            float2 A2 = __half22float2(Ahw[kb + 2*PKT]);
            float2 B0 = __half22float2(Bhw[kb]);
            float2 B1 = __half22float2(Bhw[kb + PKT]);
            float2 B2 = __half22float2(Bhw[kb + 2*PKT]);
            float2 v[16], X[16];
            #pragma unroll
            for (int t = 0; t < 16; ++t) v[t] = __half22float2(tl[t][rT][cg]);
            dft16<-1>(v, X);
            #pragma unroll
            for (int ta = 0; ta < 16; ++ta) {
                float2 wv = make_float2(CT16[ta], -ST16[ta]);
                float2 wc = make_float2(CT16[ta],  ST16[ta]);
                float2 Af = A1; Af = cmac(Af, A0, wc); Af = cmac(Af, A2, wv);
                float2 Bf = B1; Bf = cmac(Bf, B0, wc); Bf = cmac(Bf, B2, wv);
                // S = sum_{k=0}^{7} Af^k = (1+Af)(1+Af^2)(1+Af^4)
                float2 A2q = csq(Af), A4q = csq(A2q);
                float2 S = cmul(make_float2(1.f+Af.x, Af.y), make_float2(1.f+A2q.x, A2q.y));
                S = cmul(S, make_float2(1.f+A4q.x, A4q.y));
                float2 G = cmul(S, Bf);
                X[ta] = cmul(X[ta], G);
            }
            dft16<1>(X, v);
            const float sc = 0.015625f;              // 1/64 fold
            #pragma unroll
            for (int t = 0; t < 16; ++t)
                tl[t][rT][cg] = __float22half2_rn(make_float2(v[t].x*sc, v[t].y*sc));
        }
    }
    __syncthreads();
    // inverse H stage 1: DFT8<+1> over eta1 at fixed eta0=d, twiddle w^{+d*h0}
    #pragma unroll
    for (int q = 0; q < 4; ++q) {
        int t = ts*4 + q;
        float2 a[8], Y[8];
        #pragma unroll
        for (int e1 = 0; e1 < 8; ++e1)
            a[e1] = __half22float2(tl[t][d*8 + e1][cl]);
        dft8<1>(a, Y);
        #pragma unroll
        for (int h0 = 0; h0 < 8; ++h0) {
            float2 z = make_float2( Y[h0].x*twc[h0] + Y[h0].y*tws[h0],
                                   -Y[h0].x*tws[h0] + Y[h0].y*twc[h0]);
            tl[t][d*8 + h0][cl] = __float22half2_rn(z);
        }
    }
    __syncthreads();
    // inverse H stage 2: DFT8<+1> over eta0 at fixed h0=d; out row d+8*h1 (natural h)
    #pragma unroll
    for (int q = 0; q < 4; ++q) {
        int t = ts*4 + q;
        float2 a[8], Y[8];
        #pragma unroll
        for (int e0 = 0; e0 < 8; ++e0)
            a[e0] = __half22float2(tl[t][e0*8 + d][cl]);
        dft8<1>(a, Y);
        #pragma unroll
        for (int h1 = 0; h1 < 8; ++h1)
            tl[t][d + 8*h1][cl] = __float22half2_rn(Y[h1]);
    }
    __syncthreads();
    // write back: full-line overwrite of the block-private chunk
    for (int i = tid; i < 2048; i += 256) {
        int t = i >> 7, h = (i >> 1) & 63, p = i & 1;
        uint4 u;
        __half2 v0 = tl[t][h][p*4+0], v1 = tl[t][h][p*4+1];
        __half2 v2 = tl[t][h][p*4+2], v3 = tl[t][h][p*4+3];
        u.x = *(unsigned int*)&v0; u.y = *(unsigned int*)&v1;
        u.z = *(unsigned int*)&v2; u.w = *(unsigned int*)&v3;
        g[i] = u;
    }
}

// ------- pass 5: dense Z read + Hermitian-expand + inverse W-FFT, real out -------
// grid: t(16) x hq(16) x chalf(2) = 512 blocks, 512 threads.
__global__ __launch_bounds__(512) void p5(const uint4* __restrict__ Z,
                                          float* __restrict__ out) {
    __shared__ __half2 sp[4][33][64];      // 33.8 KB
    __shared__ __half2 plane[64][64];      // 16 KB
    __shared__ float2 tw64[64];
    int bid = blockIdx.x;
    int t = bid >> 5, hq = (bid >> 1) & 15, chalf = bid & 1;
    int tid = threadIdx.x;
    if (tid < 64) {
        float s, cq; sincosf(6.283185307179586f * tid / 64.0f, &s, &cq);
        tw64[tid] = make_float2(cq, s);
    }
    // dense staging read (full 128B lines)
    for (int i = tid; i < 2112; i += 512) {
        int p = i & 1, hh = (i >> 1) & 3, jj = i >> 3;
        int om = jj >> 3, ccl = jj & 7;
        uint4 u = Z[(((size_t)(om*16 + chalf*8 + ccl)*16 + t)*64 + hq*4 + hh)*2 + p];
        int cb = ccl * 8 + p * 4;
        sp[hh][om][cb+0] = *(__half2*)&u.x;
        sp[hh][om][cb+1] = *(__half2*)&u.y;
        sp[hh][om][cb+2] = *(__half2*)&u.z;
        sp[hh][om][cb+3] = *(__half2*)&u.w;
    }
    __syncthreads();
    int c = tid & 63, s4 = tid >> 6;
    for (int hh = 0; hh < 4; ++hh) {
        // Hermitian expand into the 64-om plane
        for (int i = tid; i < 33 * 64; i += 512) {
            int om = i >> 6, cl = i & 63;
            __half2 v = sp[hh][om][cl];
            plane[om][cl] = v;
            if (om >= 1 && om <= 31) {
                __half2 m = v; m.y = __hneg(m.y);
                plane[64 - om][cl] = m;
            }
        }
        __syncthreads();
        // stage 1 phase A: reads to registers
        float2 ar[8];
        #pragma unroll
        for (int h1 = 0; h1 < 8; ++h1)
            ar[h1] = __half22float2(plane[h1*8 + s4][c]);
        __syncthreads();
        // stage 1 phase B: dft8 + twiddle, in place
        {
            float2 Y[8];
            dft8<1>(ar, Y);
            #pragma unroll
            for (int k0 = 0; k0 < 8; ++k0) {
                float2 z = cmul(Y[k0], tw64[(s4 * k0) & 63]);
                plane[k0*8 + s4][c] = __float22half2_rn(z);
            }
        }
        __syncthreads();
        // stage 2 + dense fp32 output
        {
            float2 b[8], X[8];
            #pragma unroll
            for (int h0 = 0; h0 < 8; ++h0)
                b[h0] = __half22float2(plane[s4*8 + h0][c]);
            dft8<1>(b, X);
            float* dst = out + (size_t)(t*64 + hq*4 + hh) * 64 * 128 + chalf * 64 + c;
            #pragma unroll
            for (int k1 = 0; k1 < 8; ++k1)
                dst[(size_t)(s4 + 8*k1) * 128] = X[k1].x * (1.0f / 1024.0f);
        }
        __syncthreads();
    }
}

extern "C" void kernel_launch(void* const* d_in, const int* in_sizes, int n_in,
                              void* d_out, int out_size, void* d_ws, size_t ws_size,
                              hipStream_t stream) {
    const float* x  = (const float*)d_in[0];
    const float* Ak = (const float*)d_in[1];
    const float* Bk = (const float*)d_in[2];
    float* out = (float*)d_out;

    // Z: 33*16*16*64*8 half2 = 17.3 MB (uint4-addressed); G tables after.
    uint4* Z = (uint4*)d_ws;
    __half2* Ahw = (__half2*)((char*)d_ws + (size_t)33*16*16*64*8*4);
    __half2* Bhw = Ahw + 3 * 33 * 64 * 128;

    hipLaunchKernelGGL(k_prep, dim3(198), dim3(256), 0, stream, Ak, Bk, Ahw, Bhw);
    hipLaunchKernelGGL(p1,     dim3(512), dim3(512), 0, stream, x, Z);
    hipLaunchKernelGGL(pmid,   dim3(528), dim3(256), 0, stream, Z, Ahw, Bhw);
    hipLaunchKernelGGL(p5,     dim3(512), dim3(512), 0, stream, Z, out);
}

// Round 10
// 71.281 us; speedup vs baseline: 1.5116x; 1.1691x over previous
//
#include <hip/hip_runtime.h>
#include <hip/hip_fp16.h>
#include <math.h>

#define TT 16
#define HH 64
#define WW 64
#define CC 128

__device__ __forceinline__ float2 cadd(float2 a, float2 b){ return make_float2(a.x+b.x, a.y+b.y); }
__device__ __forceinline__ float2 csub(float2 a, float2 b){ return make_float2(a.x-b.x, a.y-b.y); }
__device__ __forceinline__ float2 cmul(float2 a, float2 b) {
    return make_float2(a.x*b.x - a.y*b.y, a.x*b.y + a.y*b.x);
}
__device__ __forceinline__ float2 cmac(float2 acc, float2 a, float2 b) {
    acc.x = fmaf(a.x, b.x, fmaf(-a.y, b.y, acc.x));
    acc.y = fmaf(a.x, b.y, fmaf(a.y, b.x, acc.y));
    return acc;
}
__device__ __forceinline__ float2 csq(float2 a) {
    return make_float2(a.x*a.x - a.y*a.y, 2.f*a.x*a.y);
}

// ---------------- radix butterflies ----------------
template<int SGN>
__device__ __forceinline__ void dft4(float2 b0, float2 b1, float2 b2, float2 b3,
                                     float2& y0, float2& y1, float2& y2, float2& y3) {
    float2 e0 = cadd(b0, b2), e1 = csub(b0, b2);
    float2 o0 = cadd(b1, b3), o1 = csub(b1, b3);
    y0 = cadd(e0, o0); y2 = csub(e0, o0);
    float2 r = make_float2((float)(-SGN) * o1.y, (float)SGN * o1.x);
    y1 = cadd(e1, r); y3 = csub(e1, r);
}

template<int SGN>
__device__ __forceinline__ void dft8(const float2* a, float2* X) {
    const float C = 0.70710678118654752f;
    float2 E0,E1,E2,E3,O0,O1,O2,O3;
    dft4<SGN>(a[0],a[2],a[4],a[6], E0,E1,E2,E3);
    dft4<SGN>(a[1],a[3],a[5],a[7], O0,O1,O2,O3);
    float2 T1 = make_float2(C*(O1.x - (float)SGN*O1.y), C*((float)SGN*O1.x + O1.y));
    float2 T2 = make_float2((float)(-SGN)*O2.y, (float)SGN*O2.x);
    float2 T3 = make_float2(-C*(O3.x + (float)SGN*O3.y), C*((float)SGN*O3.x - O3.y));
    X[0]=cadd(E0,O0); X[4]=csub(E0,O0);
    X[1]=cadd(E1,T1); X[5]=csub(E1,T1);
    X[2]=cadd(E2,T2); X[6]=csub(E2,T2);
    X[3]=cadd(E3,T3); X[7]=csub(E3,T3);
}

template<int SGN>
__device__ __forceinline__ void dft16(const float2* v, float2* X) {
    const float ct[10] = {1.f, 0.92387953251f, 0.70710678119f, 0.38268343236f, 0.f,
                          0.f, -0.70710678119f, 0.f, 0.f, -0.92387953251f};
    const float st[10] = {0.f, 0.38268343236f, 0.70710678119f, 0.92387953251f, 1.f,
                          0.f, 0.70710678119f, 0.f, 0.f, -0.38268343236f};
    float2 Z[16];
    #pragma unroll
    for (int h0 = 0; h0 < 4; ++h0) {
        float2 y0,y1,y2,y3;
        dft4<SGN>(v[h0], v[4+h0], v[8+h0], v[12+h0], y0,y1,y2,y3);
        float2 ys[4] = {y0,y1,y2,y3};
        #pragma unroll
        for (int k0 = 0; k0 < 4; ++k0) {
            int m = h0 * k0;
            float cc = ct[m], ss = (float)SGN * st[m];
            Z[k0*4 + h0] = make_float2(ys[k0].x*cc - ys[k0].y*ss,
                                       ys[k0].x*ss + ys[k0].y*cc);
        }
    }
    #pragma unroll
    for (int k0 = 0; k0 < 4; ++k0) {
        float2 y0,y1,y2,y3;
        dft4<SGN>(Z[k0*4+0], Z[k0*4+1], Z[k0*4+2], Z[k0*4+3], y0,y1,y2,y3);
        X[k0] = y0; X[k0+4] = y1; X[k0+8] = y2; X[k0+12] = y3;
    }
}

// ---------------- fused kernel prep: tanh + kw-DFT + kh-DFT, half2 out ----------------
__global__ __launch_bounds__(256) void k_prep(const float* __restrict__ Ak,
                                              const float* __restrict__ Bk,
                                              __half2* __restrict__ Ahw,
                                              __half2* __restrict__ Bhw) {
    __shared__ float Asl[7][7][64];
    __shared__ float Bsl[7][7][64];
    __shared__ float2 Awl[7][64];
    __shared__ float2 Bwl[7][64];
    __shared__ float2 tw64[64];
    int bid = blockIdx.x;
    int kt = bid / 66;
    int rem = bid % 66;
    int om = rem >> 1, chalf = rem & 1;
    int c0 = chalf * 64;
    int tid = threadIdx.x;
    for (int i = tid; i < 64; i += 256) {
        float s, cq; sincosf(-6.283185307179586f * i / 64.0f, &s, &cq);
        tw64[i] = make_float2(cq, s);
    }
    for (int i = tid; i < 49 * 64; i += 256) {
        int p = i >> 6, cl = i & 63;
        int kh = p / 7, kw = p % 7;
        int idx = (((c0 + cl) * 3 + kt) * 7 + kh) * 7 + kw;
        Asl[kh][kw][cl] = 0.9f * tanhf(Ak[idx]);
        Bsl[kh][kw][cl] = Bk[idx];
    }
    __syncthreads();
    for (int i = tid; i < 7 * 64; i += 256) {
        int kh = i >> 6, cl = i & 63;
        float2 aA = make_float2(0.f,0.f), aB = make_float2(0.f,0.f);
        #pragma unroll
        for (int kw = 0; kw < 7; ++kw) {
            float2 t = tw64[(om * (kw - 3)) & 63];
            float va = Asl[kh][kw][cl], vb = Bsl[kh][kw][cl];
            aA.x = fmaf(va, t.x, aA.x); aA.y = fmaf(va, t.y, aA.y);
            aB.x = fmaf(vb, t.x, aB.x); aB.y = fmaf(vb, t.y, aB.y);
        }
        Awl[kh][cl] = aA; Bwl[kh][cl] = aB;
    }
    __syncthreads();
    for (int i = tid; i < 64 * 64; i += 256) {
        int eta = i >> 6, cl = i & 63;
        float2 aA = make_float2(0.f,0.f), aB = make_float2(0.f,0.f);
        #pragma unroll
        for (int kh = 0; kh < 7; ++kh) {
            float2 t = tw64[(eta * (kh - 3)) & 63];
            aA = cmac(aA, Awl[kh][cl], t);
            aB = cmac(aB, Bwl[kh][cl], t);
        }
        int ep = ((eta & 7) << 3) | (eta >> 3);      // digit-swapped eta position
        int o = ((kt * 33 + om) * 64 + ep) * 128 + c0 + cl;
        Ahw[o] = __float22half2_rn(aA);
        Bhw[o] = __float22half2_rn(aB);
    }
}

// Z layout (half2): Z[om33][cc16][t16][h64][c8]  -> uint4 index:
//   (((om*16+cc)*16 + t)*64 + h)*2 + p   (p = c-half of 8 channels)
// Each pmid block owns one contiguous 32 KB chunk (om,cc).

// ------- pass 1: forward radix-8 FFT along W (real input) -> dense Z -------
// grid: t(16) x hq(16) x chalf(2) = 512 blocks, 512 threads.
__global__ __launch_bounds__(512) void p1(const float* __restrict__ x,
                                          uint4* __restrict__ Z) {
    __shared__ float rf[64][64];           // 16 KB plane (fp32), aliased half2 after stage 1
    __shared__ __half2 sp[4][33][64];      // 33.8 KB spectra staging
    __shared__ float2 tw64[64];
    __half2* zal = (__half2*)&rf[0][0];
    int bid = blockIdx.x;
    int t = bid >> 5, hq = (bid >> 1) & 15, chalf = bid & 1;
    int tid = threadIdx.x;
    if (tid < 64) {
        float s, cq; sincosf(-6.283185307179586f * tid / 64.0f, &s, &cq);
        tw64[tid] = make_float2(cq, s);
    }
    int c = tid & 63, s4 = tid >> 6;       // s4 in [0,8)
    for (int hh = 0; hh < 4; ++hh) {
        const float4* src4 = (const float4*)(x + (size_t)(t*64 + hq*4 + hh) * 64 * 128
                                               + chalf * 64);
        for (int i = tid; i < 1024; i += 512) {
            int w = i >> 4, c4 = (i & 15) * 4;
            float4 v = src4[w * 32 + (i & 15)];
            rf[w][c4] = v.x; rf[w][c4+1] = v.y; rf[w][c4+2] = v.z; rf[w][c4+3] = v.w;
        }
        __syncthreads();
        // stage 1 phase A: all fp32 reads to registers
        float ar[8];
        #pragma unroll
        for (int h1 = 0; h1 < 8; ++h1) ar[h1] = rf[h1*8 + s4][c];
        __syncthreads();
        // stage 1 phase B: dft8 + twiddle -> half2 alias in place
        {
            float2 a[8], Y[8];
            #pragma unroll
            for (int h1 = 0; h1 < 8; ++h1) a[h1] = make_float2(ar[h1], 0.f);
            dft8<-1>(a, Y);
            #pragma unroll
            for (int k0 = 0; k0 < 8; ++k0) {
                float2 z = cmul(Y[k0], tw64[(s4 * k0) & 63]);
                zal[(k0*8 + s4) * 64 + c] = __float22half2_rn(z);
            }
        }
        __syncthreads();
        // stage 2: k0 = s4, emit om<=32 into staging
        {
            float2 b[8], X[8];
            #pragma unroll
            for (int h0 = 0; h0 < 8; ++h0)
                b[h0] = __half22float2(zal[(s4*8 + h0) * 64 + c]);
            dft8<-1>(b, X);
            #pragma unroll
            for (int k1 = 0; k1 < 8; ++k1) {
                int om = s4 + 8 * k1;
                if (om <= 32) sp[hh][om][c] = __float22half2_rn(X[k1]);
            }
        }
        __syncthreads();
    }
    // dense write: 8 consecutive lanes emit one full 128B line (4h x 8c)
    for (int i = tid; i < 2112; i += 512) {
        int p = i & 1, hh = (i >> 1) & 3, jj = i >> 3;   // jj < 264
        int om = jj >> 3, ccl = jj & 7;
        int cb = ccl * 8 + p * 4;
        uint4 u;
        __half2 v0 = sp[hh][om][cb+0], v1 = sp[hh][om][cb+1];
        __half2 v2 = sp[hh][om][cb+2], v3 = sp[hh][om][cb+3];
        u.x = *(unsigned int*)&v0; u.y = *(unsigned int*)&v1;
        u.z = *(unsigned int*)&v2; u.w = *(unsigned int*)&v3;
        Z[(((size_t)(om*16 + chalf*8 + ccl)*16 + t)*64 + hq*4 + hh)*2 + p] = u;
    }
}

// ------- fused middle pass: H-FFT + T-FFT + G multiply + inv-T + inv-H, in place -------
// 256 threads, PLAIN __launch_bounds__(256): no min-waves arg -> compiler free to use
// ~124 VGPR (r3 evidence) -> no scratch spill of the T-phase v[16]/X[16].
__global__ __launch_bounds__(256) void pmid(uint4* __restrict__ Z,
                                            const __half2* __restrict__ Ahw,
                                            const __half2* __restrict__ Bhw) {
    __shared__ __half2 tl[16][64][9];     // 36.9 KB, pad column -> <=2-way banks
    // XCD-chunked swizzle: 528 = 8*66 (bijective)
    int l = (blockIdx.x & 7) * 66 + (blockIdx.x >> 3);
    int om = l >> 4, cc = l & 15;
    int c0 = cc * 8;
    int tid = threadIdx.x;
    uint4* g = Z + (size_t)l * 2048;

    int d = tid & 7;
    float twc[8], tws[8];
    {
        float s1, c1; sincosf(-6.283185307179586f * d / 64.0f, &s1, &c1);
        twc[0] = 1.f; tws[0] = 0.f;
        #pragma unroll
        for (int k = 1; k < 8; ++k) {
            twc[k] = twc[k-1]*c1 - tws[k-1]*s1;
            tws[k] = twc[k-1]*s1 + tws[k-1]*c1;
        }
    }
    // load tile: fully contiguous 32 KB
    for (int i = tid; i < 2048; i += 256) {
        uint4 u = g[i];
        int t = i >> 7, h = (i >> 1) & 63, p = i & 1;
        tl[t][h][p*4+0] = *(__half2*)&u.x;
        tl[t][h][p*4+1] = *(__half2*)&u.y;
        tl[t][h][p*4+2] = *(__half2*)&u.z;
        tl[t][h][p*4+3] = *(__half2*)&u.w;
    }
    __syncthreads();
    int cl = (tid >> 3) & 7, ts = tid >> 6;          // ts in [0,4)
    // H forward stage 1: DFT8 over h1 at fixed h0=d, twiddle w^{-d*k0}
    #pragma unroll
    for (int q = 0; q < 4; ++q) {
        int t = ts*4 + q;
        float2 a[8], Y[8];
        #pragma unroll
        for (int h1 = 0; h1 < 8; ++h1)
            a[h1] = __half22float2(tl[t][h1*8 + d][cl]);
        dft8<-1>(a, Y);
        #pragma unroll
        for (int k0 = 0; k0 < 8; ++k0) {
            float2 z = make_float2(Y[k0].x*twc[k0] - Y[k0].y*tws[k0],
                                   Y[k0].x*tws[k0] + Y[k0].y*twc[k0]);
            tl[t][k0*8 + d][cl] = __float22half2_rn(z);
        }
    }
    __syncthreads();
    // H forward stage 2: DFT8 over h0 at fixed k0=d; row k0*8+k1 := bin k0+8*k1
    #pragma unroll
    for (int q = 0; q < 4; ++q) {
        int t = ts*4 + q;
        float2 a[8], Y[8];
        #pragma unroll
        for (int h0 = 0; h0 < 8; ++h0)
            a[h0] = __half22float2(tl[t][d*8 + h0][cl]);
        dft8<-1>(a, Y);
        #pragma unroll
        for (int k1 = 0; k1 < 8; ++k1)
            tl[t][d*8 + k1][cl] = __float22half2_rn(Y[k1]);
    }
    __syncthreads();
    // T phase: fwd dft16, G = S(A_f)*B_f multiply, inv dft16 (tables pre-permuted).
    // Two 32-row halves per thread; G loaded per half (L2-resident, coalesced).
    {
        const float CT16[16] = {1.f, 0.9238795325f, 0.7071067812f, 0.3826834324f, 0.f,
                                -0.3826834324f, -0.7071067812f, -0.9238795325f, -1.f,
                                -0.9238795325f, -0.7071067812f, -0.3826834324f, 0.f,
                                0.3826834324f, 0.7071067812f, 0.9238795325f};
        const float ST16[16] = {0.f, 0.3826834324f, 0.7071067812f, 0.9238795325f, 1.f,
                                0.9238795325f, 0.7071067812f, 0.3826834324f, 0.f,
                                -0.3826834324f, -0.7071067812f, -0.9238795325f, -1.f,
                                -0.9238795325f, -0.7071067812f, -0.3826834324f};
        int cg = tid & 7, rT0 = tid >> 3;            // rT0 in [0,32)
        const int PKT = 33 * 64 * 128;
        #pragma unroll
        for (int j = 0; j < 2; ++j) {
            int rT = rT0 + 32*j;
            int kb = (om * 64 + rT) * 128 + c0 + cg;
            float2 A0 = __half22float2(Ahw[kb]);
            float2 A1 = __half22float2(Ahw[kb + PKT]);
            float2 A2 = __half22float2(Ahw[kb + 2*PKT]);
            float2 B0 = __half22float2(Bhw[kb]);
            float2 B1 = __half22float2(Bhw[kb + PKT]);
            float2 B2 = __half22float2(Bhw[kb + 2*PKT]);
            float2 v[16], X[16];
            #pragma unroll
            for (int t = 0; t < 16; ++t) v[t] = __half22float2(tl[t][rT][cg]);
            dft16<-1>(v, X);
            #pragma unroll
            for (int ta = 0; ta < 16; ++ta) {
                float2 wv = make_float2(CT16[ta], -ST16[ta]);
                float2 wc = make_float2(CT16[ta],  ST16[ta]);
                float2 Af = A1; Af = cmac(Af, A0, wc); Af = cmac(Af, A2, wv);
                float2 Bf = B1; Bf = cmac(Bf, B0, wc); Bf = cmac(Bf, B2, wv);
                // S = sum_{k=0}^{7} Af^k = (1+Af)(1+Af^2)(1+Af^4)
                float2 A2q = csq(Af), A4q = csq(A2q);
                float2 S = cmul(make_float2(1.f+Af.x, Af.y), make_float2(1.f+A2q.x, A2q.y));
                S = cmul(S, make_float2(1.f+A4q.x, A4q.y));
                float2 G = cmul(S, Bf);
                X[ta] = cmul(X[ta], G);
            }
            dft16<1>(X, v);
            const float sc = 0.015625f;              // 1/64 fold
            #pragma unroll
            for (int t = 0; t < 16; ++t)
                tl[t][rT][cg] = __float22half2_rn(make_float2(v[t].x*sc, v[t].y*sc));
        }
    }
    __syncthreads();
    // inverse H stage 1: DFT8<+1> over eta1 at fixed eta0=d, twiddle w^{+d*h0}
    #pragma unroll
    for (int q = 0; q < 4; ++q) {
        int t = ts*4 + q;
        float2 a[8], Y[8];
        #pragma unroll
        for (int e1 = 0; e1 < 8; ++e1)
            a[e1] = __half22float2(tl[t][d*8 + e1][cl]);
        dft8<1>(a, Y);
        #pragma unroll
        for (int h0 = 0; h0 < 8; ++h0) {
            float2 z = make_float2( Y[h0].x*twc[h0] + Y[h0].y*tws[h0],
                                   -Y[h0].x*tws[h0] + Y[h0].y*twc[h0]);
            tl[t][d*8 + h0][cl] = __float22half2_rn(z);
        }
    }
    __syncthreads();
    // inverse H stage 2: DFT8<+1> over eta0 at fixed h0=d; out row d+8*h1 (natural h)
    #pragma unroll
    for (int q = 0; q < 4; ++q) {
        int t = ts*4 + q;
        float2 a[8], Y[8];
        #pragma unroll
        for (int e0 = 0; e0 < 8; ++e0)
            a[e0] = __half22float2(tl[t][e0*8 + d][cl]);
        dft8<1>(a, Y);
        #pragma unroll
        for (int h1 = 0; h1 < 8; ++h1)
            tl[t][d + 8*h1][cl] = __float22half2_rn(Y[h1]);
    }
    __syncthreads();
    // write back: full-line overwrite of the block-private chunk
    for (int i = tid; i < 2048; i += 256) {
        int t = i >> 7, h = (i >> 1) & 63, p = i & 1;
        uint4 u;
        __half2 v0 = tl[t][h][p*4+0], v1 = tl[t][h][p*4+1];
        __half2 v2 = tl[t][h][p*4+2], v3 = tl[t][h][p*4+3];
        u.x = *(unsigned int*)&v0; u.y = *(unsigned int*)&v1;
        u.z = *(unsigned int*)&v2; u.w = *(unsigned int*)&v3;
        g[i] = u;
    }
}

// ------- pass 5: dense Z read + Hermitian-expand + inverse W-FFT, real out -------
// grid: t(16) x hq(16) x chalf(2) = 512 blocks, 512 threads.
__global__ __launch_bounds__(512) void p5(const uint4* __restrict__ Z,
                                          float* __restrict__ out) {
    __shared__ __half2 sp[4][33][64];      // 33.8 KB
    __shared__ __half2 plane[64][64];      // 16 KB
    __shared__ float2 tw64[64];
    int bid = blockIdx.x;
    int t = bid >> 5, hq = (bid >> 1) & 15, chalf = bid & 1;
    int tid = threadIdx.x;
    if (tid < 64) {
        float s, cq; sincosf(6.283185307179586f * tid / 64.0f, &s, &cq);
        tw64[tid] = make_float2(cq, s);
    }
    // dense staging read (full 128B lines)
    for (int i = tid; i < 2112; i += 512) {
        int p = i & 1, hh = (i >> 1) & 3, jj = i >> 3;
        int om = jj >> 3, ccl = jj & 7;
        uint4 u = Z[(((size_t)(om*16 + chalf*8 + ccl)*16 + t)*64 + hq*4 + hh)*2 + p];
        int cb = ccl * 8 + p * 4;
        sp[hh][om][cb+0] = *(__half2*)&u.x;
        sp[hh][om][cb+1] = *(__half2*)&u.y;
        sp[hh][om][cb+2] = *(__half2*)&u.z;
        sp[hh][om][cb+3] = *(__half2*)&u.w;
    }
    __syncthreads();
    int c = tid & 63, s4 = tid >> 6;
    for (int hh = 0; hh < 4; ++hh) {
        // Hermitian expand into the 64-om plane
        for (int i = tid; i < 33 * 64; i += 512) {
            int om = i >> 6, cl = i & 63;
            __half2 v = sp[hh][om][cl];
            plane[om][cl] = v;
            if (om >= 1 && om <= 31) {
                __half2 m = v; m.y = __hneg(m.y);
                plane[64 - om][cl] = m;
            }
        }
        __syncthreads();
        // stage 1 phase A: reads to registers
        float2 ar[8];
        #pragma unroll
        for (int h1 = 0; h1 < 8; ++h1)
            ar[h1] = __half22float2(plane[h1*8 + s4][c]);
        __syncthreads();
        // stage 1 phase B: dft8 + twiddle, in place
        {
            float2 Y[8];
            dft8<1>(ar, Y);
            #pragma unroll
            for (int k0 = 0; k0 < 8; ++k0) {
                float2 z = cmul(Y[k0], tw64[(s4 * k0) & 63]);
                plane[k0*8 + s4][c] = __float22half2_rn(z);
            }
        }
        __syncthreads();
        // stage 2 + dense fp32 output
        {
            float2 b[8], X[8];
            #pragma unroll
            for (int h0 = 0; h0 < 8; ++h0)
                b[h0] = __half22float2(plane[s4*8 + h0][c]);
            dft8<1>(b, X);
            float* dst = out + (size_t)(t*64 + hq*4 + hh) * 64 * 128 + chalf * 64 + c;
            #pragma unroll
            for (int k1 = 0; k1 < 8; ++k1)
                dst[(size_t)(s4 + 8*k1) * 128] = X[k1].x * (1.0f / 1024.0f);
        }
        __syncthreads();
    }
}

extern "C" void kernel_launch(void* const* d_in, const int* in_sizes, int n_in,
                              void* d_out, int out_size, void* d_ws, size_t ws_size,
                              hipStream_t stream) {
    const float* x  = (const float*)d_in[0];
    const float* Ak = (const float*)d_in[1];
    const float* Bk = (const float*)d_in[2];
    float* out = (float*)d_out;

    // Z: 33*16*16*64*8 half2 = 17.3 MB (uint4-addressed); G tables after.
    uint4* Z = (uint4*)d_ws;
    __half2* Ahw = (__half2*)((char*)d_ws + (size_t)33*16*16*64*8*4);
    __half2* Bhw = Ahw + 3 * 33 * 64 * 128;

    hipLaunchKernelGGL(k_prep, dim3(198), dim3(256), 0, stream, Ak, Bk, Ahw, Bhw);
    hipLaunchKernelGGL(p1,     dim3(512), dim3(512), 0, stream, x, Z);
    hipLaunchKernelGGL(pmid,   dim3(528), dim3(256), 0, stream, Z, Ahw, Bhw);
    hipLaunchKernelGGL(p5,     dim3(512), dim3(512), 0, stream, Z, out);
}

// Round 11
// 68.665 us; speedup vs baseline: 1.5692x; 1.0381x over previous
//
#include <hip/hip_runtime.h>
#include <hip/hip_fp16.h>
#include <math.h>

#define TT 16
#define HH 64
#define WW 64
#define CC 128

// XOR digit swizzle: row r = hi*8+lo -> hi*8 + (lo^hi). Makes both stride-8 and
// block-8 row accesses hit distinct banks in the narrow [.,64][4] half2 tile.
#define LROW(r) (((r) & 0x38) | ((((r) >> 3) ^ (r)) & 7))

__device__ __forceinline__ float2 cadd(float2 a, float2 b){ return make_float2(a.x+b.x, a.y+b.y); }
__device__ __forceinline__ float2 csub(float2 a, float2 b){ return make_float2(a.x-b.x, a.y-b.y); }
__device__ __forceinline__ float2 cmul(float2 a, float2 b) {
    return make_float2(a.x*b.x - a.y*b.y, a.x*b.y + a.y*b.x);
}
__device__ __forceinline__ float2 cmac(float2 acc, float2 a, float2 b) {
    acc.x = fmaf(a.x, b.x, fmaf(-a.y, b.y, acc.x));
    acc.y = fmaf(a.x, b.y, fmaf(a.y, b.x, acc.y));
    return acc;
}
__device__ __forceinline__ float2 csq(float2 a) {
    return make_float2(a.x*a.x - a.y*a.y, 2.f*a.x*a.y);
}

// ---------------- radix butterflies ----------------
template<int SGN>
__device__ __forceinline__ void dft4(float2 b0, float2 b1, float2 b2, float2 b3,
                                     float2& y0, float2& y1, float2& y2, float2& y3) {
    float2 e0 = cadd(b0, b2), e1 = csub(b0, b2);
    float2 o0 = cadd(b1, b3), o1 = csub(b1, b3);
    y0 = cadd(e0, o0); y2 = csub(e0, o0);
    float2 r = make_float2((float)(-SGN) * o1.y, (float)SGN * o1.x);
    y1 = cadd(e1, r); y3 = csub(e1, r);
}

template<int SGN>
__device__ __forceinline__ void dft8(const float2* a, float2* X) {
    const float C = 0.70710678118654752f;
    float2 E0,E1,E2,E3,O0,O1,O2,O3;
    dft4<SGN>(a[0],a[2],a[4],a[6], E0,E1,E2,E3);
    dft4<SGN>(a[1],a[3],a[5],a[7], O0,O1,O2,O3);
    float2 T1 = make_float2(C*(O1.x - (float)SGN*O1.y), C*((float)SGN*O1.x + O1.y));
    float2 T2 = make_float2((float)(-SGN)*O2.y, (float)SGN*O2.x);
    float2 T3 = make_float2(-C*(O3.x + (float)SGN*O3.y), C*((float)SGN*O3.x - O3.y));
    X[0]=cadd(E0,O0); X[4]=csub(E0,O0);
    X[1]=cadd(E1,T1); X[5]=csub(E1,T1);
    X[2]=cadd(E2,T2); X[6]=csub(E2,T2);
    X[3]=cadd(E3,T3); X[7]=csub(E3,T3);
}

template<int SGN>
__device__ __forceinline__ void dft16(const float2* v, float2* X) {
    const float ct[10] = {1.f, 0.92387953251f, 0.70710678119f, 0.38268343236f, 0.f,
                          0.f, -0.70710678119f, 0.f, 0.f, -0.92387953251f};
    const float st[10] = {0.f, 0.38268343236f, 0.70710678119f, 0.92387953251f, 1.f,
                          0.f, 0.70710678119f, 0.f, 0.f, -0.38268343236f};
    float2 Z[16];
    #pragma unroll
    for (int h0 = 0; h0 < 4; ++h0) {
        float2 y0,y1,y2,y3;
        dft4<SGN>(v[h0], v[4+h0], v[8+h0], v[12+h0], y0,y1,y2,y3);
        float2 ys[4] = {y0,y1,y2,y3};
        #pragma unroll
        for (int k0 = 0; k0 < 4; ++k0) {
            int m = h0 * k0;
            float cc = ct[m], ss = (float)SGN * st[m];
            Z[k0*4 + h0] = make_float2(ys[k0].x*cc - ys[k0].y*ss,
                                       ys[k0].x*ss + ys[k0].y*cc);
        }
    }
    #pragma unroll
    for (int k0 = 0; k0 < 4; ++k0) {
        float2 y0,y1,y2,y3;
        dft4<SGN>(Z[k0*4+0], Z[k0*4+1], Z[k0*4+2], Z[k0*4+3], y0,y1,y2,y3);
        X[k0] = y0; X[k0+4] = y1; X[k0+8] = y2; X[k0+12] = y3;
    }
}

// ---------------- fused kernel prep: tanh + kw-DFT + kh-DFT, half2 out ----------------
__global__ __launch_bounds__(256) void k_prep(const float* __restrict__ Ak,
                                              const float* __restrict__ Bk,
                                              __half2* __restrict__ Ahw,
                                              __half2* __restrict__ Bhw) {
    __shared__ float Asl[7][7][64];
    __shared__ float Bsl[7][7][64];
    __shared__ float2 Awl[7][64];
    __shared__ float2 Bwl[7][64];
    __shared__ float2 tw64[64];
    int bid = blockIdx.x;
    int kt = bid / 66;
    int rem = bid % 66;
    int om = rem >> 1, chalf = rem & 1;
    int c0 = chalf * 64;
    int tid = threadIdx.x;
    for (int i = tid; i < 64; i += 256) {
        float s, cq; sincosf(-6.283185307179586f * i / 64.0f, &s, &cq);
        tw64[i] = make_float2(cq, s);
    }
    for (int i = tid; i < 49 * 64; i += 256) {
        int p = i >> 6, cl = i & 63;
        int kh = p / 7, kw = p % 7;
        int idx = (((c0 + cl) * 3 + kt) * 7 + kh) * 7 + kw;
        Asl[kh][kw][cl] = 0.9f * tanhf(Ak[idx]);
        Bsl[kh][kw][cl] = Bk[idx];
    }
    __syncthreads();
    for (int i = tid; i < 7 * 64; i += 256) {
        int kh = i >> 6, cl = i & 63;
        float2 aA = make_float2(0.f,0.f), aB = make_float2(0.f,0.f);
        #pragma unroll
        for (int kw = 0; kw < 7; ++kw) {
            float2 t = tw64[(om * (kw - 3)) & 63];
            float va = Asl[kh][kw][cl], vb = Bsl[kh][kw][cl];
            aA.x = fmaf(va, t.x, aA.x); aA.y = fmaf(va, t.y, aA.y);
            aB.x = fmaf(vb, t.x, aB.x); aB.y = fmaf(vb, t.y, aB.y);
        }
        Awl[kh][cl] = aA; Bwl[kh][cl] = aB;
    }
    __syncthreads();
    for (int i = tid; i < 64 * 64; i += 256) {
        int eta = i >> 6, cl = i & 63;
        float2 aA = make_float2(0.f,0.f), aB = make_float2(0.f,0.f);
        #pragma unroll
        for (int kh = 0; kh < 7; ++kh) {
            float2 t = tw64[(eta * (kh - 3)) & 63];
            aA = cmac(aA, Awl[kh][cl], t);
            aB = cmac(aB, Bwl[kh][cl], t);
        }
        int ep = ((eta & 7) << 3) | (eta >> 3);      // digit-swapped eta position
        int o = ((kt * 33 + om) * 64 + ep) * 128 + c0 + cl;
        Ahw[o] = __float22half2_rn(aA);
        Bhw[o] = __float22half2_rn(aB);
    }
}

// Z layout (uint4 = 4 half2 = 4 channels): index ((om*32 + cc)*16 + t)*64 + h,
// cc in [0,32) = chalf*16 + ccl. Each pmid block owns one contiguous 16 KB chunk.

// ------- pass 1: forward radix-8 FFT along W (real input) -> dense Z -------
// grid: t(16) x hq(16) x chalf(2) = 512 blocks, 512 threads.
__global__ __launch_bounds__(512) void p1(const float* __restrict__ x,
                                          uint4* __restrict__ Z) {
    __shared__ float rf[64][64];           // 16 KB plane (fp32), aliased half2 after stage 1
    __shared__ __half2 sp[4][33][64];      // 33.8 KB spectra staging
    __shared__ float2 tw64[64];
    __half2* zal = (__half2*)&rf[0][0];
    int bid = blockIdx.x;
    int t = bid >> 5, hq = (bid >> 1) & 15, chalf = bid & 1;
    int tid = threadIdx.x;
    if (tid < 64) {
        float s, cq; sincosf(-6.283185307179586f * tid / 64.0f, &s, &cq);
        tw64[tid] = make_float2(cq, s);
    }
    int c = tid & 63, s4 = tid >> 6;       // s4 in [0,8)
    for (int hh = 0; hh < 4; ++hh) {
        const float4* src4 = (const float4*)(x + (size_t)(t*64 + hq*4 + hh) * 64 * 128
                                               + chalf * 64);
        for (int i = tid; i < 1024; i += 512) {
            int w = i >> 4, c4 = (i & 15) * 4;
            float4 v = src4[w * 32 + (i & 15)];
            rf[w][c4] = v.x; rf[w][c4+1] = v.y; rf[w][c4+2] = v.z; rf[w][c4+3] = v.w;
        }
        __syncthreads();
        // stage 1 phase A: all fp32 reads to registers
        float ar[8];
        #pragma unroll
        for (int h1 = 0; h1 < 8; ++h1) ar[h1] = rf[h1*8 + s4][c];
        __syncthreads();
        // stage 1 phase B: dft8 + twiddle -> half2 alias in place
        {
            float2 a[8], Y[8];
            #pragma unroll
            for (int h1 = 0; h1 < 8; ++h1) a[h1] = make_float2(ar[h1], 0.f);
            dft8<-1>(a, Y);
            #pragma unroll
            for (int k0 = 0; k0 < 8; ++k0) {
                float2 z = cmul(Y[k0], tw64[(s4 * k0) & 63]);
                zal[(k0*8 + s4) * 64 + c] = __float22half2_rn(z);
            }
        }
        __syncthreads();
        // stage 2: k0 = s4, emit om<=32 into staging
        {
            float2 b[8], X[8];
            #pragma unroll
            for (int h0 = 0; h0 < 8; ++h0)
                b[h0] = __half22float2(zal[(s4*8 + h0) * 64 + c]);
            dft8<-1>(b, X);
            #pragma unroll
            for (int k1 = 0; k1 < 8; ++k1) {
                int om = s4 + 8 * k1;
                if (om <= 32) sp[hh][om][c] = __float22half2_rn(X[k1]);
            }
        }
        __syncthreads();
    }
    // dense write: 4 consecutive lanes emit one aligned 64-B segment (4h x 4c)
    for (int i = tid; i < 2112; i += 512) {
        int hh = i & 3, ccl = (i >> 2) & 15, om = i >> 6;
        int cb = ccl * 4;
        uint4 u;
        __half2 v0 = sp[hh][om][cb+0], v1 = sp[hh][om][cb+1];
        __half2 v2 = sp[hh][om][cb+2], v3 = sp[hh][om][cb+3];
        u.x = *(unsigned int*)&v0; u.y = *(unsigned int*)&v1;
        u.z = *(unsigned int*)&v2; u.w = *(unsigned int*)&v3;
        Z[(((size_t)(om*32 + chalf*16 + ccl)*16 + t)*64 + hq*4 + hh)] = u;
    }
}

// ------- fused middle pass: H-FFT + T-FFT + G multiply + inv-T + inv-H, in place -------
// 1056 blocks (om33 x cc32) x 256 threads, plain launch_bounds (no spill).
// 16 KB LDS tile with LROW swizzle -> <=2-way banks; 16 KB contiguous global chunk.
__global__ __launch_bounds__(256) void pmid(uint4* __restrict__ Z,
                                            const __half2* __restrict__ Ahw,
                                            const __half2* __restrict__ Bhw) {
    __shared__ __half2 tl[16][64][4];     // 16 KB
    // XCD-chunked swizzle: 1056 = 8*132 (bijective)
    int l = (blockIdx.x & 7) * 132 + (blockIdx.x >> 3);
    int om = l >> 5, cc = l & 31;
    int c0 = cc * 4;                       // half2-channel base within 128
    int tid = threadIdx.x;
    uint4* g = Z + (size_t)l * 1024;

    int d = tid & 7;
    float twc[8], tws[8];
    {
        float s1, c1; sincosf(-6.283185307179586f * d / 64.0f, &s1, &c1);
        twc[0] = 1.f; tws[0] = 0.f;
        #pragma unroll
        for (int k = 1; k < 8; ++k) {
            twc[k] = twc[k-1]*c1 - tws[k-1]*s1;
            tws[k] = twc[k-1]*s1 + tws[k-1]*c1;
        }
    }
    // load: contiguous 16 KB
    for (int i = tid; i < 1024; i += 256) {
        uint4 u = g[i];
        int t = i >> 6, h = i & 63;
        int pr = LROW(h);
        tl[t][pr][0] = *(__half2*)&u.x;
        tl[t][pr][1] = *(__half2*)&u.y;
        tl[t][pr][2] = *(__half2*)&u.z;
        tl[t][pr][3] = *(__half2*)&u.w;
    }
    __syncthreads();
    int cl = (tid >> 3) & 3, ts = tid >> 5;          // ts in [0,8)
    // H forward stage 1: DFT8 over h1 at fixed h0=d, twiddle w^{-d*k0}
    #pragma unroll
    for (int q = 0; q < 2; ++q) {
        int t = ts*2 + q;
        float2 a[8], Y[8];
        #pragma unroll
        for (int h1 = 0; h1 < 8; ++h1)
            a[h1] = __half22float2(tl[t][LROW(h1*8 + d)][cl]);
        dft8<-1>(a, Y);
        #pragma unroll
        for (int k0 = 0; k0 < 8; ++k0) {
            float2 z = make_float2(Y[k0].x*twc[k0] - Y[k0].y*tws[k0],
                                   Y[k0].x*tws[k0] + Y[k0].y*twc[k0]);
            tl[t][LROW(k0*8 + d)][cl] = __float22half2_rn(z);
        }
    }
    __syncthreads();
    // H forward stage 2: DFT8 over h0 at fixed k0=d; row k0*8+k1 := bin k0+8*k1
    #pragma unroll
    for (int q = 0; q < 2; ++q) {
        int t = ts*2 + q;
        float2 a[8], Y[8];
        #pragma unroll
        for (int h0 = 0; h0 < 8; ++h0)
            a[h0] = __half22float2(tl[t][LROW(d*8 + h0)][cl]);
        dft8<-1>(a, Y);
        #pragma unroll
        for (int k1 = 0; k1 < 8; ++k1)
            tl[t][LROW(d*8 + k1)][cl] = __float22half2_rn(Y[k1]);
    }
    __syncthreads();
    // T phase: fwd dft16, G = S(A_f)*B_f multiply, inv dft16 (tables pre-permuted).
    // One row per thread (rT in [0,64), cg in [0,4)).
    {
        const float CT16[16] = {1.f, 0.9238795325f, 0.7071067812f, 0.3826834324f, 0.f,
                                -0.3826834324f, -0.7071067812f, -0.9238795325f, -1.f,
                                -0.9238795325f, -0.7071067812f, -0.3826834324f, 0.f,
                                0.3826834324f, 0.7071067812f, 0.9238795325f};
        const float ST16[16] = {0.f, 0.3826834324f, 0.7071067812f, 0.9238795325f, 1.f,
                                0.9238795325f, 0.7071067812f, 0.3826834324f, 0.f,
                                -0.3826834324f, -0.7071067812f, -0.9238795325f, -1.f,
                                -0.9238795325f, -0.7071067812f, -0.3826834324f};
        int cg = tid & 3, rT = tid >> 2;             // rT in [0,64)
        const int PKT = 33 * 64 * 128;
        int kb = (om * 64 + rT) * 128 + c0 + cg;
        float2 A0 = __half22float2(Ahw[kb]);
        float2 A1 = __half22float2(Ahw[kb + PKT]);
        float2 A2 = __half22float2(Ahw[kb + 2*PKT]);
        float2 B0 = __half22float2(Bhw[kb]);
        float2 B1 = __half22float2(Bhw[kb + PKT]);
        float2 B2 = __half22float2(Bhw[kb + 2*PKT]);
        int pr = LROW(rT);
        float2 v[16], X[16];
        #pragma unroll
        for (int t = 0; t < 16; ++t) v[t] = __half22float2(tl[t][pr][cg]);
        dft16<-1>(v, X);
        #pragma unroll
        for (int ta = 0; ta < 16; ++ta) {
            float2 wv = make_float2(CT16[ta], -ST16[ta]);
            float2 wc = make_float2(CT16[ta],  ST16[ta]);
            float2 Af = A1; Af = cmac(Af, A0, wc); Af = cmac(Af, A2, wv);
            float2 Bf = B1; Bf = cmac(Bf, B0, wc); Bf = cmac(Bf, B2, wv);
            // S = sum_{k=0}^{7} Af^k = (1+Af)(1+Af^2)(1+Af^4)
            float2 A2q = csq(Af), A4q = csq(A2q);
            float2 S = cmul(make_float2(1.f+Af.x, Af.y), make_float2(1.f+A2q.x, A2q.y));
            S = cmul(S, make_float2(1.f+A4q.x, A4q.y));
            float2 G = cmul(S, Bf);
            X[ta] = cmul(X[ta], G);
        }
        dft16<1>(X, v);
        const float sc = 0.015625f;                  // 1/64 fold
        #pragma unroll
        for (int t = 0; t < 16; ++t)
            tl[t][pr][cg] = __float22half2_rn(make_float2(v[t].x*sc, v[t].y*sc));
    }
    __syncthreads();
    // inverse H stage 1: DFT8<+1> over eta1 at fixed eta0=d, twiddle w^{+d*h0}
    #pragma unroll
    for (int q = 0; q < 2; ++q) {
        int t = ts*2 + q;
        float2 a[8], Y[8];
        #pragma unroll
        for (int e1 = 0; e1 < 8; ++e1)
            a[e1] = __half22float2(tl[t][LROW(d*8 + e1)][cl]);
        dft8<1>(a, Y);
        #pragma unroll
        for (int h0 = 0; h0 < 8; ++h0) {
            float2 z = make_float2( Y[h0].x*twc[h0] + Y[h0].y*tws[h0],
                                   -Y[h0].x*tws[h0] + Y[h0].y*twc[h0]);
            tl[t][LROW(d*8 + h0)][cl] = __float22half2_rn(z);
        }
    }
    __syncthreads();
    // inverse H stage 2: DFT8<+1> over eta0 at fixed h0=d; out row d+8*h1 (natural h)
    #pragma unroll
    for (int q = 0; q < 2; ++q) {
        int t = ts*2 + q;
        float2 a[8], Y[8];
        #pragma unroll
        for (int e0 = 0; e0 < 8; ++e0)
            a[e0] = __half22float2(tl[t][LROW(e0*8 + d)][cl]);
        dft8<1>(a, Y);
        #pragma unroll
        for (int h1 = 0; h1 < 8; ++h1)
            tl[t][LROW(d + 8*h1)][cl] = __float22half2_rn(Y[h1]);
    }
    __syncthreads();
    // write back: full overwrite of the block-private 16 KB chunk
    for (int i = tid; i < 1024; i += 256) {
        int t = i >> 6, h = i & 63;
        int pr = LROW(h);
        uint4 u;
        __half2 v0 = tl[t][pr][0], v1 = tl[t][pr][1];
        __half2 v2 = tl[t][pr][2], v3 = tl[t][pr][3];
        u.x = *(unsigned int*)&v0; u.y = *(unsigned int*)&v1;
        u.z = *(unsigned int*)&v2; u.w = *(unsigned int*)&v3;
        g[i] = u;
    }
}

// ------- pass 5: dense Z read + Hermitian-expand + inverse W-FFT, real out -------
// grid: t(16) x hq(16) x chalf(2) = 512 blocks, 512 threads.
__global__ __launch_bounds__(512) void p5(const uint4* __restrict__ Z,
                                          float* __restrict__ out) {
    __shared__ __half2 sp[4][33][64];      // 33.8 KB
    __shared__ __half2 plane[64][64];      // 16 KB
    __shared__ float2 tw64[64];
    int bid = blockIdx.x;
    int t = bid >> 5, hq = (bid >> 1) & 15, chalf = bid & 1;
    int tid = threadIdx.x;
    if (tid < 64) {
        float s, cq; sincosf(6.283185307179586f * tid / 64.0f, &s, &cq);
        tw64[tid] = make_float2(cq, s);
    }
    // dense staging read (aligned 64-B segments)
    for (int i = tid; i < 2112; i += 512) {
        int hh = i & 3, ccl = (i >> 2) & 15, om = i >> 6;
        uint4 u = Z[(((size_t)(om*32 + chalf*16 + ccl)*16 + t)*64 + hq*4 + hh)];
        int cb = ccl * 4;
        sp[hh][om][cb+0] = *(__half2*)&u.x;
        sp[hh][om][cb+1] = *(__half2*)&u.y;
        sp[hh][om][cb+2] = *(__half2*)&u.z;
        sp[hh][om][cb+3] = *(__half2*)&u.w;
    }
    __syncthreads();
    int c = tid & 63, s4 = tid >> 6;
    for (int hh = 0; hh < 4; ++hh) {
        // Hermitian expand into the 64-om plane
        for (int i = tid; i < 33 * 64; i += 512) {
            int om = i >> 6, cl = i & 63;
            __half2 v = sp[hh][om][cl];
            plane[om][cl] = v;
            if (om >= 1 && om <= 31) {
                __half2 m = v; m.y = __hneg(m.y);
                plane[64 - om][cl] = m;
            }
        }
        __syncthreads();
        // stage 1 phase A: reads to registers
        float2 ar[8];
        #pragma unroll
        for (int h1 = 0; h1 < 8; ++h1)
            ar[h1] = __half22float2(plane[h1*8 + s4][c]);
        __syncthreads();
        // stage 1 phase B: dft8 + twiddle, in place
        {
            float2 Y[8];
            dft8<1>(ar, Y);
            #pragma unroll
            for (int k0 = 0; k0 < 8; ++k0) {
                float2 z = cmul(Y[k0], tw64[(s4 * k0) & 63]);
                plane[k0*8 + s4][c] = __float22half2_rn(z);
            }
        }
        __syncthreads();
        // stage 2 + dense fp32 output
        {
            float2 b[8], X[8];
            #pragma unroll
            for (int h0 = 0; h0 < 8; ++h0)
                b[h0] = __half22float2(plane[s4*8 + h0][c]);
            dft8<1>(b, X);
            float* dst = out + (size_t)(t*64 + hq*4 + hh) * 64 * 128 + chalf * 64 + c;
            #pragma unroll
            for (int k1 = 0; k1 < 8; ++k1)
                dst[(size_t)(s4 + 8*k1) * 128] = X[k1].x * (1.0f / 1024.0f);
        }
        __syncthreads();
    }
}

extern "C" void kernel_launch(void* const* d_in, const int* in_sizes, int n_in,
                              void* d_out, int out_size, void* d_ws, size_t ws_size,
                              hipStream_t stream) {
    const float* x  = (const float*)d_in[0];
    const float* Ak = (const float*)d_in[1];
    const float* Bk = (const float*)d_in[2];
    float* out = (float*)d_out;

    // Z: 33*32 chunks x 16 KB = 17.3 MB (uint4-addressed); G tables after.
    uint4* Z = (uint4*)d_ws;
    __half2* Ahw = (__half2*)((char*)d_ws + (size_t)33*32*1024*16);
    __half2* Bhw = Ahw + 3 * 33 * 64 * 128;

    hipLaunchKernelGGL(k_prep, dim3(198),  dim3(256), 0, stream, Ak, Bk, Ahw, Bhw);
    hipLaunchKernelGGL(p1,     dim3(512),  dim3(512), 0, stream, x, Z);
    hipLaunchKernelGGL(pmid,   dim3(1056), dim3(256), 0, stream, Z, Ahw, Bhw);
    hipLaunchKernelGGL(p5,     dim3(512),  dim3(512), 0, stream, Z, out);
}

// Round 12
// 65.755 us; speedup vs baseline: 1.6386x; 1.0442x over previous
//
#include <hip/hip_runtime.h>
#include <hip/hip_fp16.h>
#include <math.h>

#define TT 16
#define HH 64
#define WW 64
#define CC 128
#define PI2 6.283185307179586f

// XOR digit swizzle: row r = hi*8+lo -> hi*8 + (lo^hi). Keeps stride-8 and
// block-8 row accesses <=2-way banked in the narrow [.,64][4] half2 tile.
#define LROW(r) (((r) & 0x38) | ((((r) >> 3) ^ (r)) & 7))

__device__ __forceinline__ float2 cadd(float2 a, float2 b){ return make_float2(a.x+b.x, a.y+b.y); }
__device__ __forceinline__ float2 csub(float2 a, float2 b){ return make_float2(a.x-b.x, a.y-b.y); }
__device__ __forceinline__ float2 cmul(float2 a, float2 b) {
    return make_float2(a.x*b.x - a.y*b.y, a.x*b.y + a.y*b.x);
}
__device__ __forceinline__ float2 cmac(float2 acc, float2 a, float2 b) {
    acc.x = fmaf(a.x, b.x, fmaf(-a.y, b.y, acc.x));
    acc.y = fmaf(a.x, b.y, fmaf(a.y, b.x, acc.y));
    return acc;
}
__device__ __forceinline__ float2 csq(float2 a) {
    return make_float2(a.x*a.x - a.y*a.y, 2.f*a.x*a.y);
}

// ---------------- radix butterflies ----------------
template<int SGN>
__device__ __forceinline__ void dft4(float2 b0, float2 b1, float2 b2, float2 b3,
                                     float2& y0, float2& y1, float2& y2, float2& y3) {
    float2 e0 = cadd(b0, b2), e1 = csub(b0, b2);
    float2 o0 = cadd(b1, b3), o1 = csub(b1, b3);
    y0 = cadd(e0, o0); y2 = csub(e0, o0);
    float2 r = make_float2((float)(-SGN) * o1.y, (float)SGN * o1.x);
    y1 = cadd(e1, r); y3 = csub(e1, r);
}

template<int SGN>
__device__ __forceinline__ void dft8(const float2* a, float2* X) {
    const float C = 0.70710678118654752f;
    float2 E0,E1,E2,E3,O0,O1,O2,O3;
    dft4<SGN>(a[0],a[2],a[4],a[6], E0,E1,E2,E3);
    dft4<SGN>(a[1],a[3],a[5],a[7], O0,O1,O2,O3);
    float2 T1 = make_float2(C*(O1.x - (float)SGN*O1.y), C*((float)SGN*O1.x + O1.y));
    float2 T2 = make_float2((float)(-SGN)*O2.y, (float)SGN*O2.x);
    float2 T3 = make_float2(-C*(O3.x + (float)SGN*O3.y), C*((float)SGN*O3.x - O3.y));
    X[0]=cadd(E0,O0); X[4]=csub(E0,O0);
    X[1]=cadd(E1,T1); X[5]=csub(E1,T1);
    X[2]=cadd(E2,T2); X[6]=csub(E2,T2);
    X[3]=cadd(E3,T3); X[7]=csub(E3,T3);
}

template<int SGN>
__device__ __forceinline__ void dft16(const float2* v, float2* X) {
    const float ct[10] = {1.f, 0.92387953251f, 0.70710678119f, 0.38268343236f, 0.f,
                          0.f, -0.70710678119f, 0.f, 0.f, -0.92387953251f};
    const float st[10] = {0.f, 0.38268343236f, 0.70710678119f, 0.92387953251f, 1.f,
                          0.f, 0.70710678119f, 0.f, 0.f, -0.38268343236f};
    float2 Z[16];
    #pragma unroll
    for (int h0 = 0; h0 < 4; ++h0) {
        float2 y0,y1,y2,y3;
        dft4<SGN>(v[h0], v[4+h0], v[8+h0], v[12+h0], y0,y1,y2,y3);
        float2 ys[4] = {y0,y1,y2,y3};
        #pragma unroll
        for (int k0 = 0; k0 < 4; ++k0) {
            int m = h0 * k0;
            float cc = ct[m], ss = (float)SGN * st[m];
            Z[k0*4 + h0] = make_float2(ys[k0].x*cc - ys[k0].y*ss,
                                       ys[k0].x*ss + ys[k0].y*cc);
        }
    }
    #pragma unroll
    for (int k0 = 0; k0 < 4; ++k0) {
        float2 y0,y1,y2,y3;
        dft4<SGN>(Z[k0*4+0], Z[k0*4+1], Z[k0*4+2], Z[k0*4+3], y0,y1,y2,y3);
        X[k0] = y0; X[k0+4] = y1; X[k0+8] = y2; X[k0+12] = y3;
    }
}

// Z layout (uint4 = 4 half2 = 4 channels): index ((om*32 + cc)*16 + t)*64 + h.
// Each pmid block owns one contiguous 16 KB chunk (om,cc).

// ======== fused pass A: blocks 0..1023 = p1 (c-quarter W-FFT), 1024..1221 = k_prep ========
__global__ __launch_bounds__(256) void pA(const float* __restrict__ x,
                                          uint4* __restrict__ Z,
                                          const float* __restrict__ Ak,
                                          const float* __restrict__ Bk,
                                          __half2* __restrict__ Ahw,
                                          __half2* __restrict__ Bhw) {
    __shared__ __align__(16) char smem[33280];
    int bid = blockIdx.x;
    int tid = threadIdx.x;
    if (bid < 1024) {
        // ---------------- p1 role: forward radix-8 FFT along W, c-quarter ----------------
        float (*rf)[32]        = (float(*)[32])smem;                 // 8 KB, aliased half2
        __half2 (*sp)[33][32]  = (__half2(*)[33][32])(smem + 8192);  // 16.5 KB
        float2* tw64           = (float2*)(smem + 8192 + 16896);     // 0.5 KB
        __half2* zal           = (__half2*)smem;
        int cq = bid & 3, hq = (bid >> 2) & 15, t = bid >> 6;
        if (tid < 64) {
            float s, cw; sincosf(-PI2 * tid / 64.0f, &s, &cw);
            tw64[tid] = make_float2(cw, s);
        }
        int c = tid & 31, s4 = tid >> 5;           // s4 in [0,8)
        for (int hh = 0; hh < 4; ++hh) {
            const float4* src4 = (const float4*)(x + (size_t)(t*64 + hq*4 + hh) * 64 * 128);
            for (int i = tid; i < 512; i += 256) {
                int w = i >> 3, j = i & 7;
                float4 v = src4[w * 32 + cq * 8 + j];
                rf[w][j*4+0] = v.x; rf[w][j*4+1] = v.y;
                rf[w][j*4+2] = v.z; rf[w][j*4+3] = v.w;
            }
            __syncthreads();
            // stage 1 phase A: fp32 reads to registers
            float ar[8];
            #pragma unroll
            for (int h1 = 0; h1 < 8; ++h1) ar[h1] = rf[h1*8 + s4][c];
            __syncthreads();
            // stage 1 phase B: dft8 + twiddle -> half2 alias in place
            {
                float2 a[8], Y[8];
                #pragma unroll
                for (int h1 = 0; h1 < 8; ++h1) a[h1] = make_float2(ar[h1], 0.f);
                dft8<-1>(a, Y);
                #pragma unroll
                for (int k0 = 0; k0 < 8; ++k0) {
                    float2 z = cmul(Y[k0], tw64[(s4 * k0) & 63]);
                    zal[(k0*8 + s4) * 32 + c] = __float22half2_rn(z);
                }
            }
            __syncthreads();
            // stage 2: k0 = s4, emit om<=32 into staging
            {
                float2 b[8], X[8];
                #pragma unroll
                for (int h0 = 0; h0 < 8; ++h0)
                    b[h0] = __half22float2(zal[(s4*8 + h0) * 32 + c]);
                dft8<-1>(b, X);
                #pragma unroll
                for (int k1 = 0; k1 < 8; ++k1) {
                    int om = s4 + 8 * k1;
                    if (om <= 32) sp[hh][om][c] = __float22half2_rn(X[k1]);
                }
            }
            __syncthreads();
        }
        // dense write: full 64-B quads (4h x 4c), c-quarter owns whole lines
        for (int i = tid; i < 1056; i += 256) {
            int hh = i & 3, ccl = (i >> 2) & 7, om = i >> 5;
            uint4 u = *(const uint4*)&sp[hh][om][ccl * 4];
            Z[(((size_t)(om*32 + cq*8 + ccl)*16 + t)*64 + hq*4 + hh)] = u;
        }
    } else {
        // ---------------- k_prep role: tanh + kw-DFT + kh-DFT, half2 G tables ----------------
        float (*Asl)[7][64] = (float(*)[7][64])smem;                 // 12.25 KB
        float (*Bsl)[7][64] = (float(*)[7][64])(smem + 12544);       // 12.25 KB
        float2 (*Awl)[64]   = (float2(*)[64])(smem + 25088);         // 3.5 KB
        float2 (*Bwl)[64]   = (float2(*)[64])(smem + 28672);         // 3.5 KB
        float2* tw64        = (float2*)(smem + 32256);               // 0.5 KB
        int kid = bid - 1024;
        int kt = kid / 66;
        int rem = kid % 66;
        int om = rem >> 1, chalf = rem & 1;
        int c0 = chalf * 64;
        for (int i = tid; i < 64; i += 256) {
            float s, cw; sincosf(-PI2 * i / 64.0f, &s, &cw);
            tw64[i] = make_float2(cw, s);
        }
        for (int i = tid; i < 49 * 64; i += 256) {
            int p = i >> 6, cl = i & 63;
            int kh = p / 7, kw = p % 7;
            int idx = (((c0 + cl) * 3 + kt) * 7 + kh) * 7 + kw;
            Asl[kh][kw][cl] = 0.9f * tanhf(Ak[idx]);
            Bsl[kh][kw][cl] = Bk[idx];
        }
        __syncthreads();
        for (int i = tid; i < 7 * 64; i += 256) {
            int kh = i >> 6, cl = i & 63;
            float2 aA = make_float2(0.f,0.f), aB = make_float2(0.f,0.f);
            #pragma unroll
            for (int kw = 0; kw < 7; ++kw) {
                float2 tw = tw64[(om * (kw - 3)) & 63];
                float va = Asl[kh][kw][cl], vb = Bsl[kh][kw][cl];
                aA.x = fmaf(va, tw.x, aA.x); aA.y = fmaf(va, tw.y, aA.y);
                aB.x = fmaf(vb, tw.x, aB.x); aB.y = fmaf(vb, tw.y, aB.y);
            }
            Awl[kh][cl] = aA; Bwl[kh][cl] = aB;
        }
        __syncthreads();
        for (int i = tid; i < 64 * 64; i += 256) {
            int eta = i >> 6, cl = i & 63;
            float2 aA = make_float2(0.f,0.f), aB = make_float2(0.f,0.f);
            #pragma unroll
            for (int kh = 0; kh < 7; ++kh) {
                float2 tw = tw64[(eta * (kh - 3)) & 63];
                aA = cmac(aA, Awl[kh][cl], tw);
                aB = cmac(aB, Bwl[kh][cl], tw);
            }
            int ep = ((eta & 7) << 3) | (eta >> 3);  // digit-swapped eta position
            int o = ((kt * 33 + om) * 64 + ep) * 128 + c0 + cl;
            Ahw[o] = __float22half2_rn(aA);
            Bhw[o] = __float22half2_rn(aB);
        }
    }
}

// ------- fused middle pass: H-FFT + T-FFT + G multiply + inv-T + inv-H, in place -------
// 1056 blocks (om33 x cc32) x 256 threads, plain launch_bounds (no spill).
__global__ __launch_bounds__(256) void pmid(uint4* __restrict__ Z,
                                            const __half2* __restrict__ Ahw,
                                            const __half2* __restrict__ Bhw) {
    __shared__ __half2 tl[16][64][4];     // 16 KB
    // XCD-chunked swizzle: 1056 = 8*132 (bijective)
    int l = (blockIdx.x & 7) * 132 + (blockIdx.x >> 3);
    int om = l >> 5, cc = l & 31;
    int c0 = cc * 4;
    int tid = threadIdx.x;
    uint4* g = Z + (size_t)l * 1024;

    int d = tid & 7;
    float twc[8], tws[8];
    {
        float s1, c1; sincosf(-PI2 * d / 64.0f, &s1, &c1);
        twc[0] = 1.f; tws[0] = 0.f;
        #pragma unroll
        for (int k = 1; k < 8; ++k) {
            twc[k] = twc[k-1]*c1 - tws[k-1]*s1;
            tws[k] = twc[k-1]*s1 + tws[k-1]*c1;
        }
    }
    for (int i = tid; i < 1024; i += 256) {
        uint4 u = g[i];
        int t = i >> 6, h = i & 63;
        int pr = LROW(h);
        tl[t][pr][0] = *(__half2*)&u.x;
        tl[t][pr][1] = *(__half2*)&u.y;
        tl[t][pr][2] = *(__half2*)&u.z;
        tl[t][pr][3] = *(__half2*)&u.w;
    }
    __syncthreads();
    int cl = (tid >> 3) & 3, ts = tid >> 5;          // ts in [0,8)
    #pragma unroll
    for (int q = 0; q < 2; ++q) {
        int t = ts*2 + q;
        float2 a[8], Y[8];
        #pragma unroll
        for (int h1 = 0; h1 < 8; ++h1)
            a[h1] = __half22float2(tl[t][LROW(h1*8 + d)][cl]);
        dft8<-1>(a, Y);
        #pragma unroll
        for (int k0 = 0; k0 < 8; ++k0) {
            float2 z = make_float2(Y[k0].x*twc[k0] - Y[k0].y*tws[k0],
                                   Y[k0].x*tws[k0] + Y[k0].y*twc[k0]);
            tl[t][LROW(k0*8 + d)][cl] = __float22half2_rn(z);
        }
    }
    __syncthreads();
    #pragma unroll
    for (int q = 0; q < 2; ++q) {
        int t = ts*2 + q;
        float2 a[8], Y[8];
        #pragma unroll
        for (int h0 = 0; h0 < 8; ++h0)
            a[h0] = __half22float2(tl[t][LROW(d*8 + h0)][cl]);
        dft8<-1>(a, Y);
        #pragma unroll
        for (int k1 = 0; k1 < 8; ++k1)
            tl[t][LROW(d*8 + k1)][cl] = __float22half2_rn(Y[k1]);
    }
    __syncthreads();
    // T phase: fwd dft16, G = S(A_f)*B_f multiply, inv dft16 (tables pre-permuted)
    {
        const float CT16[16] = {1.f, 0.9238795325f, 0.7071067812f, 0.3826834324f, 0.f,
                                -0.3826834324f, -0.7071067812f, -0.9238795325f, -1.f,
                                -0.9238795325f, -0.7071067812f, -0.3826834324f, 0.f,
                                0.3826834324f, 0.7071067812f, 0.9238795325f};
        const float ST16[16] = {0.f, 0.3826834324f, 0.7071067812f, 0.9238795325f, 1.f,
                                0.9238795325f, 0.7071067812f, 0.3826834324f, 0.f,
                                -0.3826834324f, -0.7071067812f, -0.9238795325f, -1.f,
                                -0.9238795325f, -0.7071067812f, -0.3826834324f};
        int cg = tid & 3, rT = tid >> 2;             // rT in [0,64)
        const int PKT = 33 * 64 * 128;
        int kb = (om * 64 + rT) * 128 + c0 + cg;
        float2 A0 = __half22float2(Ahw[kb]);
        float2 A1 = __half22float2(Ahw[kb + PKT]);
        float2 A2 = __half22float2(Ahw[kb + 2*PKT]);
        float2 B0 = __half22float2(Bhw[kb]);
        float2 B1 = __half22float2(Bhw[kb + PKT]);
        float2 B2 = __half22float2(Bhw[kb + 2*PKT]);
        int pr = LROW(rT);
        float2 v[16], X[16];
        #pragma unroll
        for (int t = 0; t < 16; ++t) v[t] = __half22float2(tl[t][pr][cg]);
        dft16<-1>(v, X);
        #pragma unroll
        for (int ta = 0; ta < 16; ++ta) {
            float2 wv = make_float2(CT16[ta], -ST16[ta]);
            float2 wc = make_float2(CT16[ta],  ST16[ta]);
            float2 Af = A1; Af = cmac(Af, A0, wc); Af = cmac(Af, A2, wv);
            float2 Bf = B1; Bf = cmac(Bf, B0, wc); Bf = cmac(Bf, B2, wv);
            float2 A2q = csq(Af), A4q = csq(A2q);
            float2 S = cmul(make_float2(1.f+Af.x, Af.y), make_float2(1.f+A2q.x, A2q.y));
            S = cmul(S, make_float2(1.f+A4q.x, A4q.y));
            float2 G = cmul(S, Bf);
            X[ta] = cmul(X[ta], G);
        }
        dft16<1>(X, v);
        const float sc = 0.015625f;                  // 1/64 fold
        #pragma unroll
        for (int t = 0; t < 16; ++t)
            tl[t][pr][cg] = __float22half2_rn(make_float2(v[t].x*sc, v[t].y*sc));
    }
    __syncthreads();
    #pragma unroll
    for (int q = 0; q < 2; ++q) {
        int t = ts*2 + q;
        float2 a[8], Y[8];
        #pragma unroll
        for (int e1 = 0; e1 < 8; ++e1)
            a[e1] = __half22float2(tl[t][LROW(d*8 + e1)][cl]);
        dft8<1>(a, Y);
        #pragma unroll
        for (int h0 = 0; h0 < 8; ++h0) {
            float2 z = make_float2( Y[h0].x*twc[h0] + Y[h0].y*tws[h0],
                                   -Y[h0].x*tws[h0] + Y[h0].y*twc[h0]);
            tl[t][LROW(d*8 + h0)][cl] = __float22half2_rn(z);
        }
    }
    __syncthreads();
    #pragma unroll
    for (int q = 0; q < 2; ++q) {
        int t = ts*2 + q;
        float2 a[8], Y[8];
        #pragma unroll
        for (int e0 = 0; e0 < 8; ++e0)
            a[e0] = __half22float2(tl[t][LROW(e0*8 + d)][cl]);
        dft8<1>(a, Y);
        #pragma unroll
        for (int h1 = 0; h1 < 8; ++h1)
            tl[t][LROW(d + 8*h1)][cl] = __float22half2_rn(Y[h1]);
    }
    __syncthreads();
    for (int i = tid; i < 1024; i += 256) {
        int t = i >> 6, h = i & 63;
        int pr = LROW(h);
        uint4 u;
        __half2 v0 = tl[t][pr][0], v1 = tl[t][pr][1];
        __half2 v2 = tl[t][pr][2], v3 = tl[t][pr][3];
        u.x = *(unsigned int*)&v0; u.y = *(unsigned int*)&v1;
        u.z = *(unsigned int*)&v2; u.w = *(unsigned int*)&v3;
        g[i] = u;
    }
}

// ------- pass 5: dense Z read + Hermitian-expand + inverse W-FFT, c-quarter -------
// grid: t(16) x hq(16) x cq(4) = 1024 blocks, 256 threads.
__global__ __launch_bounds__(256) void p5(const uint4* __restrict__ Z,
                                          float* __restrict__ out) {
    __shared__ __half2 sp[4][33][32];      // 16.5 KB
    __shared__ __half2 plane[64][32];      // 8 KB
    __shared__ float2 tw64[64];
    int bid = blockIdx.x;
    int cq = bid & 3, hq = (bid >> 2) & 15, t = bid >> 6;
    int tid = threadIdx.x;
    if (tid < 64) {
        float s, cw; sincosf(PI2 * tid / 64.0f, &s, &cw);
        tw64[tid] = make_float2(cw, s);
    }
    // dense staging read (full 64-B quads)
    for (int i = tid; i < 1056; i += 256) {
        int hh = i & 3, ccl = (i >> 2) & 7, om = i >> 5;
        uint4 u = Z[(((size_t)(om*32 + cq*8 + ccl)*16 + t)*64 + hq*4 + hh)];
        *(uint4*)&sp[hh][om][ccl * 4] = u;
    }
    __syncthreads();
    int c = tid & 31, s4 = tid >> 5;
    for (int hh = 0; hh < 4; ++hh) {
        // Hermitian expand into the 64-om plane
        for (int i = tid; i < 1056; i += 256) {
            int om = i >> 5, cl = i & 31;
            __half2 v = sp[hh][om][cl];
            plane[om][cl] = v;
            if (om >= 1 && om <= 31) {
                __half2 m = v; m.y = __hneg(m.y);
                plane[64 - om][cl] = m;
            }
        }
        __syncthreads();
        // stage 1 phase A: reads to registers
        float2 ar[8];
        #pragma unroll
        for (int h1 = 0; h1 < 8; ++h1)
            ar[h1] = __half22float2(plane[h1*8 + s4][c]);
        __syncthreads();
        // stage 1 phase B: dft8 + twiddle, in place
        {
            float2 Y[8];
            dft8<1>(ar, Y);
            #pragma unroll
            for (int k0 = 0; k0 < 8; ++k0) {
                float2 z = cmul(Y[k0], tw64[(s4 * k0) & 63]);
                plane[k0*8 + s4][c] = __float22half2_rn(z);
            }
        }
        __syncthreads();
        // stage 2 + dense fp32 output (aligned 128-B runs)
        {
            float2 b[8], X[8];
            #pragma unroll
            for (int h0 = 0; h0 < 8; ++h0)
                b[h0] = __half22float2(plane[s4*8 + h0][c]);
            dft8<1>(b, X);
            float* dst = out + (size_t)(t*64 + hq*4 + hh) * 64 * 128 + cq * 32 + c;
            #pragma unroll
            for (int k1 = 0; k1 < 8; ++k1)
                dst[(size_t)(s4 + 8*k1) * 128] = X[k1].x * (1.0f / 1024.0f);
        }
        __syncthreads();
    }
}

extern "C" void kernel_launch(void* const* d_in, const int* in_sizes, int n_in,
                              void* d_out, int out_size, void* d_ws, size_t ws_size,
                              hipStream_t stream) {
    const float* x  = (const float*)d_in[0];
    const float* Ak = (const float*)d_in[1];
    const float* Bk = (const float*)d_in[2];
    float* out = (float*)d_out;

    // Z: 33*32 chunks x 16 KB = 17.3 MB (uint4-addressed); G tables after.
    uint4* Z = (uint4*)d_ws;
    __half2* Ahw = (__half2*)((char*)d_ws + (size_t)33*32*1024*16);
    __half2* Bhw = Ahw + 3 * 33 * 64 * 128;

    hipLaunchKernelGGL(pA,   dim3(1222), dim3(256), 0, stream, x, Z, Ak, Bk, Ahw, Bhw);
    hipLaunchKernelGGL(pmid, dim3(1056), dim3(256), 0, stream, Z, Ahw, Bhw);
    hipLaunchKernelGGL(p5,   dim3(1024), dim3(256), 0, stream, Z, out);
}

// Round 14
// 63.835 us; speedup vs baseline: 1.6879x; 1.0301x over previous
//
#include <hip/hip_runtime.h>
#include <hip/hip_fp16.h>
#include <math.h>

#define TT 16
#define HH 64
#define WW 64
#define CC 128
#define PI2 6.283185307179586f

// XOR digit swizzle: row r = hi*8+lo -> hi*8 + (lo^hi). Keeps stride-8 and
// block-8 row accesses <=2-way banked in the narrow [.,64][4] half2 tile.
#define LROW(r) (((r) & 0x38) | ((((r) >> 3) ^ (r)) & 7))

__device__ __forceinline__ float2 cadd(float2 a, float2 b){ return make_float2(a.x+b.x, a.y+b.y); }
__device__ __forceinline__ float2 csub(float2 a, float2 b){ return make_float2(a.x-b.x, a.y-b.y); }
__device__ __forceinline__ float2 cmul(float2 a, float2 b) {
    return make_float2(a.x*b.x - a.y*b.y, a.x*b.y + a.y*b.x);
}
__device__ __forceinline__ float2 cmac(float2 acc, float2 a, float2 b) {
    acc.x = fmaf(a.x, b.x, fmaf(-a.y, b.y, acc.x));
    acc.y = fmaf(a.x, b.y, fmaf(a.y, b.x, acc.y));
    return acc;
}
__device__ __forceinline__ float2 csq(float2 a) {
    return make_float2(a.x*a.x - a.y*a.y, 2.f*a.x*a.y);
}

// ---------------- radix butterflies ----------------
template<int SGN>
__device__ __forceinline__ void dft4(float2 b0, float2 b1, float2 b2, float2 b3,
                                     float2& y0, float2& y1, float2& y2, float2& y3) {
    float2 e0 = cadd(b0, b2), e1 = csub(b0, b2);
    float2 o0 = cadd(b1, b3), o1 = csub(b1, b3);
    y0 = cadd(e0, o0); y2 = csub(e0, o0);
    float2 r = make_float2((float)(-SGN) * o1.y, (float)SGN * o1.x);
    y1 = cadd(e1, r); y3 = csub(e1, r);
}

template<int SGN>
__device__ __forceinline__ void dft8(const float2* a, float2* X) {
    const float C = 0.70710678118654752f;
    float2 E0,E1,E2,E3,O0,O1,O2,O3;
    dft4<SGN>(a[0],a[2],a[4],a[6], E0,E1,E2,E3);
    dft4<SGN>(a[1],a[3],a[5],a[7], O0,O1,O2,O3);
    float2 T1 = make_float2(C*(O1.x - (float)SGN*O1.y), C*((float)SGN*O1.x + O1.y));
    float2 T2 = make_float2((float)(-SGN)*O2.y, (float)SGN*O2.x);
    float2 T3 = make_float2(-C*(O3.x + (float)SGN*O3.y), C*((float)SGN*O3.x - O3.y));
    X[0]=cadd(E0,O0); X[4]=csub(E0,O0);
    X[1]=cadd(E1,T1); X[5]=csub(E1,T1);
    X[2]=cadd(E2,T2); X[6]=csub(E2,T2);
    X[3]=cadd(E3,T3); X[7]=csub(E3,T3);
}

template<int SGN>
__device__ __forceinline__ void dft16(const float2* v, float2* X) {
    const float ct[10] = {1.f, 0.92387953251f, 0.70710678119f, 0.38268343236f, 0.f,
                          0.f, -0.70710678119f, 0.f, 0.f, -0.92387953251f};
    const float st[10] = {0.f, 0.38268343236f, 0.70710678119f, 0.92387953251f, 1.f,
                          0.f, 0.70710678119f, 0.f, 0.f, -0.38268343236f};
    float2 Z[16];
    #pragma unroll
    for (int h0 = 0; h0 < 4; ++h0) {
        float2 y0,y1,y2,y3;
        dft4<SGN>(v[h0], v[4+h0], v[8+h0], v[12+h0], y0,y1,y2,y3);
        float2 ys[4] = {y0,y1,y2,y3};
        #pragma unroll
        for (int k0 = 0; k0 < 4; ++k0) {
            int m = h0 * k0;
            float cc = ct[m], ss = (float)SGN * st[m];
            Z[k0*4 + h0] = make_float2(ys[k0].x*cc - ys[k0].y*ss,
                                       ys[k0].x*ss + ys[k0].y*cc);
        }
    }
    #pragma unroll
    for (int k0 = 0; k0 < 4; ++k0) {
        float2 y0,y1,y2,y3;
        dft4<SGN>(Z[k0*4+0], Z[k0*4+1], Z[k0*4+2], Z[k0*4+3], y0,y1,y2,y3);
        X[k0] = y0; X[k0+4] = y1; X[k0+8] = y2; X[k0+12] = y3;
    }
}

// Z layout (uint4 = 4 half2 = 4 channels): index ((om*32 + cc)*16 + t)*64 + h.
// Each pmid block owns one contiguous 16 KB chunk (om,cc).

// ======== fused pass A: blocks 0..1023 = p1 (c-quarter W-FFT), 1024..1221 = k_prep ========
// p1 role: direct global->register stage-1 loads, register twiddles, 2 barriers.
// LDS: zs half2[4][64][32] @0 (32768 B) + sp half2[4][33][32] @32768 (16896 B) = 49664 B.
__global__ __launch_bounds__(256) void pA(const float* __restrict__ x,
                                          uint4* __restrict__ Z,
                                          const float* __restrict__ Ak,
                                          const float* __restrict__ Bk,
                                          __half2* __restrict__ Ahw,
                                          __half2* __restrict__ Bhw) {
    __shared__ __align__(16) char smem[49664];
    int bid = blockIdx.x;
    int tid = threadIdx.x;
    if (bid < 1024) {
        __half2 (*zs)[64][32] = (__half2(*)[64][32])smem;             // 32 KB
        __half2 (*sp)[33][32] = (__half2(*)[33][32])(smem + 32768);   // 16.5 KB
        int cq = bid & 3, hq = (bid >> 2) & 15, t = bid >> 6;
        int c = tid & 31, s4 = tid >> 5;           // s4 in [0,8)
        // per-thread stage-1 twiddles: w64^{-s4*k0}
        float twc[8], tws[8];
        {
            float s1, c1; sincosf(-PI2 * s4 / 64.0f, &s1, &c1);
            twc[0] = 1.f; tws[0] = 0.f;
            #pragma unroll
            for (int k = 1; k < 8; ++k) {
                twc[k] = twc[k-1]*c1 - tws[k-1]*s1;
                tws[k] = twc[k-1]*s1 + tws[k-1]*c1;
            }
        }
        // direct global->register loads (coalesced 128-B segments per row)
        const float* xb = x + (size_t)(t*64 + hq*4) * 8192 + cq * 32 + c;
        float xr[4][8];
        #pragma unroll
        for (int hh = 0; hh < 4; ++hh)
            #pragma unroll
            for (int h1 = 0; h1 < 8; ++h1)
                xr[hh][h1] = xb[(size_t)hh * 8192 + (h1*8 + s4) * 128];
        // stage 1: dft8 over w1 + twiddle -> zs
        #pragma unroll
        for (int hh = 0; hh < 4; ++hh) {
            float2 a[8], Y[8];
            #pragma unroll
            for (int h1 = 0; h1 < 8; ++h1) a[h1] = make_float2(xr[hh][h1], 0.f);
            dft8<-1>(a, Y);
            #pragma unroll
            for (int k0 = 0; k0 < 8; ++k0) {
                float2 z = make_float2(Y[k0].x*twc[k0] - Y[k0].y*tws[k0],
                                       Y[k0].x*tws[k0] + Y[k0].y*twc[k0]);
                zs[hh][k0*8 + s4][c] = __float22half2_rn(z);
            }
        }
        __syncthreads();                                      // B1
        // stage 2: dft8 over w0, emit om<=32 into sp
        #pragma unroll
        for (int hh = 0; hh < 4; ++hh) {
            float2 b[8], X[8];
            #pragma unroll
            for (int h0 = 0; h0 < 8; ++h0)
                b[h0] = __half22float2(zs[hh][s4*8 + h0][c]);
            dft8<-1>(b, X);
            #pragma unroll
            for (int k1 = 0; k1 < 8; ++k1) {
                int om = s4 + 8 * k1;
                if (om <= 32) sp[hh][om][c] = __float22half2_rn(X[k1]);
            }
        }
        __syncthreads();                                      // B2
        // dense write: full 64-B quads
        for (int i = tid; i < 1056; i += 256) {
            int hh = i & 3, ccl = (i >> 2) & 7, om = i >> 5;
            uint4 u = *(const uint4*)&sp[hh][om][ccl * 4];
            Z[(((size_t)(om*32 + cq*8 + ccl)*16 + t)*64 + hq*4 + hh)] = u;
        }
    } else {
        // ---------------- k_prep role (unchanged, fits in 32.8 KB) ----------------
        float (*Asl)[7][64] = (float(*)[7][64])smem;
        float (*Bsl)[7][64] = (float(*)[7][64])(smem + 12544);
        float2 (*Awl)[64]   = (float2(*)[64])(smem + 25088);
        float2 (*Bwl)[64]   = (float2(*)[64])(smem + 28672);
        float2* tw64        = (float2*)(smem + 32256);
        int kid = bid - 1024;
        int kt = kid / 66;
        int rem = kid % 66;
        int om = rem >> 1, chalf = rem & 1;
        int c0 = chalf * 64;
        for (int i = tid; i < 64; i += 256) {
            float s, cw; sincosf(-PI2 * i / 64.0f, &s, &cw);
            tw64[i] = make_float2(cw, s);
        }
        for (int i = tid; i < 49 * 64; i += 256) {
            int p = i >> 6, cl = i & 63;
            int kh = p / 7, kw = p % 7;
            int idx = (((c0 + cl) * 3 + kt) * 7 + kh) * 7 + kw;
            Asl[kh][kw][cl] = 0.9f * tanhf(Ak[idx]);
            Bsl[kh][kw][cl] = Bk[idx];
        }
        __syncthreads();
        for (int i = tid; i < 7 * 64; i += 256) {
            int kh = i >> 6, cl = i & 63;
            float2 aA = make_float2(0.f,0.f), aB = make_float2(0.f,0.f);
            #pragma unroll
            for (int kw = 0; kw < 7; ++kw) {
                float2 tw = tw64[(om * (kw - 3)) & 63];
                float va = Asl[kh][kw][cl], vb = Bsl[kh][kw][cl];
                aA.x = fmaf(va, tw.x, aA.x); aA.y = fmaf(va, tw.y, aA.y);
                aB.x = fmaf(vb, tw.x, aB.x); aB.y = fmaf(vb, tw.y, aB.y);
            }
            Awl[kh][cl] = aA; Bwl[kh][cl] = aB;
        }
        __syncthreads();
        for (int i = tid; i < 64 * 64; i += 256) {
            int eta = i >> 6, cl = i & 63;
            float2 aA = make_float2(0.f,0.f), aB = make_float2(0.f,0.f);
            #pragma unroll
            for (int kh = 0; kh < 7; ++kh) {
                float2 tw = tw64[(eta * (kh - 3)) & 63];
                aA = cmac(aA, Awl[kh][cl], tw);
                aB = cmac(aB, Bwl[kh][cl], tw);
            }
            int ep = ((eta & 7) << 3) | (eta >> 3);  // digit-swapped eta position
            int o = ((kt * 33 + om) * 64 + ep) * 128 + c0 + cl;
            Ahw[o] = __float22half2_rn(aA);
            Bhw[o] = __float22half2_rn(aB);
        }
    }
}

// ------- fused middle pass (unchanged, verified r10-r12): H-FFT + T + G + inv -------
__global__ __launch_bounds__(256) void pmid(uint4* __restrict__ Z,
                                            const __half2* __restrict__ Ahw,
                                            const __half2* __restrict__ Bhw) {
    __shared__ __half2 tl[16][64][4];     // 16 KB
    int l = (blockIdx.x & 7) * 132 + (blockIdx.x >> 3);   // XCD-chunked, bijective
    int om = l >> 5, cc = l & 31;
    int c0 = cc * 4;
    int tid = threadIdx.x;
    uint4* g = Z + (size_t)l * 1024;

    int d = tid & 7;
    float twc[8], tws[8];
    {
        float s1, c1; sincosf(-PI2 * d / 64.0f, &s1, &c1);
        twc[0] = 1.f; tws[0] = 0.f;
        #pragma unroll
        for (int k = 1; k < 8; ++k) {
            twc[k] = twc[k-1]*c1 - tws[k-1]*s1;
            tws[k] = twc[k-1]*s1 + tws[k-1]*c1;
        }
    }
    for (int i = tid; i < 1024; i += 256) {
        uint4 u = g[i];
        int t = i >> 6, h = i & 63;
        int pr = LROW(h);
        tl[t][pr][0] = *(__half2*)&u.x;
        tl[t][pr][1] = *(__half2*)&u.y;
        tl[t][pr][2] = *(__half2*)&u.z;
        tl[t][pr][3] = *(__half2*)&u.w;
    }
    __syncthreads();
    int cl = (tid >> 3) & 3, ts = tid >> 5;          // ts in [0,8)
    #pragma unroll
    for (int q = 0; q < 2; ++q) {
        int t = ts*2 + q;
        float2 a[8], Y[8];
        #pragma unroll
        for (int h1 = 0; h1 < 8; ++h1)
            a[h1] = __half22float2(tl[t][LROW(h1*8 + d)][cl]);
        dft8<-1>(a, Y);
        #pragma unroll
        for (int k0 = 0; k0 < 8; ++k0) {
            float2 z = make_float2(Y[k0].x*twc[k0] - Y[k0].y*tws[k0],
                                   Y[k0].x*tws[k0] + Y[k0].y*twc[k0]);
            tl[t][LROW(k0*8 + d)][cl] = __float22half2_rn(z);
        }
    }
    __syncthreads();
    #pragma unroll
    for (int q = 0; q < 2; ++q) {
        int t = ts*2 + q;
        float2 a[8], Y[8];
        #pragma unroll
        for (int h0 = 0; h0 < 8; ++h0)
            a[h0] = __half22float2(tl[t][LROW(d*8 + h0)][cl]);
        dft8<-1>(a, Y);
        #pragma unroll
        for (int k1 = 0; k1 < 8; ++k1)
            tl[t][LROW(d*8 + k1)][cl] = __float22half2_rn(Y[k1]);
    }
    __syncthreads();
    {
        const float CT16[16] = {1.f, 0.9238795325f, 0.7071067812f, 0.3826834324f, 0.f,
                                -0.3826834324f, -0.7071067812f, -0.9238795325f, -1.f,
                                -0.9238795325f, -0.7071067812f, -0.3826834324f, 0.f,
                                0.3826834324f, 0.7071067812f, 0.9238795325f};
        const float ST16[16] = {0.f, 0.3826834324f, 0.7071067812f, 0.9238795325f, 1.f,
                                0.9238795325f, 0.7071067812f, 0.3826834324f, 0.f,
                                -0.3826834324f, -0.7071067812f, -0.9238795325f, -1.f,
                                -0.9238795325f, -0.7071067812f, -0.3826834324f};
        int cg = tid & 3, rT = tid >> 2;             // rT in [0,64)
        const int PKT = 33 * 64 * 128;
        int kb = (om * 64 + rT) * 128 + c0 + cg;
        float2 A0 = __half22float2(Ahw[kb]);
        float2 A1 = __half22float2(Ahw[kb + PKT]);
        float2 A2 = __half22float2(Ahw[kb + 2*PKT]);
        float2 B0 = __half22float2(Bhw[kb]);
        float2 B1 = __half22float2(Bhw[kb + PKT]);
        float2 B2 = __half22float2(Bhw[kb + 2*PKT]);
        int pr = LROW(rT);
        float2 v[16], X[16];
        #pragma unroll
        for (int t = 0; t < 16; ++t) v[t] = __half22float2(tl[t][pr][cg]);
        dft16<-1>(v, X);
        #pragma unroll
        for (int ta = 0; ta < 16; ++ta) {
            float2 wv = make_float2(CT16[ta], -ST16[ta]);
            float2 wc = make_float2(CT16[ta],  ST16[ta]);
            float2 Af = A1; Af = cmac(Af, A0, wc); Af = cmac(Af, A2, wv);
            float2 Bf = B1; Bf = cmac(Bf, B0, wc); Bf = cmac(Bf, B2, wv);
            float2 A2q = csq(Af), A4q = csq(A2q);
            float2 S = cmul(make_float2(1.f+Af.x, Af.y), make_float2(1.f+A2q.x, A2q.y));
            S = cmul(S, make_float2(1.f+A4q.x, A4q.y));
            float2 G = cmul(S, Bf);
            X[ta] = cmul(X[ta], G);
        }
        dft16<1>(X, v);
        const float sc = 0.015625f;                  // 1/64 fold
        #pragma unroll
        for (int t = 0; t < 16; ++t)
            tl[t][pr][cg] = __float22half2_rn(make_float2(v[t].x*sc, v[t].y*sc));
    }
    __syncthreads();
    #pragma unroll
    for (int q = 0; q < 2; ++q) {
        int t = ts*2 + q;
        float2 a[8], Y[8];
        #pragma unroll
        for (int e1 = 0; e1 < 8; ++e1)
            a[e1] = __half22float2(tl[t][LROW(d*8 + e1)][cl]);
        dft8<1>(a, Y);
        #pragma unroll
        for (int h0 = 0; h0 < 8; ++h0) {
            float2 z = make_float2( Y[h0].x*twc[h0] + Y[h0].y*tws[h0],
                                   -Y[h0].x*tws[h0] + Y[h0].y*twc[h0]);
            tl[t][LROW(d*8 + h0)][cl] = __float22half2_rn(z);
        }
    }
    __syncthreads();
    #pragma unroll
    for (int q = 0; q < 2; ++q) {
        int t = ts*2 + q;
        float2 a[8], Y[8];
        #pragma unroll
        for (int e0 = 0; e0 < 8; ++e0)
            a[e0] = __half22float2(tl[t][LROW(e0*8 + d)][cl]);
        dft8<1>(a, Y);
        #pragma unroll
        for (int h1 = 0; h1 < 8; ++h1)
            tl[t][LROW(d + 8*h1)][cl] = __float22half2_rn(Y[h1]);
    }
    __syncthreads();
    for (int i = tid; i < 1024; i += 256) {
        int t = i >> 6, h = i & 63;
        int pr = LROW(h);
        uint4 u;
        __half2 v0 = tl[t][pr][0], v1 = tl[t][pr][1];
        __half2 v2 = tl[t][pr][2], v3 = tl[t][pr][3];
        u.x = *(unsigned int*)&v0; u.y = *(unsigned int*)&v1;
        u.z = *(unsigned int*)&v2; u.w = *(unsigned int*)&v3;
        g[i] = u;
    }
}

// ------- pass 5: dense Z read + Hermitian-expand + inverse W-FFT, c-quarter -------
// All 4 h-planes batched per phase -> 3 barriers (correctly sized 32 KB plane).
__global__ __launch_bounds__(256) void p5(const uint4* __restrict__ Z,
                                          float* __restrict__ out) {
    __shared__ __half2 plane[4][64][32];   // 32 KB
    __shared__ float2 tw64[64];
    int bid = blockIdx.x;
    int cq = bid & 3, hq = (bid >> 2) & 15, t = bid >> 6;
    int tid = threadIdx.x;
    if (tid < 64) {
        float s, cw; sincosf(PI2 * tid / 64.0f, &s, &cw);
        tw64[tid] = make_float2(cw, s);
    }
    // phase 1: dense read + Hermitian mirror directly into plane
    for (int i = tid; i < 1056; i += 256) {
        int hh = i & 3, ccl = (i >> 2) & 7, om = i >> 5;
        uint4 u = Z[(((size_t)(om*32 + cq*8 + ccl)*16 + t)*64 + hq*4 + hh)];
        *(uint4*)&plane[hh][om][ccl * 4] = u;
        if (om >= 1 && om <= 31) {
            __half2 m0 = *(__half2*)&u.x; m0.y = __hneg(m0.y);
            __half2 m1 = *(__half2*)&u.y; m1.y = __hneg(m1.y);
            __half2 m2 = *(__half2*)&u.z; m2.y = __hneg(m2.y);
            __half2 m3 = *(__half2*)&u.w; m3.y = __hneg(m3.y);
            plane[hh][64-om][ccl*4+0] = m0;
            plane[hh][64-om][ccl*4+1] = m1;
            plane[hh][64-om][ccl*4+2] = m2;
            plane[hh][64-om][ccl*4+3] = m3;
        }
    }
    __syncthreads();                                          // B1
    int c = tid & 31, s4 = tid >> 5;
    // phase 2a: read stage-1 inputs for all planes to registers
    __half2 arh[4][8];
    #pragma unroll
    for (int hh = 0; hh < 4; ++hh)
        #pragma unroll
        for (int h1 = 0; h1 < 8; ++h1)
            arh[hh][h1] = plane[hh][h1*8 + s4][c];
    __syncthreads();                                          // B2
    // phase 2b: dft8 + twiddle, write back in place
    #pragma unroll
    for (int hh = 0; hh < 4; ++hh) {
        float2 a[8], Y[8];
        #pragma unroll
        for (int h1 = 0; h1 < 8; ++h1) a[h1] = __half22float2(arh[hh][h1]);
        dft8<1>(a, Y);
        #pragma unroll
        for (int k0 = 0; k0 < 8; ++k0) {
            float2 z = cmul(Y[k0], tw64[(s4 * k0) & 63]);
            plane[hh][k0*8 + s4][c] = __float22half2_rn(z);
        }
    }
    __syncthreads();                                          // B3
    // phase 3: stage 2 + dense fp32 output (aligned 128-B runs)
    #pragma unroll
    for (int hh = 0; hh < 4; ++hh) {
        float2 b[8], X[8];
        #pragma unroll
        for (int h0 = 0; h0 < 8; ++h0)
            b[h0] = __half22float2(plane[hh][s4*8 + h0][c]);
        dft8<1>(b, X);
        float* dst = out + (size_t)(t*64 + hq*4 + hh) * 64 * 128 + cq * 32 + c;
        #pragma unroll
        for (int k1 = 0; k1 < 8; ++k1)
            dst[(size_t)(s4 + 8*k1) * 128] = X[k1].x * (1.0f / 1024.0f);
    }
}

extern "C" void kernel_launch(void* const* d_in, const int* in_sizes, int n_in,
                              void* d_out, int out_size, void* d_ws, size_t ws_size,
                              hipStream_t stream) {
    const float* x  = (const float*)d_in[0];
    const float* Ak = (const float*)d_in[1];
    const float* Bk = (const float*)d_in[2];
    float* out = (float*)d_out;

    // Z: 33*32 chunks x 16 KB = 17.3 MB (uint4-addressed); G tables after.
    uint4* Z = (uint4*)d_ws;
    __half2* Ahw = (__half2*)((char*)d_ws + (size_t)33*32*1024*16);
    __half2* Bhw = Ahw + 3 * 33 * 64 * 128;

    hipLaunchKernelGGL(pA,   dim3(1222), dim3(256), 0, stream, x, Z, Ak, Bk, Ahw, Bhw);
    hipLaunchKernelGGL(pmid, dim3(1056), dim3(256), 0, stream, Z, Ahw, Bhw);
    hipLaunchKernelGGL(p5,   dim3(1024), dim3(256), 0, stream, Z, out);
}

// Round 15
// 60.806 us; speedup vs baseline: 1.7720x; 1.0498x over previous
//
#include <hip/hip_runtime.h>
#include <hip/hip_fp16.h>
#include <math.h>

#define TT 16
#define HH 64
#define WW 64
#define CC 128
#define PI2 6.283185307179586f

// XOR digit swizzle: row r = hi*8+lo -> hi*8 + (lo^hi). Keeps stride-8 and
// block-8 row accesses <=2-way banked in the narrow [.,64][4] half2 tile.
#define LROW(r) (((r) & 0x38) | ((((r) >> 3) ^ (r)) & 7))

__device__ __forceinline__ float2 cadd(float2 a, float2 b){ return make_float2(a.x+b.x, a.y+b.y); }
__device__ __forceinline__ float2 csub(float2 a, float2 b){ return make_float2(a.x-b.x, a.y-b.y); }
__device__ __forceinline__ float2 cmul(float2 a, float2 b) {
    return make_float2(a.x*b.x - a.y*b.y, a.x*b.y + a.y*b.x);
}
__device__ __forceinline__ float2 cmac(float2 acc, float2 a, float2 b) {
    acc.x = fmaf(a.x, b.x, fmaf(-a.y, b.y, acc.x));
    acc.y = fmaf(a.x, b.y, fmaf(a.y, b.x, acc.y));
    return acc;
}
__device__ __forceinline__ float2 csq(float2 a) {
    return make_float2(a.x*a.x - a.y*a.y, 2.f*a.x*a.y);
}

// ---------------- radix butterflies ----------------
template<int SGN>
__device__ __forceinline__ void dft4(float2 b0, float2 b1, float2 b2, float2 b3,
                                     float2& y0, float2& y1, float2& y2, float2& y3) {
    float2 e0 = cadd(b0, b2), e1 = csub(b0, b2);
    float2 o0 = cadd(b1, b3), o1 = csub(b1, b3);
    y0 = cadd(e0, o0); y2 = csub(e0, o0);
    float2 r = make_float2((float)(-SGN) * o1.y, (float)SGN * o1.x);
    y1 = cadd(e1, r); y3 = csub(e1, r);
}

template<int SGN>
__device__ __forceinline__ void dft8(const float2* a, float2* X) {
    const float C = 0.70710678118654752f;
    float2 E0,E1,E2,E3,O0,O1,O2,O3;
    dft4<SGN>(a[0],a[2],a[4],a[6], E0,E1,E2,E3);
    dft4<SGN>(a[1],a[3],a[5],a[7], O0,O1,O2,O3);
    float2 T1 = make_float2(C*(O1.x - (float)SGN*O1.y), C*((float)SGN*O1.x + O1.y));
    float2 T2 = make_float2((float)(-SGN)*O2.y, (float)SGN*O2.x);
    float2 T3 = make_float2(-C*(O3.x + (float)SGN*O3.y), C*((float)SGN*O3.x - O3.y));
    X[0]=cadd(E0,O0); X[4]=csub(E0,O0);
    X[1]=cadd(E1,T1); X[5]=csub(E1,T1);
    X[2]=cadd(E2,T2); X[6]=csub(E2,T2);
    X[3]=cadd(E3,T3); X[7]=csub(E3,T3);
}

template<int SGN>
__device__ __forceinline__ void dft16(const float2* v, float2* X) {
    const float ct[10] = {1.f, 0.92387953251f, 0.70710678119f, 0.38268343236f, 0.f,
                          0.f, -0.70710678119f, 0.f, 0.f, -0.92387953251f};
    const float st[10] = {0.f, 0.38268343236f, 0.70710678119f, 0.92387953251f, 1.f,
                          0.f, 0.70710678119f, 0.f, 0.f, -0.38268343236f};
    float2 Z[16];
    #pragma unroll
    for (int h0 = 0; h0 < 4; ++h0) {
        float2 y0,y1,y2,y3;
        dft4<SGN>(v[h0], v[4+h0], v[8+h0], v[12+h0], y0,y1,y2,y3);
        float2 ys[4] = {y0,y1,y2,y3};
        #pragma unroll
        for (int k0 = 0; k0 < 4; ++k0) {
            int m = h0 * k0;
            float cc = ct[m], ss = (float)SGN * st[m];
            Z[k0*4 + h0] = make_float2(ys[k0].x*cc - ys[k0].y*ss,
                                       ys[k0].x*ss + ys[k0].y*cc);
        }
    }
    #pragma unroll
    for (int k0 = 0; k0 < 4; ++k0) {
        float2 y0,y1,y2,y3;
        dft4<SGN>(Z[k0*4+0], Z[k0*4+1], Z[k0*4+2], Z[k0*4+3], y0,y1,y2,y3);
        X[k0] = y0; X[k0+4] = y1; X[k0+8] = y2; X[k0+12] = y3;
    }
}

// Z layout (uint4 = 4 half2 = 4 channels): index ((om*32 + cc)*16 + t)*64 + h.
// Each pmid block owns one contiguous 16 KB chunk (om,cc).

// ======== fused pass A: blocks 0..1023 = p1 (paired real W-FFT), 1024..1221 = k_prep ====
// p1 role: pack h-plane pairs (2p, 2p+1) as re+i*im -> ONE complex FFT per pair,
// Hermitian-unpack in the write phase. 2 barriers, 32 KB LDS.
__global__ __launch_bounds__(256) void pA(const float* __restrict__ x,
                                          uint4* __restrict__ Z,
                                          const float* __restrict__ Ak,
                                          const float* __restrict__ Bk,
                                          __half2* __restrict__ Ahw,
                                          __half2* __restrict__ Bhw) {
    __shared__ __align__(16) char smem[32768];
    int bid = blockIdx.x;
    int tid = threadIdx.x;
    if (bid < 1024) {
        __half2 (*zs)[64][32]  = (__half2(*)[64][32])smem;             // 16 KB
        __half2 (*sp2)[64][32] = (__half2(*)[64][32])(smem + 16384);   // 16 KB (full 64 omega)
        int cq = bid & 3, hq = (bid >> 2) & 15, t = bid >> 6;
        int c = tid & 31, s4 = tid >> 5;           // s4 in [0,8)
        // per-thread stage-1 twiddles: w64^{-s4*k0}
        float twc[8], tws[8];
        {
            float s1, c1; sincosf(-PI2 * s4 / 64.0f, &s1, &c1);
            twc[0] = 1.f; tws[0] = 0.f;
            #pragma unroll
            for (int k = 1; k < 8; ++k) {
                twc[k] = twc[k-1]*c1 - tws[k-1]*s1;
                tws[k] = twc[k-1]*s1 + tws[k-1]*c1;
            }
        }
        const float* xb = x + (size_t)(t*64 + hq*4) * 8192 + cq * 32 + c;
        // stage 1: packed complex input (plane 2p = re, plane 2p+1 = im)
        #pragma unroll
        for (int p = 0; p < 2; ++p) {
            float2 a[8], Y[8];
            #pragma unroll
            for (int h1 = 0; h1 < 8; ++h1) {
                size_t off = (size_t)(h1*8 + s4) * 128;
                a[h1] = make_float2(xb[(size_t)(2*p) * 8192 + off],
                                    xb[(size_t)(2*p+1) * 8192 + off]);
            }
            dft8<-1>(a, Y);
            #pragma unroll
            for (int k0 = 0; k0 < 8; ++k0) {
                float2 z = make_float2(Y[k0].x*twc[k0] - Y[k0].y*tws[k0],
                                       Y[k0].x*tws[k0] + Y[k0].y*twc[k0]);
                zs[p][k0*8 + s4][c] = __float22half2_rn(z);
            }
        }
        __syncthreads();                                      // B1
        // stage 2: full 64-omega spectrum per pair
        #pragma unroll
        for (int p = 0; p < 2; ++p) {
            float2 b[8], X[8];
            #pragma unroll
            for (int h0 = 0; h0 < 8; ++h0)
                b[h0] = __half22float2(zs[p][s4*8 + h0][c]);
            dft8<-1>(b, X);
            #pragma unroll
            for (int k1 = 0; k1 < 8; ++k1)
                sp2[p][s4 + 8*k1][c] = __float22half2_rn(X[k1]);
        }
        __syncthreads();                                      // B2
        // unpack + dense write: X1 = (Z(om)+conj(Z(64-om)))/2, X2 = -i(Z(om)-conj)/2
        for (int i = tid; i < 528; i += 256) {                // p(2) x ccl(8) x om(33)
            int p = i & 1, ccl = (i >> 1) & 7, om = i >> 4;
            int mo = (64 - om) & 63;
            uint4 ua = *(const uint4*)&sp2[p][om][ccl * 4];
            uint4 ub = *(const uint4*)&sp2[p][mo][ccl * 4];
            uint4 u1, u2;
            const unsigned int* pa = &ua.x;
            const unsigned int* pb = &ub.x;
            unsigned int* p1o = &u1.x;
            unsigned int* p2o = &u2.x;
            #pragma unroll
            for (int j = 0; j < 4; ++j) {
                float2 za = __half22float2(*(const __half2*)&pa[j]);
                float2 zb = __half22float2(*(const __half2*)&pb[j]);
                float2 X1 = make_float2(0.5f*(za.x + zb.x), 0.5f*(za.y - zb.y));
                float2 X2 = make_float2(0.5f*(za.y + zb.y), 0.5f*(zb.x - za.x));
                __half2 h1v = __float22half2_rn(X1);
                __half2 h2v = __float22half2_rn(X2);
                p1o[j] = *(unsigned int*)&h1v;
                p2o[j] = *(unsigned int*)&h2v;
            }
            size_t base = ((size_t)(om*32 + cq*8 + ccl)*16 + t)*64 + hq*4;
            Z[base + 2*p]     = u1;
            Z[base + 2*p + 1] = u2;
        }
    } else {
        // ---------------- k_prep role (unchanged; exactly 32768 B) ----------------
        float (*Asl)[7][64] = (float(*)[7][64])smem;
        float (*Bsl)[7][64] = (float(*)[7][64])(smem + 12544);
        float2 (*Awl)[64]   = (float2(*)[64])(smem + 25088);
        float2 (*Bwl)[64]   = (float2(*)[64])(smem + 28672);
        float2* tw64        = (float2*)(smem + 32256);
        int kid = bid - 1024;
        int kt = kid / 66;
        int rem = kid % 66;
        int om = rem >> 1, chalf = rem & 1;
        int c0 = chalf * 64;
        for (int i = tid; i < 64; i += 256) {
            float s, cw; sincosf(-PI2 * i / 64.0f, &s, &cw);
            tw64[i] = make_float2(cw, s);
        }
        for (int i = tid; i < 49 * 64; i += 256) {
            int p = i >> 6, cl = i & 63;
            int kh = p / 7, kw = p % 7;
            int idx = (((c0 + cl) * 3 + kt) * 7 + kh) * 7 + kw;
            Asl[kh][kw][cl] = 0.9f * tanhf(Ak[idx]);
            Bsl[kh][kw][cl] = Bk[idx];
        }
        __syncthreads();
        for (int i = tid; i < 7 * 64; i += 256) {
            int kh = i >> 6, cl = i & 63;
            float2 aA = make_float2(0.f,0.f), aB = make_float2(0.f,0.f);
            #pragma unroll
            for (int kw = 0; kw < 7; ++kw) {
                float2 tw = tw64[(om * (kw - 3)) & 63];
                float va = Asl[kh][kw][cl], vb = Bsl[kh][kw][cl];
                aA.x = fmaf(va, tw.x, aA.x); aA.y = fmaf(va, tw.y, aA.y);
                aB.x = fmaf(vb, tw.x, aB.x); aB.y = fmaf(vb, tw.y, aB.y);
            }
            Awl[kh][cl] = aA; Bwl[kh][cl] = aB;
        }
        __syncthreads();
        for (int i = tid; i < 64 * 64; i += 256) {
            int eta = i >> 6, cl = i & 63;
            float2 aA = make_float2(0.f,0.f), aB = make_float2(0.f,0.f);
            #pragma unroll
            for (int kh = 0; kh < 7; ++kh) {
                float2 tw = tw64[(eta * (kh - 3)) & 63];
                aA = cmac(aA, Awl[kh][cl], tw);
                aB = cmac(aB, Bwl[kh][cl], tw);
            }
            int ep = ((eta & 7) << 3) | (eta >> 3);  // digit-swapped eta position
            int o = ((kt * 33 + om) * 64 + ep) * 128 + c0 + cl;
            Ahw[o] = __float22half2_rn(aA);
            Bhw[o] = __float22half2_rn(aB);
        }
    }
}

// ------- fused middle pass (unchanged, verified r10-r14): H-FFT + T + G + inv -------
__global__ __launch_bounds__(256) void pmid(uint4* __restrict__ Z,
                                            const __half2* __restrict__ Ahw,
                                            const __half2* __restrict__ Bhw) {
    __shared__ __half2 tl[16][64][4];     // 16 KB
    int l = (blockIdx.x & 7) * 132 + (blockIdx.x >> 3);   // XCD-chunked, bijective
    int om = l >> 5, cc = l & 31;
    int c0 = cc * 4;
    int tid = threadIdx.x;
    uint4* g = Z + (size_t)l * 1024;

    int d = tid & 7;
    float twc[8], tws[8];
    {
        float s1, c1; sincosf(-PI2 * d / 64.0f, &s1, &c1);
        twc[0] = 1.f; tws[0] = 0.f;
        #pragma unroll
        for (int k = 1; k < 8; ++k) {
            twc[k] = twc[k-1]*c1 - tws[k-1]*s1;
            tws[k] = twc[k-1]*s1 + tws[k-1]*c1;
        }
    }
    for (int i = tid; i < 1024; i += 256) {
        uint4 u = g[i];
        int t = i >> 6, h = i & 63;
        int pr = LROW(h);
        tl[t][pr][0] = *(__half2*)&u.x;
        tl[t][pr][1] = *(__half2*)&u.y;
        tl[t][pr][2] = *(__half2*)&u.z;
        tl[t][pr][3] = *(__half2*)&u.w;
    }
    __syncthreads();
    int cl = (tid >> 3) & 3, ts = tid >> 5;          // ts in [0,8)
    #pragma unroll
    for (int q = 0; q < 2; ++q) {
        int t = ts*2 + q;
        float2 a[8], Y[8];
        #pragma unroll
        for (int h1 = 0; h1 < 8; ++h1)
            a[h1] = __half22float2(tl[t][LROW(h1*8 + d)][cl]);
        dft8<-1>(a, Y);
        #pragma unroll
        for (int k0 = 0; k0 < 8; ++k0) {
            float2 z = make_float2(Y[k0].x*twc[k0] - Y[k0].y*tws[k0],
                                   Y[k0].x*tws[k0] + Y[k0].y*twc[k0]);
            tl[t][LROW(k0*8 + d)][cl] = __float22half2_rn(z);
        }
    }
    __syncthreads();
    #pragma unroll
    for (int q = 0; q < 2; ++q) {
        int t = ts*2 + q;
        float2 a[8], Y[8];
        #pragma unroll
        for (int h0 = 0; h0 < 8; ++h0)
            a[h0] = __half22float2(tl[t][LROW(d*8 + h0)][cl]);
        dft8<-1>(a, Y);
        #pragma unroll
        for (int k1 = 0; k1 < 8; ++k1)
            tl[t][LROW(d*8 + k1)][cl] = __float22half2_rn(Y[k1]);
    }
    __syncthreads();
    {
        const float CT16[16] = {1.f, 0.9238795325f, 0.7071067812f, 0.3826834324f, 0.f,
                                -0.3826834324f, -0.7071067812f, -0.9238795325f, -1.f,
                                -0.9238795325f, -0.7071067812f, -0.3826834324f, 0.f,
                                0.3826834324f, 0.7071067812f, 0.9238795325f};
        const float ST16[16] = {0.f, 0.3826834324f, 0.7071067812f, 0.9238795325f, 1.f,
                                0.9238795325f, 0.7071067812f, 0.3826834324f, 0.f,
                                -0.3826834324f, -0.7071067812f, -0.9238795325f, -1.f,
                                -0.9238795325f, -0.7071067812f, -0.3826834324f};
        int cg = tid & 3, rT = tid >> 2;             // rT in [0,64)
        const int PKT = 33 * 64 * 128;
        int kb = (om * 64 + rT) * 128 + c0 + cg;
        float2 A0 = __half22float2(Ahw[kb]);
        float2 A1 = __half22float2(Ahw[kb + PKT]);
        float2 A2 = __half22float2(Ahw[kb + 2*PKT]);
        float2 B0 = __half22float2(Bhw[kb]);
        float2 B1 = __half22float2(Bhw[kb + PKT]);
        float2 B2 = __half22float2(Bhw[kb + 2*PKT]);
        int pr = LROW(rT);
        float2 v[16], X[16];
        #pragma unroll
        for (int t = 0; t < 16; ++t) v[t] = __half22float2(tl[t][pr][cg]);
        dft16<-1>(v, X);
        #pragma unroll
        for (int ta = 0; ta < 16; ++ta) {
            float2 wv = make_float2(CT16[ta], -ST16[ta]);
            float2 wc = make_float2(CT16[ta],  ST16[ta]);
            float2 Af = A1; Af = cmac(Af, A0, wc); Af = cmac(Af, A2, wv);
            float2 Bf = B1; Bf = cmac(Bf, B0, wc); Bf = cmac(Bf, B2, wv);
            float2 A2q = csq(Af), A4q = csq(A2q);
            float2 S = cmul(make_float2(1.f+Af.x, Af.y), make_float2(1.f+A2q.x, A2q.y));
            S = cmul(S, make_float2(1.f+A4q.x, A4q.y));
            float2 G = cmul(S, Bf);
            X[ta] = cmul(X[ta], G);
        }
        dft16<1>(X, v);
        const float sc = 0.015625f;                  // 1/64 fold
        #pragma unroll
        for (int t = 0; t < 16; ++t)
            tl[t][pr][cg] = __float22half2_rn(make_float2(v[t].x*sc, v[t].y*sc));
    }
    __syncthreads();
    #pragma unroll
    for (int q = 0; q < 2; ++q) {
        int t = ts*2 + q;
        float2 a[8], Y[8];
        #pragma unroll
        for (int e1 = 0; e1 < 8; ++e1)
            a[e1] = __half22float2(tl[t][LROW(d*8 + e1)][cl]);
        dft8<1>(a, Y);
        #pragma unroll
        for (int h0 = 0; h0 < 8; ++h0) {
            float2 z = make_float2( Y[h0].x*twc[h0] + Y[h0].y*tws[h0],
                                   -Y[h0].x*tws[h0] + Y[h0].y*twc[h0]);
            tl[t][LROW(d*8 + h0)][cl] = __float22half2_rn(z);
        }
    }
    __syncthreads();
    #pragma unroll
    for (int q = 0; q < 2; ++q) {
        int t = ts*2 + q;
        float2 a[8], Y[8];
        #pragma unroll
        for (int e0 = 0; e0 < 8; ++e0)
            a[e0] = __half22float2(tl[t][LROW(e0*8 + d)][cl]);
        dft8<1>(a, Y);
        #pragma unroll
        for (int h1 = 0; h1 < 8; ++h1)
            tl[t][LROW(d + 8*h1)][cl] = __float22half2_rn(Y[h1]);
    }
    __syncthreads();
    for (int i = tid; i < 1024; i += 256) {
        int t = i >> 6, h = i & 63;
        int pr = LROW(h);
        uint4 u;
        __half2 v0 = tl[t][pr][0], v1 = tl[t][pr][1];
        __half2 v2 = tl[t][pr][2], v3 = tl[t][pr][3];
        u.x = *(unsigned int*)&v0; u.y = *(unsigned int*)&v1;
        u.z = *(unsigned int*)&v2; u.w = *(unsigned int*)&v3;
        g[i] = u;
    }
}

// ------- pass 5: paired inverse real-output W-FFT, 3 barriers, 16.5 KB LDS -------
// Pack Zp = X_{2p} + i*X_{2p+1} (Hermitian mirror folded into the pack);
// one inverse FFT per pair; re -> plane 2p, im -> plane 2p+1.
__global__ __launch_bounds__(256) void p5(const uint4* __restrict__ Z,
                                          float* __restrict__ out) {
    __shared__ __half2 pl[2][64][32];      // 16 KB
    __shared__ float2 tw64[64];
    int bid = blockIdx.x;
    int cq = bid & 3, hq = (bid >> 2) & 15, t = bid >> 6;
    int tid = threadIdx.x;
    if (tid < 64) {
        float s, cw; sincosf(PI2 * tid / 64.0f, &s, &cw);
        tw64[tid] = make_float2(cw, s);
    }
    // phase 1: read both planes of each pair, pack + Hermitian mirror
    for (int i = tid; i < 528; i += 256) {               // p(2) x ccl(8) x om(33)
        int p = i & 1, ccl = (i >> 1) & 7, om = i >> 4;
        size_t base = ((size_t)(om*32 + cq*8 + ccl)*16 + t)*64 + hq*4;
        uint4 ua = Z[base + 2*p];
        uint4 ub = Z[base + 2*p + 1];
        const unsigned int* pa = &ua.x;
        const unsigned int* pb = &ub.x;
        #pragma unroll
        for (int j = 0; j < 4; ++j) {
            float2 za = __half22float2(*(const __half2*)&pa[j]);
            float2 zb = __half22float2(*(const __half2*)&pb[j]);
            // Zp(om) = Xa + i*Xb
            pl[p][om][ccl*4+j] = __float22half2_rn(make_float2(za.x - zb.y, za.y + zb.x));
            if (om >= 1 && om <= 31) {
                // Zp(64-om) = conj(Xa) + i*conj(Xb)
                pl[p][64-om][ccl*4+j] =
                    __float22half2_rn(make_float2(za.x + zb.y, zb.x - za.y));
            }
        }
    }
    __syncthreads();                                          // B1
    int c = tid & 31, s4 = tid >> 5;
    // phase 2a: read stage-1 inputs to registers
    __half2 arh[2][8];
    #pragma unroll
    for (int p = 0; p < 2; ++p)
        #pragma unroll
        for (int h1 = 0; h1 < 8; ++h1)
            arh[p][h1] = pl[p][h1*8 + s4][c];
    __syncthreads();                                          // B2
    // phase 2b: inverse dft8 + twiddle, in place
    #pragma unroll
    for (int p = 0; p < 2; ++p) {
        float2 a[8], Y[8];
        #pragma unroll
        for (int h1 = 0; h1 < 8; ++h1) a[h1] = __half22float2(arh[p][h1]);
        dft8<1>(a, Y);
        #pragma unroll
        for (int k0 = 0; k0 < 8; ++k0) {
            float2 z = cmul(Y[k0], tw64[(s4 * k0) & 63]);
            pl[p][k0*8 + s4][c] = __float22half2_rn(z);
        }
    }
    __syncthreads();                                          // B3
    // phase 3: stage 2 + dual-plane fp32 output (re -> 2p, im -> 2p+1)
    #pragma unroll
    for (int p = 0; p < 2; ++p) {
        float2 b[8], X[8];
        #pragma unroll
        for (int h0 = 0; h0 < 8; ++h0)
            b[h0] = __half22float2(pl[p][s4*8 + h0][c]);
        dft8<1>(b, X);
        float* dst = out + (size_t)(t*64 + hq*4 + 2*p) * 8192 + cq * 32 + c;
        #pragma unroll
        for (int k1 = 0; k1 < 8; ++k1) {
            size_t o = (size_t)(s4 + 8*k1) * 128;
            dst[o]        = X[k1].x * (1.0f / 1024.0f);
            dst[o + 8192] = X[k1].y * (1.0f / 1024.0f);
        }
    }
}

extern "C" void kernel_launch(void* const* d_in, const int* in_sizes, int n_in,
                              void* d_out, int out_size, void* d_ws, size_t ws_size,
                              hipStream_t stream) {
    const float* x  = (const float*)d_in[0];
    const float* Ak = (const float*)d_in[1];
    const float* Bk = (const float*)d_in[2];
    float* out = (float*)d_out;

    // Z: 33*32 chunks x 16 KB = 17.3 MB (uint4-addressed); G tables after.
    uint4* Z = (uint4*)d_ws;
    __half2* Ahw = (__half2*)((char*)d_ws + (size_t)33*32*1024*16);
    __half2* Bhw = Ahw + 3 * 33 * 64 * 128;

    hipLaunchKernelGGL(pA,   dim3(1222), dim3(256), 0, stream, x, Z, Ak, Bk, Ahw, Bhw);
    hipLaunchKernelGGL(pmid, dim3(1056), dim3(256), 0, stream, Z, Ahw, Bhw);
    hipLaunchKernelGGL(p5,   dim3(1024), dim3(256), 0, stream, Z, out);
}

// Round 16
// 57.108 us; speedup vs baseline: 1.8867x; 1.0647x over previous
//
#include <hip/hip_runtime.h>
#include <hip/hip_fp16.h>
#include <math.h>

#define TT 16
#define HH 64
#define WW 64
#define CC 128
#define PI2 6.283185307179586f

// XOR digit swizzle: row r = hi*8+lo -> hi*8 + (lo^hi). Keeps stride-8 and
// block-8 row accesses <=2-way banked in the narrow [.,64][4] tiles.
#define LROW(r) (((r) & 0x38) | ((((r) >> 3) ^ (r)) & 7))

__device__ __forceinline__ float2 cadd(float2 a, float2 b){ return make_float2(a.x+b.x, a.y+b.y); }
__device__ __forceinline__ float2 csub(float2 a, float2 b){ return make_float2(a.x-b.x, a.y-b.y); }
__device__ __forceinline__ float2 cmul(float2 a, float2 b) {
    return make_float2(a.x*b.x - a.y*b.y, a.x*b.y + a.y*b.x);
}
__device__ __forceinline__ float2 cmac(float2 acc, float2 a, float2 b) {
    acc.x = fmaf(a.x, b.x, fmaf(-a.y, b.y, acc.x));
    acc.y = fmaf(a.x, b.y, fmaf(a.y, b.x, acc.y));
    return acc;
}
__device__ __forceinline__ float2 csq(float2 a) {
    return make_float2(a.x*a.x - a.y*a.y, 2.f*a.x*a.y);
}

// ---------------- radix butterflies ----------------
template<int SGN>
__device__ __forceinline__ void dft4(float2 b0, float2 b1, float2 b2, float2 b3,
                                     float2& y0, float2& y1, float2& y2, float2& y3) {
    float2 e0 = cadd(b0, b2), e1 = csub(b0, b2);
    float2 o0 = cadd(b1, b3), o1 = csub(b1, b3);
    y0 = cadd(e0, o0); y2 = csub(e0, o0);
    float2 r = make_float2((float)(-SGN) * o1.y, (float)SGN * o1.x);
    y1 = cadd(e1, r); y3 = csub(e1, r);
}

template<int SGN>
__device__ __forceinline__ void dft8(const float2* a, float2* X) {
    const float C = 0.70710678118654752f;
    float2 E0,E1,E2,E3,O0,O1,O2,O3;
    dft4<SGN>(a[0],a[2],a[4],a[6], E0,E1,E2,E3);
    dft4<SGN>(a[1],a[3],a[5],a[7], O0,O1,O2,O3);
    float2 T1 = make_float2(C*(O1.x - (float)SGN*O1.y), C*((float)SGN*O1.x + O1.y));
    float2 T2 = make_float2((float)(-SGN)*O2.y, (float)SGN*O2.x);
    float2 T3 = make_float2(-C*(O3.x + (float)SGN*O3.y), C*((float)SGN*O3.x - O3.y));
    X[0]=cadd(E0,O0); X[4]=csub(E0,O0);
    X[1]=cadd(E1,T1); X[5]=csub(E1,T1);
    X[2]=cadd(E2,T2); X[6]=csub(E2,T2);
    X[3]=cadd(E3,T3); X[7]=csub(E3,T3);
}

template<int SGN>
__device__ __forceinline__ void dft16(const float2* v, float2* X) {
    const float ct[10] = {1.f, 0.92387953251f, 0.70710678119f, 0.38268343236f, 0.f,
                          0.f, -0.70710678119f, 0.f, 0.f, -0.92387953251f};
    const float st[10] = {0.f, 0.38268343236f, 0.70710678119f, 0.92387953251f, 1.f,
                          0.f, 0.70710678119f, 0.f, 0.f, -0.38268343236f};
    float2 Z[16];
    #pragma unroll
    for (int h0 = 0; h0 < 4; ++h0) {
        float2 y0,y1,y2,y3;
        dft4<SGN>(v[h0], v[4+h0], v[8+h0], v[12+h0], y0,y1,y2,y3);
        float2 ys[4] = {y0,y1,y2,y3};
        #pragma unroll
        for (int k0 = 0; k0 < 4; ++k0) {
            int m = h0 * k0;
            float cc = ct[m], ss = (float)SGN * st[m];
            Z[k0*4 + h0] = make_float2(ys[k0].x*cc - ys[k0].y*ss,
                                       ys[k0].x*ss + ys[k0].y*cc);
        }
    }
    #pragma unroll
    for (int k0 = 0; k0 < 4; ++k0) {
        float2 y0,y1,y2,y3;
        dft4<SGN>(Z[k0*4+0], Z[k0*4+1], Z[k0*4+2], Z[k0*4+3], y0,y1,y2,y3);
        X[k0] = y0; X[k0+4] = y1; X[k0+8] = y2; X[k0+12] = y3;
    }
}

// Z layout (uint4 = 4 half2 = 4 channels): index ((om*32 + cc)*16 + t)*64 + h.
// Each pmid block owns one contiguous 16 KB chunk (om,cc).

// ======== fused pass A: blocks 0..1023 = p1 (paired real W-FFT), 1024..1221 = k_prep ====
// Unchanged from r15 (verified).
__global__ __launch_bounds__(256) void pA(const float* __restrict__ x,
                                          uint4* __restrict__ Z,
                                          const float* __restrict__ Ak,
                                          const float* __restrict__ Bk,
                                          __half2* __restrict__ Ahw,
                                          __half2* __restrict__ Bhw) {
    __shared__ __align__(16) char smem[32768];
    int bid = blockIdx.x;
    int tid = threadIdx.x;
    if (bid < 1024) {
        __half2 (*zs)[64][32]  = (__half2(*)[64][32])smem;             // 16 KB
        __half2 (*sp2)[64][32] = (__half2(*)[64][32])(smem + 16384);   // 16 KB
        int cq = bid & 3, hq = (bid >> 2) & 15, t = bid >> 6;
        int c = tid & 31, s4 = tid >> 5;           // s4 in [0,8)
        float twc[8], tws[8];
        {
            float s1, c1; sincosf(-PI2 * s4 / 64.0f, &s1, &c1);
            twc[0] = 1.f; tws[0] = 0.f;
            #pragma unroll
            for (int k = 1; k < 8; ++k) {
                twc[k] = twc[k-1]*c1 - tws[k-1]*s1;
                tws[k] = twc[k-1]*s1 + tws[k-1]*c1;
            }
        }
        const float* xb = x + (size_t)(t*64 + hq*4) * 8192 + cq * 32 + c;
        #pragma unroll
        for (int p = 0; p < 2; ++p) {
            float2 a[8], Y[8];
            #pragma unroll
            for (int h1 = 0; h1 < 8; ++h1) {
                size_t off = (size_t)(h1*8 + s4) * 128;
                a[h1] = make_float2(xb[(size_t)(2*p) * 8192 + off],
                                    xb[(size_t)(2*p+1) * 8192 + off]);
            }
            dft8<-1>(a, Y);
            #pragma unroll
            for (int k0 = 0; k0 < 8; ++k0) {
                float2 z = make_float2(Y[k0].x*twc[k0] - Y[k0].y*tws[k0],
                                       Y[k0].x*tws[k0] + Y[k0].y*twc[k0]);
                zs[p][k0*8 + s4][c] = __float22half2_rn(z);
            }
        }
        __syncthreads();                                      // B1
        #pragma unroll
        for (int p = 0; p < 2; ++p) {
            float2 b[8], X[8];
            #pragma unroll
            for (int h0 = 0; h0 < 8; ++h0)
                b[h0] = __half22float2(zs[p][s4*8 + h0][c]);
            dft8<-1>(b, X);
            #pragma unroll
            for (int k1 = 0; k1 < 8; ++k1)
                sp2[p][s4 + 8*k1][c] = __float22half2_rn(X[k1]);
        }
        __syncthreads();                                      // B2
        for (int i = tid; i < 528; i += 256) {                // p(2) x ccl(8) x om(33)
            int p = i & 1, ccl = (i >> 1) & 7, om = i >> 4;
            int mo = (64 - om) & 63;
            uint4 ua = *(const uint4*)&sp2[p][om][ccl * 4];
            uint4 ub = *(const uint4*)&sp2[p][mo][ccl * 4];
            uint4 u1, u2;
            const unsigned int* pa = &ua.x;
            const unsigned int* pb = &ub.x;
            unsigned int* p1o = &u1.x;
            unsigned int* p2o = &u2.x;
            #pragma unroll
            for (int j = 0; j < 4; ++j) {
                float2 za = __half22float2(*(const __half2*)&pa[j]);
                float2 zb = __half22float2(*(const __half2*)&pb[j]);
                float2 X1 = make_float2(0.5f*(za.x + zb.x), 0.5f*(za.y - zb.y));
                float2 X2 = make_float2(0.5f*(za.y + zb.y), 0.5f*(zb.x - za.x));
                __half2 h1v = __float22half2_rn(X1);
                __half2 h2v = __float22half2_rn(X2);
                p1o[j] = *(unsigned int*)&h1v;
                p2o[j] = *(unsigned int*)&h2v;
            }
            size_t base = ((size_t)(om*32 + cq*8 + ccl)*16 + t)*64 + hq*4;
            Z[base + 2*p]     = u1;
            Z[base + 2*p + 1] = u2;
        }
    } else {
        float (*Asl)[7][64] = (float(*)[7][64])smem;
        float (*Bsl)[7][64] = (float(*)[7][64])(smem + 12544);
        float2 (*Awl)[64]   = (float2(*)[64])(smem + 25088);
        float2 (*Bwl)[64]   = (float2(*)[64])(smem + 28672);
        float2* tw64        = (float2*)(smem + 32256);
        int kid = bid - 1024;
        int kt = kid / 66;
        int rem = kid % 66;
        int om = rem >> 1, chalf = rem & 1;
        int c0 = chalf * 64;
        for (int i = tid; i < 64; i += 256) {
            float s, cw; sincosf(-PI2 * i / 64.0f, &s, &cw);
            tw64[i] = make_float2(cw, s);
        }
        for (int i = tid; i < 49 * 64; i += 256) {
            int p = i >> 6, cl = i & 63;
            int kh = p / 7, kw = p % 7;
            int idx = (((c0 + cl) * 3 + kt) * 7 + kh) * 7 + kw;
            Asl[kh][kw][cl] = 0.9f * tanhf(Ak[idx]);
            Bsl[kh][kw][cl] = Bk[idx];
        }
        __syncthreads();
        for (int i = tid; i < 7 * 64; i += 256) {
            int kh = i >> 6, cl = i & 63;
            float2 aA = make_float2(0.f,0.f), aB = make_float2(0.f,0.f);
            #pragma unroll
            for (int kw = 0; kw < 7; ++kw) {
                float2 tw = tw64[(om * (kw - 3)) & 63];
                float va = Asl[kh][kw][cl], vb = Bsl[kh][kw][cl];
                aA.x = fmaf(va, tw.x, aA.x); aA.y = fmaf(va, tw.y, aA.y);
                aB.x = fmaf(vb, tw.x, aB.x); aB.y = fmaf(vb, tw.y, aB.y);
            }
            Awl[kh][cl] = aA; Bwl[kh][cl] = aB;
        }
        __syncthreads();
        for (int i = tid; i < 64 * 64; i += 256) {
            int eta = i >> 6, cl = i & 63;
            float2 aA = make_float2(0.f,0.f), aB = make_float2(0.f,0.f);
            #pragma unroll
            for (int kh = 0; kh < 7; ++kh) {
                float2 tw = tw64[(eta * (kh - 3)) & 63];
                aA = cmac(aA, Awl[kh][cl], tw);
                aB = cmac(aB, Bwl[kh][cl], tw);
            }
            int ep = ((eta & 7) << 3) | (eta >> 3);  // digit-swapped eta position
            int o = ((kt * 33 + om) * 64 + ep) * 128 + c0 + cl;
            Ahw[o] = __float22half2_rn(aA);
            Bhw[o] = __float22half2_rn(aB);
        }
    }
}

// ------- fused middle pass: fp32 SoA LDS (conversions only at global boundary) -------
__global__ __launch_bounds__(256) void pmid(uint4* __restrict__ Z,
                                            const __half2* __restrict__ Ahw,
                                            const __half2* __restrict__ Bhw) {
    __shared__ float tre[16][64][4];      // 16 KB
    __shared__ float tim[16][64][4];      // 16 KB
    int l = (blockIdx.x & 7) * 132 + (blockIdx.x >> 3);   // XCD-chunked, bijective
    int om = l >> 5, cc = l & 31;
    int c0 = cc * 4;
    int tid = threadIdx.x;
    uint4* g = Z + (size_t)l * 1024;

    int d = tid & 7;
    float twc[8], tws[8];
    {
        float s1, c1; sincosf(-PI2 * d / 64.0f, &s1, &c1);
        twc[0] = 1.f; tws[0] = 0.f;
        #pragma unroll
        for (int k = 1; k < 8; ++k) {
            twc[k] = twc[k-1]*c1 - tws[k-1]*s1;
            tws[k] = twc[k-1]*s1 + tws[k-1]*c1;
        }
    }
    // load: contiguous 16 KB; convert half->float ONCE
    for (int i = tid; i < 1024; i += 256) {
        uint4 u = g[i];
        int t = i >> 6, h = i & 63;
        int pr = LROW(h);
        float2 v0 = __half22float2(*(__half2*)&u.x);
        float2 v1 = __half22float2(*(__half2*)&u.y);
        float2 v2 = __half22float2(*(__half2*)&u.z);
        float2 v3 = __half22float2(*(__half2*)&u.w);
        tre[t][pr][0] = v0.x; tim[t][pr][0] = v0.y;
        tre[t][pr][1] = v1.x; tim[t][pr][1] = v1.y;
        tre[t][pr][2] = v2.x; tim[t][pr][2] = v2.y;
        tre[t][pr][3] = v3.x; tim[t][pr][3] = v3.y;
    }
    __syncthreads();
    int cl = (tid >> 3) & 3, ts = tid >> 5;          // ts in [0,8)
    // H forward stage 1
    #pragma unroll
    for (int q = 0; q < 2; ++q) {
        int t = ts*2 + q;
        float2 a[8], Y[8];
        #pragma unroll
        for (int h1 = 0; h1 < 8; ++h1) {
            int pr = LROW(h1*8 + d);
            a[h1] = make_float2(tre[t][pr][cl], tim[t][pr][cl]);
        }
        dft8<-1>(a, Y);
        #pragma unroll
        for (int k0 = 0; k0 < 8; ++k0) {
            int pr = LROW(k0*8 + d);
            tre[t][pr][cl] = Y[k0].x*twc[k0] - Y[k0].y*tws[k0];
            tim[t][pr][cl] = Y[k0].x*tws[k0] + Y[k0].y*twc[k0];
        }
    }
    __syncthreads();
    // H forward stage 2
    #pragma unroll
    for (int q = 0; q < 2; ++q) {
        int t = ts*2 + q;
        float2 a[8], Y[8];
        #pragma unroll
        for (int h0 = 0; h0 < 8; ++h0) {
            int pr = LROW(d*8 + h0);
            a[h0] = make_float2(tre[t][pr][cl], tim[t][pr][cl]);
        }
        dft8<-1>(a, Y);
        #pragma unroll
        for (int k1 = 0; k1 < 8; ++k1) {
            int pr = LROW(d*8 + k1);
            tre[t][pr][cl] = Y[k1].x; tim[t][pr][cl] = Y[k1].y;
        }
    }
    __syncthreads();
    // T phase
    {
        const float CT16[16] = {1.f, 0.9238795325f, 0.7071067812f, 0.3826834324f, 0.f,
                                -0.3826834324f, -0.7071067812f, -0.9238795325f, -1.f,
                                -0.9238795325f, -0.7071067812f, -0.3826834324f, 0.f,
                                0.3826834324f, 0.7071067812f, 0.9238795325f};
        const float ST16[16] = {0.f, 0.3826834324f, 0.7071067812f, 0.9238795325f, 1.f,
                                0.9238795325f, 0.7071067812f, 0.3826834324f, 0.f,
                                -0.3826834324f, -0.7071067812f, -0.9238795325f, -1.f,
                                -0.9238795325f, -0.7071067812f, -0.3826834324f};
        int cg = tid & 3, rT = tid >> 2;             // rT in [0,64)
        const int PKT = 33 * 64 * 128;
        int kb = (om * 64 + rT) * 128 + c0 + cg;
        float2 A0 = __half22float2(Ahw[kb]);
        float2 A1 = __half22float2(Ahw[kb + PKT]);
        float2 A2 = __half22float2(Ahw[kb + 2*PKT]);
        float2 B0 = __half22float2(Bhw[kb]);
        float2 B1 = __half22float2(Bhw[kb + PKT]);
        float2 B2 = __half22float2(Bhw[kb + 2*PKT]);
        int pr = LROW(rT);
        float2 v[16], X[16];
        #pragma unroll
        for (int t = 0; t < 16; ++t) v[t] = make_float2(tre[t][pr][cg], tim[t][pr][cg]);
        dft16<-1>(v, X);
        #pragma unroll
        for (int ta = 0; ta < 16; ++ta) {
            float2 wv = make_float2(CT16[ta], -ST16[ta]);
            float2 wc = make_float2(CT16[ta],  ST16[ta]);
            float2 Af = A1; Af = cmac(Af, A0, wc); Af = cmac(Af, A2, wv);
            float2 Bf = B1; Bf = cmac(Bf, B0, wc); Bf = cmac(Bf, B2, wv);
            float2 A2q = csq(Af), A4q = csq(A2q);
            float2 S = cmul(make_float2(1.f+Af.x, Af.y), make_float2(1.f+A2q.x, A2q.y));
            S = cmul(S, make_float2(1.f+A4q.x, A4q.y));
            float2 G = cmul(S, Bf);
            X[ta] = cmul(X[ta], G);
        }
        dft16<1>(X, v);
        const float sc = 0.015625f;                  // 1/64 fold
        #pragma unroll
        for (int t = 0; t < 16; ++t) {
            tre[t][pr][cg] = v[t].x * sc;
            tim[t][pr][cg] = v[t].y * sc;
        }
    }
    __syncthreads();
    // inverse H stage 1
    #pragma unroll
    for (int q = 0; q < 2; ++q) {
        int t = ts*2 + q;
        float2 a[8], Y[8];
        #pragma unroll
        for (int e1 = 0; e1 < 8; ++e1) {
            int pr = LROW(d*8 + e1);
            a[e1] = make_float2(tre[t][pr][cl], tim[t][pr][cl]);
        }
        dft8<1>(a, Y);
        #pragma unroll
        for (int h0 = 0; h0 < 8; ++h0) {
            int pr = LROW(d*8 + h0);
            tre[t][pr][cl] =  Y[h0].x*twc[h0] + Y[h0].y*tws[h0];
            tim[t][pr][cl] = -Y[h0].x*tws[h0] + Y[h0].y*twc[h0];
        }
    }
    __syncthreads();
    // inverse H stage 2
    #pragma unroll
    for (int q = 0; q < 2; ++q) {
        int t = ts*2 + q;
        float2 a[8], Y[8];
        #pragma unroll
        for (int e0 = 0; e0 < 8; ++e0) {
            int pr = LROW(e0*8 + d);
            a[e0] = make_float2(tre[t][pr][cl], tim[t][pr][cl]);
        }
        dft8<1>(a, Y);
        #pragma unroll
        for (int h1 = 0; h1 < 8; ++h1) {
            int pr = LROW(d + 8*h1);
            tre[t][pr][cl] = Y[h1].x; tim[t][pr][cl] = Y[h1].y;
        }
    }
    __syncthreads();
    // write back: convert float->half ONCE
    for (int i = tid; i < 1024; i += 256) {
        int t = i >> 6, h = i & 63;
        int pr = LROW(h);
        uint4 u;
        __half2 v0 = __float22half2_rn(make_float2(tre[t][pr][0], tim[t][pr][0]));
        __half2 v1 = __float22half2_rn(make_float2(tre[t][pr][1], tim[t][pr][1]));
        __half2 v2 = __float22half2_rn(make_float2(tre[t][pr][2], tim[t][pr][2]));
        __half2 v3 = __float22half2_rn(make_float2(tre[t][pr][3], tim[t][pr][3]));
        u.x = *(unsigned int*)&v0; u.y = *(unsigned int*)&v1;
        u.z = *(unsigned int*)&v2; u.w = *(unsigned int*)&v3;
        g[i] = u;
    }
}

// ------- pass 5: paired inverse real-output W-FFT, fp32 SoA LDS -------
__global__ __launch_bounds__(256) void p5(const uint4* __restrict__ Z,
                                          float* __restrict__ out) {
    __shared__ float plre[2][64][32];      // 16 KB
    __shared__ float plim[2][64][32];      // 16 KB
    __shared__ float2 tw64[64];
    int bid = blockIdx.x;
    int cq = bid & 3, hq = (bid >> 2) & 15, t = bid >> 6;
    int tid = threadIdx.x;
    if (tid < 64) {
        float s, cw; sincosf(PI2 * tid / 64.0f, &s, &cw);
        tw64[tid] = make_float2(cw, s);
    }
    // phase 1: read both planes of each pair, pack + Hermitian mirror (fp32 in LDS)
    for (int i = tid; i < 528; i += 256) {               // p(2) x ccl(8) x om(33)
        int p = i & 1, ccl = (i >> 1) & 7, om = i >> 4;
        size_t base = ((size_t)(om*32 + cq*8 + ccl)*16 + t)*64 + hq*4;
        uint4 ua = Z[base + 2*p];
        uint4 ub = Z[base + 2*p + 1];
        const unsigned int* pa = &ua.x;
        const unsigned int* pb = &ub.x;
        #pragma unroll
        for (int j = 0; j < 4; ++j) {
            float2 za = __half22float2(*(const __half2*)&pa[j]);
            float2 zb = __half22float2(*(const __half2*)&pb[j]);
            // Zp(om) = Xa + i*Xb
            plre[p][om][ccl*4+j] = za.x - zb.y;
            plim[p][om][ccl*4+j] = za.y + zb.x;
            if (om >= 1 && om <= 31) {
                // Zp(64-om) = conj(Xa) + i*conj(Xb)
                plre[p][64-om][ccl*4+j] = za.x + zb.y;
                plim[p][64-om][ccl*4+j] = zb.x - za.y;
            }
        }
    }
    __syncthreads();                                          // B1
    int c = tid & 31, s4 = tid >> 5;
    // phase 2a: read stage-1 inputs to registers
    float2 ar[2][8];
    #pragma unroll
    for (int p = 0; p < 2; ++p)
        #pragma unroll
        for (int h1 = 0; h1 < 8; ++h1)
            ar[p][h1] = make_float2(plre[p][h1*8 + s4][c], plim[p][h1*8 + s4][c]);
    __syncthreads();                                          // B2
    // phase 2b: inverse dft8 + twiddle, in place (fp32)
    #pragma unroll
    for (int p = 0; p < 2; ++p) {
        float2 Y[8];
        dft8<1>(ar[p], Y);
        #pragma unroll
        for (int k0 = 0; k0 < 8; ++k0) {
            float2 z = cmul(Y[k0], tw64[(s4 * k0) & 63]);
            plre[p][k0*8 + s4][c] = z.x;
            plim[p][k0*8 + s4][c] = z.y;
        }
    }
    __syncthreads();                                          // B3
    // phase 3: stage 2 + dual-plane fp32 output (re -> 2p, im -> 2p+1)
    #pragma unroll
    for (int p = 0; p < 2; ++p) {
        float2 b[8], X[8];
        #pragma unroll
        for (int h0 = 0; h0 < 8; ++h0)
            b[h0] = make_float2(plre[p][s4*8 + h0][c], plim[p][s4*8 + h0][c]);
        dft8<1>(b, X);
        float* dst = out + (size_t)(t*64 + hq*4 + 2*p) * 8192 + cq * 32 + c;
        #pragma unroll
        for (int k1 = 0; k1 < 8; ++k1) {
            size_t o = (size_t)(s4 + 8*k1) * 128;
            dst[o]        = X[k1].x * (1.0f / 1024.0f);
            dst[o + 8192] = X[k1].y * (1.0f / 1024.0f);
        }
    }
}

extern "C" void kernel_launch(void* const* d_in, const int* in_sizes, int n_in,
                              void* d_out, int out_size, void* d_ws, size_t ws_size,
                              hipStream_t stream) {
    const float* x  = (const float*)d_in[0];
    const float* Ak = (const float*)d_in[1];
    const float* Bk = (const float*)d_in[2];
    float* out = (float*)d_out;

    // Z: 33*32 chunks x 16 KB = 17.3 MB (uint4-addressed); G tables after.
    uint4* Z = (uint4*)d_ws;
    __half2* Ahw = (__half2*)((char*)d_ws + (size_t)33*32*1024*16);
    __half2* Bhw = Ahw + 3 * 33 * 64 * 128;

    hipLaunchKernelGGL(pA,   dim3(1222), dim3(256), 0, stream, x, Z, Ak, Bk, Ahw, Bhw);
    hipLaunchKernelGGL(pmid, dim3(1056), dim3(256), 0, stream, Z, Ahw, Bhw);
    hipLaunchKernelGGL(p5,   dim3(1024), dim3(256), 0, stream, Z, out);
}

// Round 17
// 57.039 us; speedup vs baseline: 1.8890x; 1.0012x over previous
//
#include <hip/hip_runtime.h>
#include <hip/hip_fp16.h>
#include <math.h>

#define TT 16
#define HH 64
#define WW 64
#define CC 128
#define PI2 6.283185307179586f

// XOR digit swizzle: row r = hi*8+lo -> hi*8 + (lo^hi). Keeps stride-8 and
// block-8 row accesses <=2-way banked in the narrow [.,64][4] tiles.
#define LROW(r) (((r) & 0x38) | ((((r) >> 3) ^ (r)) & 7))

__device__ __forceinline__ float2 cadd(float2 a, float2 b){ return make_float2(a.x+b.x, a.y+b.y); }
__device__ __forceinline__ float2 csub(float2 a, float2 b){ return make_float2(a.x-b.x, a.y-b.y); }
__device__ __forceinline__ float2 cmul(float2 a, float2 b) {
    return make_float2(a.x*b.x - a.y*b.y, a.x*b.y + a.y*b.x);
}
__device__ __forceinline__ float2 cmac(float2 acc, float2 a, float2 b) {
    acc.x = fmaf(a.x, b.x, fmaf(-a.y, b.y, acc.x));
    acc.y = fmaf(a.x, b.y, fmaf(a.y, b.x, acc.y));
    return acc;
}
__device__ __forceinline__ float2 csq(float2 a) {
    return make_float2(a.x*a.x - a.y*a.y, 2.f*a.x*a.y);
}

// ---------------- radix butterflies ----------------
template<int SGN>
__device__ __forceinline__ void dft4(float2 b0, float2 b1, float2 b2, float2 b3,
                                     float2& y0, float2& y1, float2& y2, float2& y3) {
    float2 e0 = cadd(b0, b2), e1 = csub(b0, b2);
    float2 o0 = cadd(b1, b3), o1 = csub(b1, b3);
    y0 = cadd(e0, o0); y2 = csub(e0, o0);
    float2 r = make_float2((float)(-SGN) * o1.y, (float)SGN * o1.x);
    y1 = cadd(e1, r); y3 = csub(e1, r);
}

template<int SGN>
__device__ __forceinline__ void dft8(const float2* a, float2* X) {
    const float C = 0.70710678118654752f;
    float2 E0,E1,E2,E3,O0,O1,O2,O3;
    dft4<SGN>(a[0],a[2],a[4],a[6], E0,E1,E2,E3);
    dft4<SGN>(a[1],a[3],a[5],a[7], O0,O1,O2,O3);
    float2 T1 = make_float2(C*(O1.x - (float)SGN*O1.y), C*((float)SGN*O1.x + O1.y));
    float2 T2 = make_float2((float)(-SGN)*O2.y, (float)SGN*O2.x);
    float2 T3 = make_float2(-C*(O3.x + (float)SGN*O3.y), C*((float)SGN*O3.x - O3.y));
    X[0]=cadd(E0,O0); X[4]=csub(E0,O0);
    X[1]=cadd(E1,T1); X[5]=csub(E1,T1);
    X[2]=cadd(E2,T2); X[6]=csub(E2,T2);
    X[3]=cadd(E3,T3); X[7]=csub(E3,T3);
}

template<int SGN>
__device__ __forceinline__ void dft16(const float2* v, float2* X) {
    const float ct[10] = {1.f, 0.92387953251f, 0.70710678119f, 0.38268343236f, 0.f,
                          0.f, -0.70710678119f, 0.f, 0.f, -0.92387953251f};
    const float st[10] = {0.f, 0.38268343236f, 0.70710678119f, 0.92387953251f, 1.f,
                          0.f, 0.70710678119f, 0.f, 0.f, -0.38268343236f};
    float2 Z[16];
    #pragma unroll
    for (int h0 = 0; h0 < 4; ++h0) {
        float2 y0,y1,y2,y3;
        dft4<SGN>(v[h0], v[4+h0], v[8+h0], v[12+h0], y0,y1,y2,y3);
        float2 ys[4] = {y0,y1,y2,y3};
        #pragma unroll
        for (int k0 = 0; k0 < 4; ++k0) {
            int m = h0 * k0;
            float cc = ct[m], ss = (float)SGN * st[m];
            Z[k0*4 + h0] = make_float2(ys[k0].x*cc - ys[k0].y*ss,
                                       ys[k0].x*ss + ys[k0].y*cc);
        }
    }
    #pragma unroll
    for (int k0 = 0; k0 < 4; ++k0) {
        float2 y0,y1,y2,y3;
        dft4<SGN>(Z[k0*4+0], Z[k0*4+1], Z[k0*4+2], Z[k0*4+3], y0,y1,y2,y3);
        X[k0] = y0; X[k0+4] = y1; X[k0+8] = y2; X[k0+12] = y3;
    }
}

// Z layout (uint4 = 4 half2 = 4 channels): index ((om*32 + cc)*16 + t)*64 + h.
// Each pmid block owns one contiguous 16 KB chunk (om,cc).

// ======== fused pass A: blocks 0..1023 = p1 (paired real W-FFT), 1024..1221 = k_prep ====
// p1 role: fp32 SoA LDS throughout; half2 conversion only at the global Z write.
// zs fp32 [2][64][32] re@0/im@16384 (32 KB); sp aliases the same arena after B2.
__global__ __launch_bounds__(256) void pA(const float* __restrict__ x,
                                          uint4* __restrict__ Z,
                                          const float* __restrict__ Ak,
                                          const float* __restrict__ Bk,
                                          __half2* __restrict__ Ahw,
                                          __half2* __restrict__ Bhw) {
    __shared__ __align__(16) char smem[32768];
    int bid = blockIdx.x;
    int tid = threadIdx.x;
    if (bid < 1024) {
        float (*zsre)[64][32] = (float(*)[64][32])smem;             // 16 KB
        float (*zsim)[64][32] = (float(*)[64][32])(smem + 16384);   // 16 KB
        float (*spre)[64][32] = (float(*)[64][32])smem;             // alias
        float (*spim)[64][32] = (float(*)[64][32])(smem + 16384);   // alias
        int cq = bid & 3, hq = (bid >> 2) & 15, t = bid >> 6;
        int c = tid & 31, s4 = tid >> 5;           // s4 in [0,8)
        float twc[8], tws[8];
        {
            float s1, c1; sincosf(-PI2 * s4 / 64.0f, &s1, &c1);
            twc[0] = 1.f; tws[0] = 0.f;
            #pragma unroll
            for (int k = 1; k < 8; ++k) {
                twc[k] = twc[k-1]*c1 - tws[k-1]*s1;
                tws[k] = twc[k-1]*s1 + tws[k-1]*c1;
            }
        }
        const float* xb = x + (size_t)(t*64 + hq*4) * 8192 + cq * 32 + c;
        // stage 1: packed complex input (plane 2p = re, plane 2p+1 = im), fp32 out
        #pragma unroll
        for (int p = 0; p < 2; ++p) {
            float2 a[8], Y[8];
            #pragma unroll
            for (int h1 = 0; h1 < 8; ++h1) {
                size_t off = (size_t)(h1*8 + s4) * 128;
                a[h1] = make_float2(xb[(size_t)(2*p) * 8192 + off],
                                    xb[(size_t)(2*p+1) * 8192 + off]);
            }
            dft8<-1>(a, Y);
            #pragma unroll
            for (int k0 = 0; k0 < 8; ++k0) {
                int row = k0*8 + s4;
                zsre[p][row][c] = Y[k0].x*twc[k0] - Y[k0].y*tws[k0];
                zsim[p][row][c] = Y[k0].x*tws[k0] + Y[k0].y*twc[k0];
            }
        }
        __syncthreads();                                      // B1
        // stage 2: read ALL zs inputs for both pairs, dft8 in registers
        float2 X0[8], X1[8];
        {
            float2 b[8];
            #pragma unroll
            for (int h0 = 0; h0 < 8; ++h0)
                b[h0] = make_float2(zsre[0][s4*8 + h0][c], zsim[0][s4*8 + h0][c]);
            dft8<-1>(b, X0);
            #pragma unroll
            for (int h0 = 0; h0 < 8; ++h0)
                b[h0] = make_float2(zsre[1][s4*8 + h0][c], zsim[1][s4*8 + h0][c]);
            dft8<-1>(b, X1);
        }
        __syncthreads();                                      // B2 (all zs reads done -> alias safe)
        #pragma unroll
        for (int k1 = 0; k1 < 8; ++k1) {
            int row = s4 + 8*k1;
            spre[0][row][c] = X0[k1].x; spim[0][row][c] = X0[k1].y;
            spre[1][row][c] = X1[k1].x; spim[1][row][c] = X1[k1].y;
        }
        __syncthreads();                                      // B3
        // unpack + dense write: X1 = (Z(om)+conj(Z(mo)))/2, X2 = -i(Z(om)-conj)/2
        for (int i = tid; i < 528; i += 256) {                // p(2) x ccl(8) x om(33)
            int p = i & 1, ccl = (i >> 1) & 7, om = i >> 4;
            int mo = (64 - om) & 63;
            uint4 u1, u2;
            unsigned int* p1o = &u1.x;
            unsigned int* p2o = &u2.x;
            #pragma unroll
            for (int j = 0; j < 4; ++j) {
                int cb = ccl*4 + j;
                float2 za = make_float2(spre[p][om][cb], spim[p][om][cb]);
                float2 zb = make_float2(spre[p][mo][cb], spim[p][mo][cb]);
                float2 Xa = make_float2(0.5f*(za.x + zb.x), 0.5f*(za.y - zb.y));
                float2 Xb = make_float2(0.5f*(za.y + zb.y), 0.5f*(zb.x - za.x));
                __half2 h1v = __float22half2_rn(Xa);
                __half2 h2v = __float22half2_rn(Xb);
                p1o[j] = *(unsigned int*)&h1v;
                p2o[j] = *(unsigned int*)&h2v;
            }
            size_t base = ((size_t)(om*32 + cq*8 + ccl)*16 + t)*64 + hq*4;
            Z[base + 2*p]     = u1;
            Z[base + 2*p + 1] = u2;
        }
    } else {
        // ---------------- k_prep role (unchanged; exactly 32768 B) ----------------
        float (*Asl)[7][64] = (float(*)[7][64])smem;
        float (*Bsl)[7][64] = (float(*)[7][64])(smem + 12544);
        float2 (*Awl)[64]   = (float2(*)[64])(smem + 25088);
        float2 (*Bwl)[64]   = (float2(*)[64])(smem + 28672);
        float2* tw64        = (float2*)(smem + 32256);
        int kid = bid - 1024;
        int kt = kid / 66;
        int rem = kid % 66;
        int om = rem >> 1, chalf = rem & 1;
        int c0 = chalf * 64;
        for (int i = tid; i < 64; i += 256) {
            float s, cw; sincosf(-PI2 * i / 64.0f, &s, &cw);
            tw64[i] = make_float2(cw, s);
        }
        for (int i = tid; i < 49 * 64; i += 256) {
            int p = i >> 6, cl = i & 63;
            int kh = p / 7, kw = p % 7;
            int idx = (((c0 + cl) * 3 + kt) * 7 + kh) * 7 + kw;
            Asl[kh][kw][cl] = 0.9f * tanhf(Ak[idx]);
            Bsl[kh][kw][cl] = Bk[idx];
        }
        __syncthreads();
        for (int i = tid; i < 7 * 64; i += 256) {
            int kh = i >> 6, cl = i & 63;
            float2 aA = make_float2(0.f,0.f), aB = make_float2(0.f,0.f);
            #pragma unroll
            for (int kw = 0; kw < 7; ++kw) {
                float2 tw = tw64[(om * (kw - 3)) & 63];
                float va = Asl[kh][kw][cl], vb = Bsl[kh][kw][cl];
                aA.x = fmaf(va, tw.x, aA.x); aA.y = fmaf(va, tw.y, aA.y);
                aB.x = fmaf(vb, tw.x, aB.x); aB.y = fmaf(vb, tw.y, aB.y);
            }
            Awl[kh][cl] = aA; Bwl[kh][cl] = aB;
        }
        __syncthreads();
        for (int i = tid; i < 64 * 64; i += 256) {
            int eta = i >> 6, cl = i & 63;
            float2 aA = make_float2(0.f,0.f), aB = make_float2(0.f,0.f);
            #pragma unroll
            for (int kh = 0; kh < 7; ++kh) {
                float2 tw = tw64[(eta * (kh - 3)) & 63];
                aA = cmac(aA, Awl[kh][cl], tw);
                aB = cmac(aB, Bwl[kh][cl], tw);
            }
            int ep = ((eta & 7) << 3) | (eta >> 3);  // digit-swapped eta position
            int o = ((kt * 33 + om) * 64 + ep) * 128 + c0 + cl;
            Ahw[o] = __float22half2_rn(aA);
            Bhw[o] = __float22half2_rn(aB);
        }
    }
}

// ------- fused middle pass (unchanged from r16): fp32 SoA LDS -------
__global__ __launch_bounds__(256) void pmid(uint4* __restrict__ Z,
                                            const __half2* __restrict__ Ahw,
                                            const __half2* __restrict__ Bhw) {
    __shared__ float tre[16][64][4];      // 16 KB
    __shared__ float tim[16][64][4];      // 16 KB
    int l = (blockIdx.x & 7) * 132 + (blockIdx.x >> 3);   // XCD-chunked, bijective
    int om = l >> 5, cc = l & 31;
    int c0 = cc * 4;
    int tid = threadIdx.x;
    uint4* g = Z + (size_t)l * 1024;

    int d = tid & 7;
    float twc[8], tws[8];
    {
        float s1, c1; sincosf(-PI2 * d / 64.0f, &s1, &c1);
        twc[0] = 1.f; tws[0] = 0.f;
        #pragma unroll
        for (int k = 1; k < 8; ++k) {
            twc[k] = twc[k-1]*c1 - tws[k-1]*s1;
            tws[k] = twc[k-1]*s1 + tws[k-1]*c1;
        }
    }
    for (int i = tid; i < 1024; i += 256) {
        uint4 u = g[i];
        int t = i >> 6, h = i & 63;
        int pr = LROW(h);
        float2 v0 = __half22float2(*(__half2*)&u.x);
        float2 v1 = __half22float2(*(__half2*)&u.y);
        float2 v2 = __half22float2(*(__half2*)&u.z);
        float2 v3 = __half22float2(*(__half2*)&u.w);
        tre[t][pr][0] = v0.x; tim[t][pr][0] = v0.y;
        tre[t][pr][1] = v1.x; tim[t][pr][1] = v1.y;
        tre[t][pr][2] = v2.x; tim[t][pr][2] = v2.y;
        tre[t][pr][3] = v3.x; tim[t][pr][3] = v3.y;
    }
    __syncthreads();
    int cl = (tid >> 3) & 3, ts = tid >> 5;          // ts in [0,8)
    #pragma unroll
    for (int q = 0; q < 2; ++q) {
        int t = ts*2 + q;
        float2 a[8], Y[8];
        #pragma unroll
        for (int h1 = 0; h1 < 8; ++h1) {
            int pr = LROW(h1*8 + d);
            a[h1] = make_float2(tre[t][pr][cl], tim[t][pr][cl]);
        }
        dft8<-1>(a, Y);
        #pragma unroll
        for (int k0 = 0; k0 < 8; ++k0) {
            int pr = LROW(k0*8 + d);
            tre[t][pr][cl] = Y[k0].x*twc[k0] - Y[k0].y*tws[k0];
            tim[t][pr][cl] = Y[k0].x*tws[k0] + Y[k0].y*twc[k0];
        }
    }
    __syncthreads();
    #pragma unroll
    for (int q = 0; q < 2; ++q) {
        int t = ts*2 + q;
        float2 a[8], Y[8];
        #pragma unroll
        for (int h0 = 0; h0 < 8; ++h0) {
            int pr = LROW(d*8 + h0);
            a[h0] = make_float2(tre[t][pr][cl], tim[t][pr][cl]);
        }
        dft8<-1>(a, Y);
        #pragma unroll
        for (int k1 = 0; k1 < 8; ++k1) {
            int pr = LROW(d*8 + k1);
            tre[t][pr][cl] = Y[k1].x; tim[t][pr][cl] = Y[k1].y;
        }
    }
    __syncthreads();
    {
        const float CT16[16] = {1.f, 0.9238795325f, 0.7071067812f, 0.3826834324f, 0.f,
                                -0.3826834324f, -0.7071067812f, -0.9238795325f, -1.f,
                                -0.9238795325f, -0.7071067812f, -0.3826834324f, 0.f,
                                0.3826834324f, 0.7071067812f, 0.9238795325f};
        const float ST16[16] = {0.f, 0.3826834324f, 0.7071067812f, 0.9238795325f, 1.f,
                                0.9238795325f, 0.7071067812f, 0.3826834324f, 0.f,
                                -0.3826834324f, -0.7071067812f, -0.9238795325f, -1.f,
                                -0.9238795325f, -0.7071067812f, -0.3826834324f};
        int cg = tid & 3, rT = tid >> 2;             // rT in [0,64)
        const int PKT = 33 * 64 * 128;
        int kb = (om * 64 + rT) * 128 + c0 + cg;
        float2 A0 = __half22float2(Ahw[kb]);
        float2 A1 = __half22float2(Ahw[kb + PKT]);
        float2 A2 = __half22float2(Ahw[kb + 2*PKT]);
        float2 B0 = __half22float2(Bhw[kb]);
        float2 B1 = __half22float2(Bhw[kb + PKT]);
        float2 B2 = __half22float2(Bhw[kb + 2*PKT]);
        int pr = LROW(rT);
        float2 v[16], X[16];
        #pragma unroll
        for (int t = 0; t < 16; ++t) v[t] = make_float2(tre[t][pr][cg], tim[t][pr][cg]);
        dft16<-1>(v, X);
        #pragma unroll
        for (int ta = 0; ta < 16; ++ta) {
            float2 wv = make_float2(CT16[ta], -ST16[ta]);
            float2 wc = make_float2(CT16[ta],  ST16[ta]);
            float2 Af = A1; Af = cmac(Af, A0, wc); Af = cmac(Af, A2, wv);
            float2 Bf = B1; Bf = cmac(Bf, B0, wc); Bf = cmac(Bf, B2, wv);
            float2 A2q = csq(Af), A4q = csq(A2q);
            float2 S = cmul(make_float2(1.f+Af.x, Af.y), make_float2(1.f+A2q.x, A2q.y));
            S = cmul(S, make_float2(1.f+A4q.x, A4q.y));
            float2 G = cmul(S, Bf);
            X[ta] = cmul(X[ta], G);
        }
        dft16<1>(X, v);
        const float sc = 0.015625f;                  // 1/64 fold
        #pragma unroll
        for (int t = 0; t < 16; ++t) {
            tre[t][pr][cg] = v[t].x * sc;
            tim[t][pr][cg] = v[t].y * sc;
        }
    }
    __syncthreads();
    #pragma unroll
    for (int q = 0; q < 2; ++q) {
        int t = ts*2 + q;
        float2 a[8], Y[8];
        #pragma unroll
        for (int e1 = 0; e1 < 8; ++e1) {
            int pr = LROW(d*8 + e1);
            a[e1] = make_float2(tre[t][pr][cl], tim[t][pr][cl]);
        }
        dft8<1>(a, Y);
        #pragma unroll
        for (int h0 = 0; h0 < 8; ++h0) {
            int pr = LROW(d*8 + h0);
            tre[t][pr][cl] =  Y[h0].x*twc[h0] + Y[h0].y*tws[h0];
            tim[t][pr][cl] = -Y[h0].x*tws[h0] + Y[h0].y*twc[h0];
        }
    }
    __syncthreads();
    #pragma unroll
    for (int q = 0; q < 2; ++q) {
        int t = ts*2 + q;
        float2 a[8], Y[8];
        #pragma unroll
        for (int e0 = 0; e0 < 8; ++e0) {
            int pr = LROW(e0*8 + d);
            a[e0] = make_float2(tre[t][pr][cl], tim[t][pr][cl]);
        }
        dft8<1>(a, Y);
        #pragma unroll
        for (int h1 = 0; h1 < 8; ++h1) {
            int pr = LROW(d + 8*h1);
            tre[t][pr][cl] = Y[h1].x; tim[t][pr][cl] = Y[h1].y;
        }
    }
    __syncthreads();
    for (int i = tid; i < 1024; i += 256) {
        int t = i >> 6, h = i & 63;
        int pr = LROW(h);
        uint4 u;
        __half2 v0 = __float22half2_rn(make_float2(tre[t][pr][0], tim[t][pr][0]));
        __half2 v1 = __float22half2_rn(make_float2(tre[t][pr][1], tim[t][pr][1]));
        __half2 v2 = __float22half2_rn(make_float2(tre[t][pr][2], tim[t][pr][2]));
        __half2 v3 = __float22half2_rn(make_float2(tre[t][pr][3], tim[t][pr][3]));
        u.x = *(unsigned int*)&v0; u.y = *(unsigned int*)&v1;
        u.z = *(unsigned int*)&v2; u.w = *(unsigned int*)&v3;
        g[i] = u;
    }
}

// ------- pass 5 (unchanged from r16): paired inverse real-output W-FFT, fp32 SoA LDS -------
__global__ __launch_bounds__(256) void p5(const uint4* __restrict__ Z,
                                          float* __restrict__ out) {
    __shared__ float plre[2][64][32];      // 16 KB
    __shared__ float plim[2][64][32];      // 16 KB
    __shared__ float2 tw64[64];
    int bid = blockIdx.x;
    int cq = bid & 3, hq = (bid >> 2) & 15, t = bid >> 6;
    int tid = threadIdx.x;
    if (tid < 64) {
        float s, cw; sincosf(PI2 * tid / 64.0f, &s, &cw);
        tw64[tid] = make_float2(cw, s);
    }
    for (int i = tid; i < 528; i += 256) {               // p(2) x ccl(8) x om(33)
        int p = i & 1, ccl = (i >> 1) & 7, om = i >> 4;
        size_t base = ((size_t)(om*32 + cq*8 + ccl)*16 + t)*64 + hq*4;
        uint4 ua = Z[base + 2*p];
        uint4 ub = Z[base + 2*p + 1];
        const unsigned int* pa = &ua.x;
        const unsigned int* pb = &ub.x;
        #pragma unroll
        for (int j = 0; j < 4; ++j) {
            float2 za = __half22float2(*(const __half2*)&pa[j]);
            float2 zb = __half22float2(*(const __half2*)&pb[j]);
            plre[p][om][ccl*4+j] = za.x - zb.y;
            plim[p][om][ccl*4+j] = za.y + zb.x;
            if (om >= 1 && om <= 31) {
                plre[p][64-om][ccl*4+j] = za.x + zb.y;
                plim[p][64-om][ccl*4+j] = zb.x - za.y;
            }
        }
    }
    __syncthreads();                                          // B1
    int c = tid & 31, s4 = tid >> 5;
    float2 ar[2][8];
    #pragma unroll
    for (int p = 0; p < 2; ++p)
        #pragma unroll
        for (int h1 = 0; h1 < 8; ++h1)
            ar[p][h1] = make_float2(plre[p][h1*8 + s4][c], plim[p][h1*8 + s4][c]);
    __syncthreads();                                          // B2
    #pragma unroll
    for (int p = 0; p < 2; ++p) {
        float2 Y[8];
        dft8<1>(ar[p], Y);
        #pragma unroll
        for (int k0 = 0; k0 < 8; ++k0) {
            float2 z = cmul(Y[k0], tw64[(s4 * k0) & 63]);
            plre[p][k0*8 + s4][c] = z.x;
            plim[p][k0*8 + s4][c] = z.y;
        }
    }
    __syncthreads();                                          // B3
    #pragma unroll
    for (int p = 0; p < 2; ++p) {
        float2 b[8], X[8];
        #pragma unroll
        for (int h0 = 0; h0 < 8; ++h0)
            b[h0] = make_float2(plre[p][s4*8 + h0][c], plim[p][s4*8 + h0][c]);
        dft8<1>(b, X);
        float* dst = out + (size_t)(t*64 + hq*4 + 2*p) * 8192 + cq * 32 + c;
        #pragma unroll
        for (int k1 = 0; k1 < 8; ++k1) {
            size_t o = (size_t)(s4 + 8*k1) * 128;
            dst[o]        = X[k1].x * (1.0f / 1024.0f);
            dst[o + 8192] = X[k1].y * (1.0f / 1024.0f);
        }
    }
}

extern "C" void kernel_launch(void* const* d_in, const int* in_sizes, int n_in,
                              void* d_out, int out_size, void* d_ws, size_t ws_size,
                              hipStream_t stream) {
    const float* x  = (const float*)d_in[0];
    const float* Ak = (const float*)d_in[1];
    const float* Bk = (const float*)d_in[2];
    float* out = (float*)d_out;

    // Z: 33*32 chunks x 16 KB = 17.3 MB (uint4-addressed); G tables after.
    uint4* Z = (uint4*)d_ws;
    __half2* Ahw = (__half2*)((char*)d_ws + (size_t)33*32*1024*16);
    __half2* Bhw = Ahw + 3 * 33 * 64 * 128;

    hipLaunchKernelGGL(pA,   dim3(1222), dim3(256), 0, stream, x, Z, Ak, Bk, Ahw, Bhw);
    hipLaunchKernelGGL(pmid, dim3(1056), dim3(256), 0, stream, Z, Ahw, Bhw);
    hipLaunchKernelGGL(p5,   dim3(1024), dim3(256), 0, stream, Z, out);
}